// Round 1
// baseline (8781.155 us; speedup 1.0000x reference)
//
#include <hip/hip_runtime.h>
#include <math.h>

#define NN 20000
#define EE 320000
#define EPE 340000   // EE + NN self loops
#define GG 64
#define HH 8
#define EPSV 1e-5f

// ---- monotonic float<->uint key for atomic max on signed floats ----
__device__ __forceinline__ unsigned int fkey(float f){
    unsigned int u = __float_as_uint(f);
    return (u & 0x80000000u) ? ~u : (u | 0x80000000u);
}
__device__ __forceinline__ float funkey(unsigned int k){
    unsigned int u = (k & 0x80000000u) ? (k ^ 0x80000000u) : ~k;
    return __uint_as_float(u);
}

__global__ void k_count(const int* __restrict__ batch, float* __restrict__ cnt){
    int i = blockIdx.x*blockDim.x + threadIdx.x;
    if (i < NN) atomicAdd(&cnt[batch[i]], 1.0f);
}

// xl = h@Wl + bl ; xr = h@Wr + br  (one thread per output element, shared h read)
__global__ void k_gemm_dual(const float* __restrict__ h,
                            const float* __restrict__ Wl, const float* __restrict__ bl,
                            const float* __restrict__ Wr, const float* __restrict__ br,
                            float* __restrict__ xl, float* __restrict__ xr,
                            int K, int HC){
    int idx = blockIdx.x*blockDim.x + threadIdx.x;
    if (idx >= NN*HC) return;
    int row = idx / HC, col = idx - row*HC;
    const float* hr = h + (long)row*K;
    float al = 0.f, ar = 0.f;
    for (int k = 0; k < K; ++k){
        float hv = hr[k];
        al += hv * Wl[k*HC + col];
        ar += hv * Wr[k*HC + col];
    }
    xl[idx] = al + bl[col];
    xr[idx] = ar + br[col];
}

// per (edge, head): a = sum_c leaky_relu(xl[s]+xr[d]) * att ; atomic max per (dst, head)
__global__ void k_edge_attn(const int* __restrict__ esrc, const int* __restrict__ edst,
                            const float* __restrict__ xl, const float* __restrict__ xr,
                            const float* __restrict__ att, float* __restrict__ P,
                            unsigned int* __restrict__ M, int C, int HC){
    int idx = blockIdx.x*blockDim.x + threadIdx.x;
    if (idx >= EPE*HH) return;
    int e = idx >> 3, h = idx & 7;
    int s, d;
    if (e < EE){ s = esrc[e]; d = edst[e]; } else { s = e - EE; d = s; }
    const float* xs = xl + (long)s*HC + h*C;
    const float* xd = xr + (long)d*HC + h*C;
    const float* at = att + h*C;
    float a = 0.f;
    for (int c = 0; c < C; c += 4){
        float4 v1 = *(const float4*)(xs + c);
        float4 v2 = *(const float4*)(xd + c);
        float4 av = *(const float4*)(at + c);
        float t;
        t = v1.x + v2.x; t = t > 0.f ? t : 0.2f*t; a += t*av.x;
        t = v1.y + v2.y; t = t > 0.f ? t : 0.2f*t; a += t*av.y;
        t = v1.z + v2.z; t = t > 0.f ? t : 0.2f*t; a += t*av.z;
        t = v1.w + v2.w; t = t > 0.f ? t : 0.2f*t; a += t*av.w;
    }
    P[idx] = a;
    atomicMax(&M[d*HH + h], fkey(a));
}

// per (edge, head): p = exp(a - amax[d]); accumulate denom S[d,h] and unnormalized out D[d,h,:]
__global__ void k_edge_aggr(const int* __restrict__ esrc, const int* __restrict__ edst,
                            const float* __restrict__ xl, const float* __restrict__ P,
                            const unsigned int* __restrict__ M, float* __restrict__ S,
                            float* __restrict__ D, int C, int HC){
    int idx = blockIdx.x*blockDim.x + threadIdx.x;
    if (idx >= EPE*HH) return;
    int e = idx >> 3, h = idx & 7;
    int s, d;
    if (e < EE){ s = esrc[e]; d = edst[e]; } else { s = e - EE; d = s; }
    float p = expf(P[idx] - funkey(M[d*HH + h]));
    atomicAdd(&S[d*HH + h], p);
    const float* xs = xl + (long)s*HC + h*C;
    float* Dd = D + (long)d*HC + h*C;
    for (int c = 0; c < C; ++c) atomicAdd(&Dd[c], p * xs[c]);
}

// concat epilogue: val = D/S + bias ; accumulate per-graph sum
__global__ void k_epilogue(const float* __restrict__ D, const float* __restrict__ S,
                           const float* __restrict__ bias, const int* __restrict__ batch,
                           float* __restrict__ val, float* __restrict__ gsum, int C, int HC){
    int idx = blockIdx.x*blockDim.x + threadIdx.x;
    if (idx >= NN*HC) return;
    int n = idx / HC, c = idx - n*HC, h = c / C;
    float v = D[idx] / S[n*HH + h] + bias[c];
    val[idx] = v;
    atomicAdd(&gsum[batch[n]*HC + c], v);
}

// head-mean epilogue (layer 3): val[n,c] = mean_h(D[n,h,c]/S[n,h]) + bias[c]
__global__ void k_epilogue_mean(const float* __restrict__ D, const float* __restrict__ S,
                                const float* __restrict__ bias, const int* __restrict__ batch,
                                float* __restrict__ val, float* __restrict__ gsum){
    int idx = blockIdx.x*blockDim.x + threadIdx.x;
    if (idx >= NN*8) return;
    int n = idx >> 3, c = idx & 7;
    float acc = 0.f;
    for (int h = 0; h < 8; ++h) acc += D[n*64 + h*8 + c] / S[n*8 + h];
    float v = acc * 0.125f + bias[c];
    val[idx] = v;
    atomicAdd(&gsum[batch[n]*8 + c], v);
}

// t = val - (gsum/cnt)*ms ; accumulate t^2 per (graph, channel)
__global__ void k_gn_center(const float* __restrict__ val, const float* __restrict__ gsum,
                            const float* __restrict__ cnt, const float* __restrict__ ms,
                            const int* __restrict__ batch, float* __restrict__ t,
                            float* __restrict__ gvar, int F){
    int idx = blockIdx.x*blockDim.x + threadIdx.x;
    if (idx >= NN*F) return;
    int n = idx / F, c = idx - n*F, g = batch[n];
    float cn = fmaxf(cnt[g], 1.0f);
    float mean = gsum[g*F + c] / cn;
    float tv = val[idx] - mean * ms[c];
    t[idx] = tv;
    atomicAdd(&gvar[g*F + c], tv*tv);
}

// out = relu(w * t / sqrt(var + eps) + b)
__global__ void k_gn_final(const float* __restrict__ t, const float* __restrict__ gvar,
                           const float* __restrict__ cnt, const float* __restrict__ w,
                           const float* __restrict__ b, const int* __restrict__ batch,
                           float* __restrict__ out, int F){
    int idx = blockIdx.x*blockDim.x + threadIdx.x;
    if (idx >= NN*F) return;
    int n = idx / F, c = idx - n*F, g = batch[n];
    float cn = fmaxf(cnt[g], 1.0f);
    float var = gvar[g*F + c] / cn;
    float o = w[c] * t[idx] / sqrtf(var + EPSV) + b[c];
    out[idx] = fmaxf(o, 0.f);
}

__global__ void k_pool(const float* __restrict__ h3, const int* __restrict__ batch,
                       float* __restrict__ featsum){
    int idx = blockIdx.x*blockDim.x + threadIdx.x;
    if (idx >= NN*8) return;
    int n = idx >> 3, c = idx & 7;
    atomicAdd(&featsum[batch[n]*8 + c], h3[idx]);
}

__global__ void k_features(const float* __restrict__ featsum, const float* __restrict__ cnt,
                           float* __restrict__ outFeat){
    int idx = blockIdx.x*blockDim.x + threadIdx.x;
    if (idx >= GG*8) return;
    int g = idx >> 3;
    outFeat[idx] = featsum[idx] / fmaxf(cnt[g], 1.0f);
}

__global__ void k_logits(const float* __restrict__ feat, const float* __restrict__ lw,
                         const float* __restrict__ lb, float* __restrict__ outLog){
    int idx = blockIdx.x*blockDim.x + threadIdx.x;
    if (idx >= GG*4) return;
    int g = idx >> 2, j = idx & 3;
    float a = lb[j];
    for (int c = 0; c < 8; ++c) a += feat[g*8 + c] * lw[c*4 + j];
    outLog[idx] = a;
}

static inline unsigned int gridFor(long n, int b){ return (unsigned int)((n + b - 1)/b); }

extern "C" void kernel_launch(void* const* d_in, const int* in_sizes, int n_in,
                              void* d_out, int out_size, void* d_ws, size_t ws_size,
                              hipStream_t stream) {
    const float* x     = (const float*)d_in[0];
    const int*   ei    = (const int*)  d_in[1];
    const int*   batch = (const int*)  d_in[2];
    const float* W1l = (const float*)d_in[3];  const float* b1l = (const float*)d_in[4];
    const float* W1r = (const float*)d_in[5];  const float* b1r = (const float*)d_in[6];
    const float* att1= (const float*)d_in[7];  const float* bias1=(const float*)d_in[8];
    const float* g1w = (const float*)d_in[9];  const float* g1b = (const float*)d_in[10];
    const float* g1m = (const float*)d_in[11];
    const float* W2l = (const float*)d_in[12]; const float* b2l = (const float*)d_in[13];
    const float* W2r = (const float*)d_in[14]; const float* b2r = (const float*)d_in[15];
    const float* att2= (const float*)d_in[16]; const float* bias2=(const float*)d_in[17];
    const float* g2w = (const float*)d_in[18]; const float* g2b = (const float*)d_in[19];
    const float* g2m = (const float*)d_in[20];
    const float* W3l = (const float*)d_in[21]; const float* b3l = (const float*)d_in[22];
    const float* W3r = (const float*)d_in[23]; const float* b3r = (const float*)d_in[24];
    const float* att3= (const float*)d_in[25]; const float* bias3=(const float*)d_in[26];
    const float* g3w = (const float*)d_in[27]; const float* g3b = (const float*)d_in[28];
    const float* g3m = (const float*)d_in[29];
    const float* lin_w=(const float*)d_in[30]; const float* lin_b=(const float*)d_in[31];

    const int* esrc = ei;
    const int* edst = ei + EE;

    float* ws = (float*)d_ws;
    // arena layout (floats), all offsets 256B-aligned
    float*        cnt     = ws;                      // 64
    float*        featsum = ws + 64;                 // 512
    float*        gsum    = ws + 576;                // 16384 (max G*256)
    float*        gvar    = ws + 16960;              // 16384
    float*        S       = ws + 33344;              // 160000 (N*H)
    unsigned int* M       = (unsigned int*)(ws + 193344); // 160000
    float*        P       = ws + 353344;             // 2720000 (E'*H)
    float*        A       = ws + 3073344;            // 5120000 (N*256)
    float*        B       = ws + 8193344;            // 5120000
    float*        Cb      = ws + 13313344;           // 5120000
    float*        D       = ws + 18433344;           // 5120000
    // total = 23,553,344 floats = ~94.2 MB

    const int TB = 256;

    hipMemsetAsync(cnt, 0, GG*sizeof(float), stream);
    hipMemsetAsync(featsum, 0, GG*8*sizeof(float), stream);
    k_count<<<gridFor(NN, TB), TB, 0, stream>>>(batch, cnt);

    struct LayerP {
        const float* hin; int K, C, HC, F; bool concat;
        const float *Wl, *bl, *Wr, *br, *att, *bias, *gw, *gb, *gms;
    };
    LayerP layers[3] = {
        { x, 19, 32, 256, 256, true,  W1l,b1l,W1r,b1r,att1,bias1,g1w,g1b,g1m },
        { A, 256,16, 128, 128, true,  W2l,b2l,W2r,b2r,att2,bias2,g2w,g2b,g2m },
        { A, 128, 8,  64,   8, false, W3l,b3l,W3r,b3r,att3,bias3,g3w,g3b,g3m },
    };

    for (int l = 0; l < 3; ++l){
        const LayerP& L = layers[l];
        hipMemsetAsync(M, 0, (size_t)NN*HH*sizeof(unsigned int), stream);  // key(0)=sentinel below all real keys w/ self-loops present
        hipMemsetAsync(S, 0, (size_t)NN*HH*sizeof(float), stream);
        hipMemsetAsync(D, 0, (size_t)NN*L.HC*sizeof(float), stream);
        hipMemsetAsync(gsum, 0, (size_t)GG*L.F*sizeof(float), stream);
        hipMemsetAsync(gvar, 0, (size_t)GG*L.F*sizeof(float), stream);

        k_gemm_dual<<<gridFor((long)NN*L.HC, TB), TB, 0, stream>>>(
            L.hin, L.Wl, L.bl, L.Wr, L.br, B, Cb, L.K, L.HC);
        k_edge_attn<<<gridFor((long)EPE*HH, TB), TB, 0, stream>>>(
            esrc, edst, B, Cb, L.att, P, M, L.C, L.HC);
        k_edge_aggr<<<gridFor((long)EPE*HH, TB), TB, 0, stream>>>(
            esrc, edst, B, P, M, S, D, L.C, L.HC);
        if (L.concat)
            k_epilogue<<<gridFor((long)NN*L.HC, TB), TB, 0, stream>>>(
                D, S, L.bias, batch, B, gsum, L.C, L.HC);
        else
            k_epilogue_mean<<<gridFor((long)NN*8, TB), TB, 0, stream>>>(
                D, S, L.bias, batch, B, gsum);
        k_gn_center<<<gridFor((long)NN*L.F, TB), TB, 0, stream>>>(
            B, gsum, cnt, L.gms, batch, Cb, gvar, L.F);
        k_gn_final<<<gridFor((long)NN*L.F, TB), TB, 0, stream>>>(
            Cb, gvar, cnt, L.gw, L.gb, batch, A, L.F);
    }

    float* outLog  = (float*)d_out;        // [G,4] = 256
    float* outFeat = outLog + GG*4;        // [G,8] = 512

    k_pool<<<gridFor((long)NN*8, TB), TB, 0, stream>>>(A, batch, featsum);
    k_features<<<gridFor(GG*8, TB), TB, 0, stream>>>(featsum, cnt, outFeat);
    k_logits<<<gridFor(GG*4, TB), TB, 0, stream>>>(outFeat, lin_w, lin_b, outLog);
}

// Round 2
// 1118.315 us; speedup vs baseline: 7.8521x; 7.8521x over previous
//
#include <hip/hip_runtime.h>
#include <math.h>

#define NN 20000
#define EE 320000
#define GG 64
#define HH 8
#define EPSV 1e-5f

static inline unsigned int gridFor(long n, int b){ return (unsigned int)((n + b - 1)/b); }

// ---------------- CSR build ----------------
__global__ void k_deg(const int* __restrict__ edst, int* __restrict__ deg){
    int e = blockIdx.x*blockDim.x + threadIdx.x;
    if (e < EE) atomicAdd(&deg[edst[e]], 1);
}

// single-block exclusive scan over NN degrees -> indptr[NN+1]
__global__ void k_scan(const int* __restrict__ deg, int* __restrict__ indptr){
    __shared__ int partial[1024];
    const int CH = (NN + 1023)/1024;   // 20
    int t = threadIdx.x;
    int base = t*CH;
    int vals[CH];
    int sum = 0;
    for (int i = 0; i < CH; ++i){
        int v = (base+i < NN) ? deg[base+i] : 0;
        vals[i] = sum; sum += v;
    }
    partial[t] = sum;
    __syncthreads();
    for (int off = 1; off < 1024; off <<= 1){
        int v = (t >= off) ? partial[t-off] : 0;
        __syncthreads();
        partial[t] += v;
        __syncthreads();
    }
    int prefix = (t > 0) ? partial[t-1] : 0;
    for (int i = 0; i < CH; ++i)
        if (base+i < NN) indptr[base+i] = prefix + vals[i];
    if (t == 1023) indptr[NN] = prefix + sum;
}

__global__ void k_scatter(const int* __restrict__ esrc, const int* __restrict__ edst,
                          const int* __restrict__ indptr, int* __restrict__ cursor,
                          int* __restrict__ srclist){
    int e = blockIdx.x*blockDim.x + threadIdx.x;
    if (e >= EE) return;
    int d = edst[e];
    int pos = atomicAdd(&cursor[d], 1);
    srclist[indptr[d] + pos] = esrc[e];
}

// per-graph contiguous node ranges (batch is sorted)
__global__ void k_bounds(const int* __restrict__ batch, int* __restrict__ gstart, int* __restrict__ gend){
    int i = blockIdx.x*blockDim.x + threadIdx.x;
    if (i >= NN) return;
    int b = batch[i];
    atomicMin(&gstart[b], i);
    atomicMax(&gend[b], i+1);
}

// ---------------- dense linear: xl = h@Wl+bl ; xr = h@Wr+br ----------------
__global__ void k_gemm_dual(const float* __restrict__ h,
                            const float* __restrict__ Wl, const float* __restrict__ bl,
                            const float* __restrict__ Wr, const float* __restrict__ br,
                            float* __restrict__ xl, float* __restrict__ xr,
                            int K, int HC){
    int idx = blockIdx.x*blockDim.x + threadIdx.x;
    if (idx >= NN*HC) return;
    int row = idx / HC, col = idx - row*HC;
    const float* hr = h + (long)row*K;
    float al = 0.f, ar = 0.f;
    for (int k = 0; k < K; ++k){
        float hv = hr[k];
        al += hv * Wl[k*HC + col];
        ar += hv * Wr[k*HC + col];
    }
    xl[idx] = al + bl[col];
    xr[idx] = ar + br[col];
}

// ---------------- fused GATv2: logits + online softmax + aggregate ----------------
template<int C>
__device__ __forceinline__ float headReduce(float v){
    #pragma unroll
    for (int m = 1; m < C; m <<= 1) v += __shfl_xor(v, m, C);
    return v;
}

template<int C, bool MEAN>
__global__ void k_gat(const int* __restrict__ indptr, const int* __restrict__ srclist,
                      const float* __restrict__ xl, const float* __restrict__ xr,
                      const float* __restrict__ att, const float* __restrict__ bias,
                      float* __restrict__ val){
    constexpr int HC = 8*C;
    int d = blockIdx.x;
    int t = threadIdx.x;
    float xr_d = xr[(long)d*HC + t];
    float at   = att[t];

    // self loop first (always present)
    float xls = xl[(long)d*HC + t];
    float tm = xls + xr_d; tm = tm > 0.f ? tm : 0.2f*tm; tm *= at;
    float m = headReduce<C>(tm);
    float l = 1.0f;
    float o = xls;

    int beg = indptr[d], end = indptr[d+1];
    float xvNext = 0.f;
    if (beg < end){
        int s0 = srclist[beg];
        xvNext = xl[(long)s0*HC + t];
    }
    for (int j = beg; j < end; ++j){
        float xv = xvNext;
        if (j+1 < end){
            int s2 = srclist[j+1];
            xvNext = xl[(long)s2*HC + t];
        }
        float q = xv + xr_d; q = q > 0.f ? q : 0.2f*q; q *= at;
        float a2 = headReduce<C>(q);
        float nm = fmaxf(m, a2);
        float sc = expf(m - nm);
        float p  = expf(a2 - nm);
        l = l*sc + p;
        o = o*sc + p*xv;
        m = nm;
    }
    float r = o / l;
    if (!MEAN){
        val[(long)d*HC + t] = r + bias[t];
    } else {
        // C==8: one wave; sum over heads (lane stride 8)
        r += __shfl_xor(r, 8, 64);
        r += __shfl_xor(r, 16, 64);
        r += __shfl_xor(r, 32, 64);
        if (t < 8) val[(long)d*8 + t] = r*0.125f + bias[t];
    }
}

// ---------------- GraphNorm: per-graph stats (contiguous ranges, no atomics) ----------------
template<int F, int R>   // block = F*R threads; if R>1 then F*R must be <= 64 (single wave)
__global__ void k_gn_stats(const float* __restrict__ val,
                           const int* __restrict__ gstart, const int* __restrict__ gend,
                           const float* __restrict__ ms,
                           float* __restrict__ gmu, float* __restrict__ ginv){
    int g = blockIdx.x;
    int t = threadIdx.x;
    int c = t % F, r = t / F;
    int s = gstart[g], e = gend[g];
    float sum = 0.f, sq = 0.f;
    for (int i = s + r; i < e; i += R){
        float v = val[(long)i*F + c];
        sum += v; sq += v*v;
    }
    if (R > 1){
        #pragma unroll
        for (int mask = F; mask < F*R; mask <<= 1){
            sum += __shfl_xor(sum, mask, 64);
            sq  += __shfl_xor(sq,  mask, 64);
        }
    }
    if (r == 0){
        int cnti = e - s; if (cnti < 0) cnti = 0;
        float cn = cnti > 0 ? (float)cnti : 1.f;
        float mean = sum / cn;
        float mu = mean * ms[c];
        float var = sq/cn - 2.f*mu*mean + mu*mu;
        gmu[g*F + c]  = mu;
        ginv[g*F + c] = rsqrtf(var + EPSV);
    }
}

__global__ void k_gn_apply(const float* __restrict__ val,
                           const float* __restrict__ gmu, const float* __restrict__ ginv,
                           const float* __restrict__ w, const float* __restrict__ b,
                           const int* __restrict__ batch, float* __restrict__ out, int F){
    int idx = blockIdx.x*blockDim.x + threadIdx.x;
    if (idx >= NN*F) return;
    int n = idx / F, c = idx - n*F, g = batch[n];
    float v = (val[idx] - gmu[g*F + c]) * ginv[g*F + c] * w[c] + b[c];
    out[idx] = fmaxf(v, 0.f);
}

// ---------------- pool + head ----------------
__global__ void k_pool(const float* __restrict__ h,
                       const int* __restrict__ gstart, const int* __restrict__ gend,
                       float* __restrict__ outFeat){
    int g = blockIdx.x;
    int t = threadIdx.x;          // 64 threads: c = t&7, r = t>>3
    int c = t & 7, r = t >> 3;
    int s = gstart[g], e = gend[g];
    float sum = 0.f;
    for (int i = s + r; i < e; i += 8) sum += h[(long)i*8 + c];
    sum += __shfl_xor(sum, 8, 64);
    sum += __shfl_xor(sum, 16, 64);
    sum += __shfl_xor(sum, 32, 64);
    if (t < 8){
        int cnti = e - s;
        float cn = cnti > 0 ? (float)cnti : 1.f;
        outFeat[g*8 + t] = sum / cn;
    }
}

__global__ void k_logits(const float* __restrict__ feat, const float* __restrict__ lw,
                         const float* __restrict__ lb, float* __restrict__ outLog){
    int idx = blockIdx.x*blockDim.x + threadIdx.x;
    if (idx >= GG*4) return;
    int g = idx >> 2, j = idx & 3;
    float a = lb[j];
    for (int c = 0; c < 8; ++c) a += feat[g*8 + c] * lw[c*4 + j];
    outLog[idx] = a;
}

extern "C" void kernel_launch(void* const* d_in, const int* in_sizes, int n_in,
                              void* d_out, int out_size, void* d_ws, size_t ws_size,
                              hipStream_t stream) {
    const float* x     = (const float*)d_in[0];
    const int*   ei    = (const int*)  d_in[1];
    const int*   batch = (const int*)  d_in[2];
    const float* W1l = (const float*)d_in[3];  const float* b1l = (const float*)d_in[4];
    const float* W1r = (const float*)d_in[5];  const float* b1r = (const float*)d_in[6];
    const float* att1= (const float*)d_in[7];  const float* bias1=(const float*)d_in[8];
    const float* g1w = (const float*)d_in[9];  const float* g1b = (const float*)d_in[10];
    const float* g1m = (const float*)d_in[11];
    const float* W2l = (const float*)d_in[12]; const float* b2l = (const float*)d_in[13];
    const float* W2r = (const float*)d_in[14]; const float* b2r = (const float*)d_in[15];
    const float* att2= (const float*)d_in[16]; const float* bias2=(const float*)d_in[17];
    const float* g2w = (const float*)d_in[18]; const float* g2b = (const float*)d_in[19];
    const float* g2m = (const float*)d_in[20];
    const float* W3l = (const float*)d_in[21]; const float* b3l = (const float*)d_in[22];
    const float* W3r = (const float*)d_in[23]; const float* b3r = (const float*)d_in[24];
    const float* att3= (const float*)d_in[25]; const float* bias3=(const float*)d_in[26];
    const float* g3w = (const float*)d_in[27]; const float* g3b = (const float*)d_in[28];
    const float* g3m = (const float*)d_in[29];
    const float* lin_w=(const float*)d_in[30]; const float* lin_b=(const float*)d_in[31];

    const int* esrc = ei;
    const int* edst = ei + EE;

    // ---- workspace arena (units of 4B) ----
    float* ws = (float*)d_ws;
    int*   cursor  = (int*)(ws + 0);         // 20480
    int*   indptr  = (int*)(ws + 20480);     // 20480 (NN+1 used)
    int*   srclist = (int*)(ws + 40960);     // 320512
    int*   gstart  = (int*)(ws + 361472);    // 512
    int*   gend    = (int*)(ws + 361984);    // 512
    float* gmu     = ws + 362496;            // 16384
    float* ginv    = ws + 378880;            // 16384
    float* A  = ws + 395264;                 // 5,120,000  (layer activations)
    float* B  = ws + 5515264;                // 5,120,000  (xl)
    float* Cb = ws + 10635264;               // 5,120,000  (xr)
    float* D  = ws + 15755264;               // 5,120,000  (pre-norm GAT out)

    const int TB = 256;

    // CSR + graph bounds (rebuilt every call; ws is poisoned between calls)
    hipMemsetAsync(cursor, 0, NN*sizeof(int), stream);
    hipMemsetAsync(gstart, 0x7f, GG*sizeof(int), stream);
    hipMemsetAsync(gend, 0, GG*sizeof(int), stream);
    k_deg<<<gridFor(EE, TB), TB, 0, stream>>>(edst, cursor);
    k_scan<<<1, 1024, 0, stream>>>(cursor, indptr);
    hipMemsetAsync(cursor, 0, NN*sizeof(int), stream);
    k_scatter<<<gridFor(EE, TB), TB, 0, stream>>>(esrc, edst, indptr, cursor, srclist);
    k_bounds<<<gridFor(NN, TB), TB, 0, stream>>>(batch, gstart, gend);

    // ---- layer 1: 19 -> 256 (concat) ----
    k_gemm_dual<<<gridFor((long)NN*256, TB), TB, 0, stream>>>(x,  W1l, b1l, W1r, b1r, B, Cb, 19, 256);
    k_gat<32, false><<<NN, 256, 0, stream>>>(indptr, srclist, B, Cb, att1, bias1, D);
    k_gn_stats<256,1><<<GG, 256, 0, stream>>>(D, gstart, gend, g1m, gmu, ginv);
    k_gn_apply<<<gridFor((long)NN*256, TB), TB, 0, stream>>>(D, gmu, ginv, g1w, g1b, batch, A, 256);

    // ---- layer 2: 256 -> 128 (concat) ----
    k_gemm_dual<<<gridFor((long)NN*128, TB), TB, 0, stream>>>(A, W2l, b2l, W2r, b2r, B, Cb, 256, 128);
    k_gat<16, false><<<NN, 128, 0, stream>>>(indptr, srclist, B, Cb, att2, bias2, D);
    k_gn_stats<128,1><<<GG, 128, 0, stream>>>(D, gstart, gend, g2m, gmu, ginv);
    k_gn_apply<<<gridFor((long)NN*128, TB), TB, 0, stream>>>(D, gmu, ginv, g2w, g2b, batch, A, 128);

    // ---- layer 3: 128 -> 64 (head mean -> 8) ----
    k_gemm_dual<<<gridFor((long)NN*64, TB), TB, 0, stream>>>(A, W3l, b3l, W3r, b3r, B, Cb, 128, 64);
    k_gat<8, true><<<NN, 64, 0, stream>>>(indptr, srclist, B, Cb, att3, bias3, D);
    k_gn_stats<8,8><<<GG, 64, 0, stream>>>(D, gstart, gend, g3m, gmu, ginv);
    k_gn_apply<<<gridFor((long)NN*8, TB), TB, 0, stream>>>(D, gmu, ginv, g3w, g3b, batch, A, 8);

    // ---- pool + head ----
    float* outLog  = (float*)d_out;        // [G,4]
    float* outFeat = outLog + GG*4;        // [G,8]
    k_pool<<<GG, 64, 0, stream>>>(A, gstart, gend, outFeat);
    k_logits<<<1, 256, 0, stream>>>(outFeat, lin_w, lin_b, outLog);
}

// Round 3
// 809.074 us; speedup vs baseline: 10.8533x; 1.3822x over previous
//
#include <hip/hip_runtime.h>
#include <math.h>

#define NN 20000
#define EE 320000
#define GG 64
#define HH 8
#define EPSV 1e-5f

static inline unsigned int gridFor(long n, int b){ return (unsigned int)((n + b - 1)/b); }

// ---------------- CSR build ----------------
__global__ void k_deg(const int* __restrict__ edst, int* __restrict__ deg){
    int e = blockIdx.x*blockDim.x + threadIdx.x;
    if (e < EE) atomicAdd(&deg[edst[e]], 1);
}

// single-block exclusive scan over NN degrees -> indptr[NN+1]
__global__ void k_scan(const int* __restrict__ deg, int* __restrict__ indptr){
    __shared__ int partial[1024];
    const int CH = (NN + 1023)/1024;   // 20
    int t = threadIdx.x;
    int base = t*CH;
    int vals[CH];
    int sum = 0;
    for (int i = 0; i < CH; ++i){
        int v = (base+i < NN) ? deg[base+i] : 0;
        vals[i] = sum; sum += v;
    }
    partial[t] = sum;
    __syncthreads();
    for (int off = 1; off < 1024; off <<= 1){
        int v = (t >= off) ? partial[t-off] : 0;
        __syncthreads();
        partial[t] += v;
        __syncthreads();
    }
    int prefix = (t > 0) ? partial[t-1] : 0;
    for (int i = 0; i < CH; ++i)
        if (base+i < NN) indptr[base+i] = prefix + vals[i];
    if (t == 1023) indptr[NN] = prefix + sum;
}

__global__ void k_scatter(const int* __restrict__ esrc, const int* __restrict__ edst,
                          const int* __restrict__ indptr, int* __restrict__ cursor,
                          int* __restrict__ srclist){
    int e = blockIdx.x*blockDim.x + threadIdx.x;
    if (e >= EE) return;
    int d = edst[e];
    int pos = atomicAdd(&cursor[d], 1);
    srclist[indptr[d] + pos] = esrc[e];
}

// per-graph contiguous node ranges (batch is sorted)
__global__ void k_bounds(const int* __restrict__ batch, int* __restrict__ gstart, int* __restrict__ gend){
    int i = blockIdx.x*blockDim.x + threadIdx.x;
    if (i >= NN) return;
    int b = batch[i];
    atomicMin(&gstart[b], i);
    atomicMax(&gend[b], i+1);
}

// ---------------- tiled dual linear: [xl | xr] = h @ [Wl | Wr] + [bl | br] ----------------
// 64x64 output tile, BK=16, 256 threads, 4x4 register micro-tile.
// Column block is entirely within xl (n0 < HC) or xr (n0 >= HC) since HC % 64 == 0.
__global__ __launch_bounds__(256)
void k_gemm_tiled(const float* __restrict__ h,
                  const float* __restrict__ Wl, const float* __restrict__ bl,
                  const float* __restrict__ Wr, const float* __restrict__ br,
                  float* __restrict__ xl, float* __restrict__ xr,
                  int K, int HC){
    __shared__ float As[16][68];   // [kk][mm], pad 68: bank = (4kk+mm)%32 -> <=2-way (free)
    __shared__ float Bs[16][68];   // [kk][nn]
    const int tid = threadIdx.x;
    const int m0 = blockIdx.x * 64;
    const int n0 = blockIdx.y * 64;
    const int tx = tid & 15, ty = tid >> 4;

    const bool right = (n0 >= HC);
    const float* W  = right ? Wr : Wl;
    const float* bv = right ? br : bl;
    const int nbase = right ? (n0 - HC) : n0;

    float acc[4][4] = {};

    for (int k0 = 0; k0 < K; k0 += 16){
        // stage A: 64 rows x 16 k (coalesced: 16 consecutive k per 16 lanes)
        #pragma unroll
        for (int i = 0; i < 4; ++i){
            int idx = i*256 + tid;
            int kk = idx & 15, mm = idx >> 4;
            int gm = m0 + mm, gk = k0 + kk;
            As[kk][mm] = (gm < NN && gk < K) ? h[(long)gm*K + gk] : 0.f;
        }
        // stage B: 16 k x 64 n (coalesced along n)
        #pragma unroll
        for (int i = 0; i < 4; ++i){
            int idx = i*256 + tid;
            int kk = idx >> 6, nn = idx & 63;
            int gk = k0 + kk;
            Bs[kk][nn] = (gk < K) ? W[(long)gk*HC + nbase + nn] : 0.f;
        }
        __syncthreads();
        #pragma unroll
        for (int kk = 0; kk < 16; ++kk){
            float4 a = *(const float4*)&As[kk][ty*4];
            float4 b = *(const float4*)&Bs[kk][tx*4];
            acc[0][0] += a.x*b.x; acc[0][1] += a.x*b.y; acc[0][2] += a.x*b.z; acc[0][3] += a.x*b.w;
            acc[1][0] += a.y*b.x; acc[1][1] += a.y*b.y; acc[1][2] += a.y*b.z; acc[1][3] += a.y*b.w;
            acc[2][0] += a.z*b.x; acc[2][1] += a.z*b.y; acc[2][2] += a.z*b.z; acc[2][3] += a.z*b.w;
            acc[3][0] += a.w*b.x; acc[3][1] += a.w*b.y; acc[3][2] += a.w*b.z; acc[3][3] += a.w*b.w;
        }
        __syncthreads();
    }

    float* X = right ? xr : xl;
    float4 bb = *(const float4*)&bv[nbase + tx*4];
    #pragma unroll
    for (int i = 0; i < 4; ++i){
        int gm = m0 + ty*4 + i;
        if (gm >= NN) break;
        float4 v;
        v.x = acc[i][0] + bb.x; v.y = acc[i][1] + bb.y;
        v.z = acc[i][2] + bb.z; v.w = acc[i][3] + bb.w;
        *(float4*)&X[(long)gm*HC + nbase + tx*4] = v;
    }
}

// ---------------- fused GATv2: logits + online softmax + aggregate ----------------
template<int C>
__device__ __forceinline__ float headReduce(float v){
    #pragma unroll
    for (int m = 1; m < C; m <<= 1) v += __shfl_xor(v, m, C);
    return v;
}

template<int C, bool MEAN>
__global__ void k_gat(const int* __restrict__ indptr, const int* __restrict__ srclist,
                      const float* __restrict__ xl, const float* __restrict__ xr,
                      const float* __restrict__ att, const float* __restrict__ bias,
                      float* __restrict__ val){
    constexpr int HC = 8*C;
    int d = blockIdx.x;
    int t = threadIdx.x;
    float xr_d = xr[(long)d*HC + t];
    float at   = att[t];

    // self loop first (always present)
    float xls = xl[(long)d*HC + t];
    float tm = xls + xr_d; tm = tm > 0.f ? tm : 0.2f*tm; tm *= at;
    float m = headReduce<C>(tm);
    float l = 1.0f;
    float o = xls;

    int beg = indptr[d], end = indptr[d+1];
    float xvNext = 0.f;
    if (beg < end){
        int s0 = srclist[beg];
        xvNext = xl[(long)s0*HC + t];
    }
    for (int j = beg; j < end; ++j){
        float xv = xvNext;
        if (j+1 < end){
            int s2 = srclist[j+1];
            xvNext = xl[(long)s2*HC + t];
        }
        float q = xv + xr_d; q = q > 0.f ? q : 0.2f*q; q *= at;
        float a2 = headReduce<C>(q);
        float nm = fmaxf(m, a2);
        float sc = expf(m - nm);
        float p  = expf(a2 - nm);
        l = l*sc + p;
        o = o*sc + p*xv;
        m = nm;
    }
    float r = o / l;
    if (!MEAN){
        val[(long)d*HC + t] = r + bias[t];
    } else {
        // C==8: one wave; sum over heads (lane stride 8)
        r += __shfl_xor(r, 8, 64);
        r += __shfl_xor(r, 16, 64);
        r += __shfl_xor(r, 32, 64);
        if (t < 8) val[(long)d*8 + t] = r*0.125f + bias[t];
    }
}

// ---------------- GraphNorm: per-graph stats (contiguous ranges, no atomics) ----------------
template<int F, int R>   // block = F*R threads; if R>1 then F*R must be <= 64 (single wave)
__global__ void k_gn_stats(const float* __restrict__ val,
                           const int* __restrict__ gstart, const int* __restrict__ gend,
                           const float* __restrict__ ms,
                           float* __restrict__ gmu, float* __restrict__ ginv){
    int g = blockIdx.x;
    int t = threadIdx.x;
    int c = t % F, r = t / F;
    int s = gstart[g], e = gend[g];
    float sum = 0.f, sq = 0.f;
    for (int i = s + r; i < e; i += R){
        float v = val[(long)i*F + c];
        sum += v; sq += v*v;
    }
    if (R > 1){
        #pragma unroll
        for (int mask = F; mask < F*R; mask <<= 1){
            sum += __shfl_xor(sum, mask, 64);
            sq  += __shfl_xor(sq,  mask, 64);
        }
    }
    if (r == 0){
        int cnti = e - s; if (cnti < 0) cnti = 0;
        float cn = cnti > 0 ? (float)cnti : 1.f;
        float mean = sum / cn;
        float mu = mean * ms[c];
        float var = sq/cn - 2.f*mu*mean + mu*mu;
        gmu[g*F + c]  = mu;
        ginv[g*F + c] = rsqrtf(var + EPSV);
    }
}

__global__ void k_gn_apply(const float* __restrict__ val,
                           const float* __restrict__ gmu, const float* __restrict__ ginv,
                           const float* __restrict__ w, const float* __restrict__ b,
                           const int* __restrict__ batch, float* __restrict__ out, int F){
    int idx = blockIdx.x*blockDim.x + threadIdx.x;
    if (idx >= NN*F) return;
    int n = idx / F, c = idx - n*F, g = batch[n];
    float v = (val[idx] - gmu[g*F + c]) * ginv[g*F + c] * w[c] + b[c];
    out[idx] = fmaxf(v, 0.f);
}

// ---------------- pool + head ----------------
__global__ void k_pool(const float* __restrict__ h,
                       const int* __restrict__ gstart, const int* __restrict__ gend,
                       float* __restrict__ outFeat){
    int g = blockIdx.x;
    int t = threadIdx.x;          // 64 threads: c = t&7, r = t>>3
    int c = t & 7, r = t >> 3;
    int s = gstart[g], e = gend[g];
    float sum = 0.f;
    for (int i = s + r; i < e; i += 8) sum += h[(long)i*8 + c];
    sum += __shfl_xor(sum, 8, 64);
    sum += __shfl_xor(sum, 16, 64);
    sum += __shfl_xor(sum, 32, 64);
    if (t < 8){
        int cnti = e - s;
        float cn = cnti > 0 ? (float)cnti : 1.f;
        outFeat[g*8 + t] = sum / cn;
    }
}

__global__ void k_logits(const float* __restrict__ feat, const float* __restrict__ lw,
                         const float* __restrict__ lb, float* __restrict__ outLog){
    int idx = blockIdx.x*blockDim.x + threadIdx.x;
    if (idx >= GG*4) return;
    int g = idx >> 2, j = idx & 3;
    float a = lb[j];
    for (int c = 0; c < 8; ++c) a += feat[g*8 + c] * lw[c*4 + j];
    outLog[idx] = a;
}

extern "C" void kernel_launch(void* const* d_in, const int* in_sizes, int n_in,
                              void* d_out, int out_size, void* d_ws, size_t ws_size,
                              hipStream_t stream) {
    const float* x     = (const float*)d_in[0];
    const int*   ei    = (const int*)  d_in[1];
    const int*   batch = (const int*)  d_in[2];
    const float* W1l = (const float*)d_in[3];  const float* b1l = (const float*)d_in[4];
    const float* W1r = (const float*)d_in[5];  const float* b1r = (const float*)d_in[6];
    const float* att1= (const float*)d_in[7];  const float* bias1=(const float*)d_in[8];
    const float* g1w = (const float*)d_in[9];  const float* g1b = (const float*)d_in[10];
    const float* g1m = (const float*)d_in[11];
    const float* W2l = (const float*)d_in[12]; const float* b2l = (const float*)d_in[13];
    const float* W2r = (const float*)d_in[14]; const float* b2r = (const float*)d_in[15];
    const float* att2= (const float*)d_in[16]; const float* bias2=(const float*)d_in[17];
    const float* g2w = (const float*)d_in[18]; const float* g2b = (const float*)d_in[19];
    const float* g2m = (const float*)d_in[20];
    const float* W3l = (const float*)d_in[21]; const float* b3l = (const float*)d_in[22];
    const float* W3r = (const float*)d_in[23]; const float* b3r = (const float*)d_in[24];
    const float* att3= (const float*)d_in[25]; const float* bias3=(const float*)d_in[26];
    const float* g3w = (const float*)d_in[27]; const float* g3b = (const float*)d_in[28];
    const float* g3m = (const float*)d_in[29];
    const float* lin_w=(const float*)d_in[30]; const float* lin_b=(const float*)d_in[31];

    const int* esrc = ei;
    const int* edst = ei + EE;

    // ---- workspace arena (units of 4B) ----
    float* ws = (float*)d_ws;
    int*   cursor  = (int*)(ws + 0);         // 20480
    int*   indptr  = (int*)(ws + 20480);     // 20480 (NN+1 used)
    int*   srclist = (int*)(ws + 40960);     // 320512
    int*   gstart  = (int*)(ws + 361472);    // 512
    int*   gend    = (int*)(ws + 361984);    // 512
    float* gmu     = ws + 362496;            // 16384
    float* ginv    = ws + 378880;            // 16384
    float* A  = ws + 395264;                 // 5,120,000  (layer activations)
    float* B  = ws + 5515264;                // 5,120,000  (xl)
    float* Cb = ws + 10635264;               // 5,120,000  (xr)
    float* D  = ws + 15755264;               // 5,120,000  (pre-norm GAT out)

    const int TB = 256;
    const int MB = (NN + 63)/64;  // 313 row-tiles

    // CSR + graph bounds (rebuilt every call; ws is poisoned between calls)
    hipMemsetAsync(cursor, 0, NN*sizeof(int), stream);
    hipMemsetAsync(gstart, 0x7f, GG*sizeof(int), stream);
    hipMemsetAsync(gend, 0, GG*sizeof(int), stream);
    k_deg<<<gridFor(EE, TB), TB, 0, stream>>>(edst, cursor);
    k_scan<<<1, 1024, 0, stream>>>(cursor, indptr);
    hipMemsetAsync(cursor, 0, NN*sizeof(int), stream);
    k_scatter<<<gridFor(EE, TB), TB, 0, stream>>>(esrc, edst, indptr, cursor, srclist);
    k_bounds<<<gridFor(NN, TB), TB, 0, stream>>>(batch, gstart, gend);

    // ---- layer 1: 19 -> 256 (concat) ----
    k_gemm_tiled<<<dim3(MB, 8), 256, 0, stream>>>(x,  W1l, b1l, W1r, b1r, B, Cb, 19, 256);
    k_gat<32, false><<<NN, 256, 0, stream>>>(indptr, srclist, B, Cb, att1, bias1, D);
    k_gn_stats<256,1><<<GG, 256, 0, stream>>>(D, gstart, gend, g1m, gmu, ginv);
    k_gn_apply<<<gridFor((long)NN*256, TB), TB, 0, stream>>>(D, gmu, ginv, g1w, g1b, batch, A, 256);

    // ---- layer 2: 256 -> 128 (concat) ----
    k_gemm_tiled<<<dim3(MB, 4), 256, 0, stream>>>(A, W2l, b2l, W2r, b2r, B, Cb, 256, 128);
    k_gat<16, false><<<NN, 128, 0, stream>>>(indptr, srclist, B, Cb, att2, bias2, D);
    k_gn_stats<128,1><<<GG, 128, 0, stream>>>(D, gstart, gend, g2m, gmu, ginv);
    k_gn_apply<<<gridFor((long)NN*128, TB), TB, 0, stream>>>(D, gmu, ginv, g2w, g2b, batch, A, 128);

    // ---- layer 3: 128 -> 64 (head mean -> 8) ----
    k_gemm_tiled<<<dim3(MB, 2), 256, 0, stream>>>(A, W3l, b3l, W3r, b3r, B, Cb, 128, 64);
    k_gat<8, true><<<NN, 64, 0, stream>>>(indptr, srclist, B, Cb, att3, bias3, D);
    k_gn_stats<8,8><<<GG, 64, 0, stream>>>(D, gstart, gend, g3m, gmu, ginv);
    k_gn_apply<<<gridFor((long)NN*8, TB), TB, 0, stream>>>(D, gmu, ginv, g3w, g3b, batch, A, 8);

    // ---- pool + head ----
    float* outLog  = (float*)d_out;        // [G,4]
    float* outFeat = outLog + GG*4;        // [G,8]
    k_pool<<<GG, 64, 0, stream>>>(A, gstart, gend, outFeat);
    k_logits<<<1, 256, 0, stream>>>(outFeat, lin_w, lin_b, outLog);
}

// Round 4
// 547.744 us; speedup vs baseline: 16.0315x; 1.4771x over previous
//
#include <hip/hip_runtime.h>
#include <math.h>

#define NN 20000
#define EE 320000
#define GG 64
#define HH 8
#define EPSV 1e-5f

static inline unsigned int gridFor(long n, int b){ return (unsigned int)((n + b - 1)/b); }

// ---------------- CSR build ----------------
__global__ void k_deg(const int* __restrict__ edst, int* __restrict__ deg){
    int e = blockIdx.x*blockDim.x + threadIdx.x;
    if (e < EE) atomicAdd(&deg[edst[e]], 1);
}

// single-block exclusive scan over NN degrees -> indptr[NN+1]
__global__ void k_scan(const int* __restrict__ deg, int* __restrict__ indptr){
    __shared__ int partial[1024];
    const int CH = (NN + 1023)/1024;   // 20
    int t = threadIdx.x;
    int base = t*CH;
    int vals[CH];
    int sum = 0;
    for (int i = 0; i < CH; ++i){
        int v = (base+i < NN) ? deg[base+i] : 0;
        vals[i] = sum; sum += v;
    }
    partial[t] = sum;
    __syncthreads();
    for (int off = 1; off < 1024; off <<= 1){
        int v = (t >= off) ? partial[t-off] : 0;
        __syncthreads();
        partial[t] += v;
        __syncthreads();
    }
    int prefix = (t > 0) ? partial[t-1] : 0;
    for (int i = 0; i < CH; ++i)
        if (base+i < NN) indptr[base+i] = prefix + vals[i];
    if (t == 1023) indptr[NN] = prefix + sum;
}

__global__ void k_scatter(const int* __restrict__ esrc, const int* __restrict__ edst,
                          const int* __restrict__ indptr, int* __restrict__ cursor,
                          int* __restrict__ srclist){
    int e = blockIdx.x*blockDim.x + threadIdx.x;
    if (e >= EE) return;
    int d = edst[e];
    int pos = atomicAdd(&cursor[d], 1);
    srclist[indptr[d] + pos] = esrc[e];
}

// batch is sorted: boundary detection, no atomics.
__global__ void k_bounds(const int* __restrict__ batch, int* __restrict__ gstart, int* __restrict__ gend){
    int i = blockIdx.x*blockDim.x + threadIdx.x;
    if (i >= NN) return;
    int b = batch[i];
    if (i == 0 || batch[i-1] != b) gstart[b] = i;
    if (i == NN-1 || batch[i+1] != b) gend[b] = i+1;
}

// ---------------- tiled dual linear: [xl | xr] = h @ [Wl | Wr] + [bl | br] ----------------
__global__ __launch_bounds__(256)
void k_gemm_tiled(const float* __restrict__ h,
                  const float* __restrict__ Wl, const float* __restrict__ bl,
                  const float* __restrict__ Wr, const float* __restrict__ br,
                  float* __restrict__ xl, float* __restrict__ xr,
                  int K, int HC){
    __shared__ float As[16][68];
    __shared__ float Bs[16][68];
    const int tid = threadIdx.x;
    const int m0 = blockIdx.x * 64;
    const int n0 = blockIdx.y * 64;
    const int tx = tid & 15, ty = tid >> 4;

    const bool right = (n0 >= HC);
    const float* W  = right ? Wr : Wl;
    const float* bv = right ? br : bl;
    const int nbase = right ? (n0 - HC) : n0;

    float acc[4][4] = {};

    for (int k0 = 0; k0 < K; k0 += 16){
        #pragma unroll
        for (int i = 0; i < 4; ++i){
            int idx = i*256 + tid;
            int kk = idx & 15, mm = idx >> 4;
            int gm = m0 + mm, gk = k0 + kk;
            As[kk][mm] = (gm < NN && gk < K) ? h[(long)gm*K + gk] : 0.f;
        }
        #pragma unroll
        for (int i = 0; i < 4; ++i){
            int idx = i*256 + tid;
            int kk = idx >> 6, nn = idx & 63;
            int gk = k0 + kk;
            Bs[kk][nn] = (gk < K) ? W[(long)gk*HC + nbase + nn] : 0.f;
        }
        __syncthreads();
        #pragma unroll
        for (int kk = 0; kk < 16; ++kk){
            float4 a = *(const float4*)&As[kk][ty*4];
            float4 b = *(const float4*)&Bs[kk][tx*4];
            acc[0][0] += a.x*b.x; acc[0][1] += a.x*b.y; acc[0][2] += a.x*b.z; acc[0][3] += a.x*b.w;
            acc[1][0] += a.y*b.x; acc[1][1] += a.y*b.y; acc[1][2] += a.y*b.z; acc[1][3] += a.y*b.w;
            acc[2][0] += a.z*b.x; acc[2][1] += a.z*b.y; acc[2][2] += a.z*b.z; acc[2][3] += a.z*b.w;
            acc[3][0] += a.w*b.x; acc[3][1] += a.w*b.y; acc[3][2] += a.w*b.z; acc[3][3] += a.w*b.w;
        }
        __syncthreads();
    }

    float* X = right ? xr : xl;
    float4 bb = *(const float4*)&bv[nbase + tx*4];
    #pragma unroll
    for (int i = 0; i < 4; ++i){
        int gm = m0 + ty*4 + i;
        if (gm >= NN) break;
        float4 v;
        v.x = acc[i][0] + bb.x; v.y = acc[i][1] + bb.y;
        v.z = acc[i][2] + bb.z; v.w = acc[i][3] + bb.w;
        *(float4*)&X[(long)gm*HC + nbase + tx*4] = v;
    }
}

// ---------------- fused GATv2: logits + online softmax + aggregate ----------------
template<int C>
__device__ __forceinline__ float headReduce(float v){
    #pragma unroll
    for (int m = 1; m < C; m <<= 1) v += __shfl_xor(v, m, C);
    return v;
}

template<int C, bool MEAN>
__global__ void k_gat(const int* __restrict__ indptr, const int* __restrict__ srclist,
                      const float* __restrict__ xl, const float* __restrict__ xr,
                      const float* __restrict__ att, const float* __restrict__ bias,
                      float* __restrict__ val){
    constexpr int HC = 8*C;
    int d = blockIdx.x;
    int t = threadIdx.x;
    float xr_d = xr[(long)d*HC + t];
    float at   = att[t];

    float xls = xl[(long)d*HC + t];
    float tm = xls + xr_d; tm = tm > 0.f ? tm : 0.2f*tm; tm *= at;
    float m = headReduce<C>(tm);
    float l = 1.0f;
    float o = xls;

    int beg = indptr[d], end = indptr[d+1];
    float xvNext = 0.f;
    if (beg < end){
        int s0 = srclist[beg];
        xvNext = xl[(long)s0*HC + t];
    }
    for (int j = beg; j < end; ++j){
        float xv = xvNext;
        if (j+1 < end){
            int s2 = srclist[j+1];
            xvNext = xl[(long)s2*HC + t];
        }
        float q = xv + xr_d; q = q > 0.f ? q : 0.2f*q; q *= at;
        float a2 = headReduce<C>(q);
        float nm = fmaxf(m, a2);
        float sc = expf(m - nm);
        float p  = expf(a2 - nm);
        l = l*sc + p;
        o = o*sc + p*xv;
        m = nm;
    }
    float r = o / l;
    if (!MEAN){
        val[(long)d*HC + t] = r + bias[t];
    } else {
        r += __shfl_xor(r, 8, 64);
        r += __shfl_xor(r, 16, 64);
        r += __shfl_xor(r, 32, 64);
        if (t < 8) val[(long)d*8 + t] = r*0.125f + bias[t];
    }
}

// ---------------- GraphNorm stats, phase 1: chunked partial sums ----------------
// grid (GG, NCH), block = F threads. Rows strided by NCH within [gstart, gend).
template<int F>
__global__ void k_gn_partial(const float* __restrict__ val,
                             const int* __restrict__ gstart, const int* __restrict__ gend,
                             float* __restrict__ gsum, float* __restrict__ gsq){
    int g = blockIdx.x, ch = blockIdx.y, nch = gridDim.y;
    int c = threadIdx.x;
    int s = gstart[g], e = gend[g];
    float sum = 0.f, sq = 0.f;
    for (int i = s + ch; i < e; i += nch){
        float v = val[(long)i*F + c];
        sum += v; sq += v*v;
    }
    if (sum != 0.f || sq != 0.f){
        atomicAdd(&gsum[g*F + c], sum);
        atomicAdd(&gsq[g*F + c], sq);
    }
}

// phase 2: finalize mu / inv-sigma per (graph, channel)
__global__ void k_gn_finalize(const float* __restrict__ gsum, const float* __restrict__ gsq,
                              const int* __restrict__ gstart, const int* __restrict__ gend,
                              const float* __restrict__ ms,
                              float* __restrict__ gmu, float* __restrict__ ginv, int F){
    int idx = blockIdx.x*blockDim.x + threadIdx.x;
    if (idx >= GG*F) return;
    int g = idx / F, c = idx - g*F;
    int cnti = gend[g] - gstart[g];
    float cn = cnti > 0 ? (float)cnti : 1.f;
    float mean = gsum[idx] / cn;
    float mu = mean * ms[c];
    float var = gsq[idx]/cn - 2.f*mu*mean + mu*mu;
    gmu[idx]  = mu;
    ginv[idx] = rsqrtf(var + EPSV);
}

// single-wave stats for F=8 (layer 3)
__global__ void k_gn_stats8(const float* __restrict__ val,
                            const int* __restrict__ gstart, const int* __restrict__ gend,
                            const float* __restrict__ ms,
                            float* __restrict__ gmu, float* __restrict__ ginv){
    const int F = 8;
    int g = blockIdx.x;
    int t = threadIdx.x;
    int c = t % F, r = t / F;
    int s = gstart[g], e = gend[g];
    float sum = 0.f, sq = 0.f;
    for (int i = s + r; i < e; i += 8){
        float v = val[(long)i*F + c];
        sum += v; sq += v*v;
    }
    #pragma unroll
    for (int mask = 8; mask < 64; mask <<= 1){
        sum += __shfl_xor(sum, mask, 64);
        sq  += __shfl_xor(sq,  mask, 64);
    }
    if (r == 0){
        int cnti = e - s;
        float cn = cnti > 0 ? (float)cnti : 1.f;
        float mean = sum / cn;
        float mu = mean * ms[c];
        float var = sq/cn - 2.f*mu*mean + mu*mu;
        gmu[g*F + c]  = mu;
        ginv[g*F + c] = rsqrtf(var + EPSV);
    }
}

__global__ void k_gn_apply(const float* __restrict__ val,
                           const float* __restrict__ gmu, const float* __restrict__ ginv,
                           const float* __restrict__ w, const float* __restrict__ b,
                           const int* __restrict__ batch, float* __restrict__ out, int F){
    int idx = blockIdx.x*blockDim.x + threadIdx.x;
    if (idx >= NN*F) return;
    int n = idx / F, c = idx - n*F, g = batch[n];
    float v = (val[idx] - gmu[g*F + c]) * ginv[g*F + c] * w[c] + b[c];
    out[idx] = fmaxf(v, 0.f);
}

// ---------------- pool + head ----------------
__global__ void k_pool(const float* __restrict__ h,
                       const int* __restrict__ gstart, const int* __restrict__ gend,
                       float* __restrict__ outFeat){
    int g = blockIdx.x;
    int t = threadIdx.x;
    int c = t & 7, r = t >> 3;
    int s = gstart[g], e = gend[g];
    float sum = 0.f;
    for (int i = s + r; i < e; i += 8) sum += h[(long)i*8 + c];
    sum += __shfl_xor(sum, 8, 64);
    sum += __shfl_xor(sum, 16, 64);
    sum += __shfl_xor(sum, 32, 64);
    if (t < 8){
        int cnti = e - s;
        float cn = cnti > 0 ? (float)cnti : 1.f;
        outFeat[g*8 + t] = sum / cn;
    }
}

__global__ void k_logits(const float* __restrict__ feat, const float* __restrict__ lw,
                         const float* __restrict__ lb, float* __restrict__ outLog){
    int idx = blockIdx.x*blockDim.x + threadIdx.x;
    if (idx >= GG*4) return;
    int g = idx >> 2, j = idx & 3;
    float a = lb[j];
    for (int c = 0; c < 8; ++c) a += feat[g*8 + c] * lw[c*4 + j];
    outLog[idx] = a;
}

extern "C" void kernel_launch(void* const* d_in, const int* in_sizes, int n_in,
                              void* d_out, int out_size, void* d_ws, size_t ws_size,
                              hipStream_t stream) {
    const float* x     = (const float*)d_in[0];
    const int*   ei    = (const int*)  d_in[1];
    const int*   batch = (const int*)  d_in[2];
    const float* W1l = (const float*)d_in[3];  const float* b1l = (const float*)d_in[4];
    const float* W1r = (const float*)d_in[5];  const float* b1r = (const float*)d_in[6];
    const float* att1= (const float*)d_in[7];  const float* bias1=(const float*)d_in[8];
    const float* g1w = (const float*)d_in[9];  const float* g1b = (const float*)d_in[10];
    const float* g1m = (const float*)d_in[11];
    const float* W2l = (const float*)d_in[12]; const float* b2l = (const float*)d_in[13];
    const float* W2r = (const float*)d_in[14]; const float* b2r = (const float*)d_in[15];
    const float* att2= (const float*)d_in[16]; const float* bias2=(const float*)d_in[17];
    const float* g2w = (const float*)d_in[18]; const float* g2b = (const float*)d_in[19];
    const float* g2m = (const float*)d_in[20];
    const float* W3l = (const float*)d_in[21]; const float* b3l = (const float*)d_in[22];
    const float* W3r = (const float*)d_in[23]; const float* b3r = (const float*)d_in[24];
    const float* att3= (const float*)d_in[25]; const float* bias3=(const float*)d_in[26];
    const float* g3w = (const float*)d_in[27]; const float* g3b = (const float*)d_in[28];
    const float* g3m = (const float*)d_in[29];
    const float* lin_w=(const float*)d_in[30]; const float* lin_b=(const float*)d_in[31];

    const int* esrc = ei;
    const int* edst = ei + EE;

    // ---- workspace arena (units of 4B) ----
    float* ws = (float*)d_ws;
    int*   cursor  = (int*)(ws + 0);         // 20480
    int*   indptr  = (int*)(ws + 20480);     // 20480
    int*   srclist = (int*)(ws + 40960);     // 320512
    int*   gstart  = (int*)(ws + 361472);    // 512
    int*   gend    = (int*)(ws + 361984);    // 512
    float* gmu     = ws + 362496;            // 16384
    float* ginv    = ws + 378880;            // 16384
    float* gsumP   = ws + 395264;            // 16384
    float* gsqP    = ws + 411648;            // 16384
    float* A  = ws + 428032;                 // 5,120,000
    float* B  = ws + 5548032;                // 5,120,000
    float* Cb = ws + 10668032;               // 5,120,000
    float* D  = ws + 15788032;               // 5,120,000  (end 20,908,032 floats = 83.6 MB)

    const int TB = 256;
    const int MB = (NN + 63)/64;
    const int NCH = 32;

    // CSR + graph bounds
    hipMemsetAsync(cursor, 0, NN*sizeof(int), stream);
    hipMemsetAsync(gstart, 0x7f, GG*sizeof(int), stream);
    hipMemsetAsync(gend, 0, GG*sizeof(int), stream);
    k_deg<<<gridFor(EE, TB), TB, 0, stream>>>(edst, cursor);
    k_scan<<<1, 1024, 0, stream>>>(cursor, indptr);
    hipMemsetAsync(cursor, 0, NN*sizeof(int), stream);
    k_scatter<<<gridFor(EE, TB), TB, 0, stream>>>(esrc, edst, indptr, cursor, srclist);
    k_bounds<<<gridFor(NN, TB), TB, 0, stream>>>(batch, gstart, gend);

    // ---- layer 1: 19 -> 256 (concat) ----
    k_gemm_tiled<<<dim3(MB, 8), 256, 0, stream>>>(x,  W1l, b1l, W1r, b1r, B, Cb, 19, 256);
    k_gat<32, false><<<NN, 256, 0, stream>>>(indptr, srclist, B, Cb, att1, bias1, D);
    hipMemsetAsync(gsumP, 0, GG*256*sizeof(float), stream);
    hipMemsetAsync(gsqP, 0, GG*256*sizeof(float), stream);
    k_gn_partial<256><<<dim3(GG, NCH), 256, 0, stream>>>(D, gstart, gend, gsumP, gsqP);
    k_gn_finalize<<<gridFor(GG*256, TB), TB, 0, stream>>>(gsumP, gsqP, gstart, gend, g1m, gmu, ginv, 256);
    k_gn_apply<<<gridFor((long)NN*256, TB), TB, 0, stream>>>(D, gmu, ginv, g1w, g1b, batch, A, 256);

    // ---- layer 2: 256 -> 128 (concat) ----
    k_gemm_tiled<<<dim3(MB, 4), 256, 0, stream>>>(A, W2l, b2l, W2r, b2r, B, Cb, 256, 128);
    k_gat<16, false><<<NN, 128, 0, stream>>>(indptr, srclist, B, Cb, att2, bias2, D);
    hipMemsetAsync(gsumP, 0, GG*128*sizeof(float), stream);
    hipMemsetAsync(gsqP, 0, GG*128*sizeof(float), stream);
    k_gn_partial<128><<<dim3(GG, NCH), 128, 0, stream>>>(D, gstart, gend, gsumP, gsqP);
    k_gn_finalize<<<gridFor(GG*128, TB), TB, 0, stream>>>(gsumP, gsqP, gstart, gend, g2m, gmu, ginv, 128);
    k_gn_apply<<<gridFor((long)NN*128, TB), TB, 0, stream>>>(D, gmu, ginv, g2w, g2b, batch, A, 128);

    // ---- layer 3: 128 -> 64 (head mean -> 8) ----
    k_gemm_tiled<<<dim3(MB, 2), 256, 0, stream>>>(A, W3l, b3l, W3r, b3r, B, Cb, 128, 64);
    k_gat<8, true><<<NN, 64, 0, stream>>>(indptr, srclist, B, Cb, att3, bias3, D);
    k_gn_stats8<<<GG, 64, 0, stream>>>(D, gstart, gend, g3m, gmu, ginv);
    k_gn_apply<<<gridFor((long)NN*8, TB), TB, 0, stream>>>(D, gmu, ginv, g3w, g3b, batch, A, 8);

    // ---- pool + head ----
    float* outLog  = (float*)d_out;
    float* outFeat = outLog + GG*4;
    k_pool<<<GG, 64, 0, stream>>>(A, gstart, gend, outFeat);
    k_logits<<<1, 256, 0, stream>>>(outFeat, lin_w, lin_b, outLog);
}

// Round 5
// 502.373 us; speedup vs baseline: 17.4794x; 1.0903x over previous
//
#include <hip/hip_runtime.h>
#include <math.h>

#define NN 20000
#define EE 320000
#define GG 64
#define HH 8
#define EPSV 1e-5f

static inline unsigned int gridFor(long n, int b){ return (unsigned int)((n + b - 1)/b); }

// ---------------- CSR build ----------------
__global__ void k_deg(const int* __restrict__ edst, int* __restrict__ deg){
    int e = blockIdx.x*blockDim.x + threadIdx.x;
    if (e < EE) atomicAdd(&deg[edst[e]], 1);
}

__global__ void k_scan(const int* __restrict__ deg, int* __restrict__ indptr){
    __shared__ int partial[1024];
    const int CH = (NN + 1023)/1024;   // 20
    int t = threadIdx.x;
    int base = t*CH;
    int vals[CH];
    int sum = 0;
    for (int i = 0; i < CH; ++i){
        int v = (base+i < NN) ? deg[base+i] : 0;
        vals[i] = sum; sum += v;
    }
    partial[t] = sum;
    __syncthreads();
    for (int off = 1; off < 1024; off <<= 1){
        int v = (t >= off) ? partial[t-off] : 0;
        __syncthreads();
        partial[t] += v;
        __syncthreads();
    }
    int prefix = (t > 0) ? partial[t-1] : 0;
    for (int i = 0; i < CH; ++i)
        if (base+i < NN) indptr[base+i] = prefix + vals[i];
    if (t == 1023) indptr[NN] = prefix + sum;
}

__global__ void k_scatter(const int* __restrict__ esrc, const int* __restrict__ edst,
                          const int* __restrict__ indptr, int* __restrict__ cursor,
                          int* __restrict__ srclist){
    int e = blockIdx.x*blockDim.x + threadIdx.x;
    if (e >= EE) return;
    int d = edst[e];
    int pos = atomicAdd(&cursor[d], 1);
    srclist[indptr[d] + pos] = esrc[e];
}

// batch sorted: boundary detection, no atomics
__global__ void k_bounds(const int* __restrict__ batch, int* __restrict__ gstart, int* __restrict__ gend){
    int i = blockIdx.x*blockDim.x + threadIdx.x;
    if (i >= NN) return;
    int b = batch[i];
    if (i == 0 || batch[i-1] != b) gstart[b] = i;
    if (i == NN-1 || batch[i+1] != b) gend[b] = i+1;
}

// ---------------- tiled dual linear: [xl | xr] = h @ [Wl | Wr] + [bl | br] ----------------
// 128x64 output tile, BK=16, 256 threads, 8x4 micro-tile.
__global__ __launch_bounds__(256)
void k_gemm_tiled(const float* __restrict__ h,
                  const float* __restrict__ Wl, const float* __restrict__ bl,
                  const float* __restrict__ Wr, const float* __restrict__ br,
                  float* __restrict__ xl, float* __restrict__ xr,
                  int K, int HC){
    __shared__ float As[16][132];   // [kk][mm]
    __shared__ float Bs[16][68];    // [kk][nn]
    const int tid = threadIdx.x;
    const int m0 = blockIdx.x * 128;
    const int n0 = blockIdx.y * 64;
    const int tx = tid & 15, ty = tid >> 4;

    const bool right = (n0 >= HC);
    const float* W  = right ? Wr : Wl;
    const float* bv = right ? br : bl;
    const int nbase = right ? (n0 - HC) : n0;

    float acc[8][4] = {};

    for (int k0 = 0; k0 < K; k0 += 16){
        #pragma unroll
        for (int i = 0; i < 8; ++i){
            int idx = i*256 + tid;
            int kk = idx & 15, mm = idx >> 4;
            int gm = m0 + mm, gk = k0 + kk;
            As[kk][mm] = (gm < NN && gk < K) ? h[(long)gm*K + gk] : 0.f;
        }
        #pragma unroll
        for (int i = 0; i < 4; ++i){
            int idx = i*256 + tid;
            int kk = idx >> 6, nn = idx & 63;
            int gk = k0 + kk;
            Bs[kk][nn] = (gk < K) ? W[(long)gk*HC + nbase + nn] : 0.f;
        }
        __syncthreads();
        #pragma unroll
        for (int kk = 0; kk < 16; ++kk){
            float4 a0 = *(const float4*)&As[kk][ty*8];
            float4 a1 = *(const float4*)&As[kk][ty*8 + 4];
            float4 b  = *(const float4*)&Bs[kk][tx*4];
            acc[0][0] = fmaf(a0.x,b.x,acc[0][0]); acc[0][1] = fmaf(a0.x,b.y,acc[0][1]); acc[0][2] = fmaf(a0.x,b.z,acc[0][2]); acc[0][3] = fmaf(a0.x,b.w,acc[0][3]);
            acc[1][0] = fmaf(a0.y,b.x,acc[1][0]); acc[1][1] = fmaf(a0.y,b.y,acc[1][1]); acc[1][2] = fmaf(a0.y,b.z,acc[1][2]); acc[1][3] = fmaf(a0.y,b.w,acc[1][3]);
            acc[2][0] = fmaf(a0.z,b.x,acc[2][0]); acc[2][1] = fmaf(a0.z,b.y,acc[2][1]); acc[2][2] = fmaf(a0.z,b.z,acc[2][2]); acc[2][3] = fmaf(a0.z,b.w,acc[2][3]);
            acc[3][0] = fmaf(a0.w,b.x,acc[3][0]); acc[3][1] = fmaf(a0.w,b.y,acc[3][1]); acc[3][2] = fmaf(a0.w,b.z,acc[3][2]); acc[3][3] = fmaf(a0.w,b.w,acc[3][3]);
            acc[4][0] = fmaf(a1.x,b.x,acc[4][0]); acc[4][1] = fmaf(a1.x,b.y,acc[4][1]); acc[4][2] = fmaf(a1.x,b.z,acc[4][2]); acc[4][3] = fmaf(a1.x,b.w,acc[4][3]);
            acc[5][0] = fmaf(a1.y,b.x,acc[5][0]); acc[5][1] = fmaf(a1.y,b.y,acc[5][1]); acc[5][2] = fmaf(a1.y,b.z,acc[5][2]); acc[5][3] = fmaf(a1.y,b.w,acc[5][3]);
            acc[6][0] = fmaf(a1.z,b.x,acc[6][0]); acc[6][1] = fmaf(a1.z,b.y,acc[6][1]); acc[6][2] = fmaf(a1.z,b.z,acc[6][2]); acc[6][3] = fmaf(a1.z,b.w,acc[6][3]);
            acc[7][0] = fmaf(a1.w,b.x,acc[7][0]); acc[7][1] = fmaf(a1.w,b.y,acc[7][1]); acc[7][2] = fmaf(a1.w,b.z,acc[7][2]); acc[7][3] = fmaf(a1.w,b.w,acc[7][3]);
        }
        __syncthreads();
    }

    float* X = right ? xr : xl;
    float4 bb = *(const float4*)&bv[nbase + tx*4];
    #pragma unroll
    for (int i = 0; i < 8; ++i){
        int gm = m0 + ty*8 + i;
        if (gm >= NN) break;
        float4 v;
        v.x = acc[i][0] + bb.x; v.y = acc[i][1] + bb.y;
        v.z = acc[i][2] + bb.z; v.w = acc[i][3] + bb.w;
        *(float4*)&X[(long)gm*HC + nbase + tx*4] = v;
    }
}

// ---------------- fused GATv2: fixed-baseline softmax (exact: o/l invariant to baseline) ----------------
template<int C>
__device__ __forceinline__ float headReduce(float v){
    #pragma unroll
    for (int m = 1; m < C; m <<= 1) v += __shfl_xor(v, m, C);
    return v;
}

template<int C, bool MEAN>
__global__ void k_gat(const int* __restrict__ indptr, const int* __restrict__ srclist,
                      const float* __restrict__ xl, const float* __restrict__ xr,
                      const float* __restrict__ att, const float* __restrict__ bias,
                      float* __restrict__ val){
    constexpr int HC = 8*C;
    int d = blockIdx.x;
    int t = threadIdx.x;
    float xr_d = xr[(long)d*HC + t];
    float at   = att[t];

    // self loop logit = fixed baseline m0 (softmax result is baseline-invariant)
    float xls = xl[(long)d*HC + t];
    float tm = xls + xr_d; tm = tm > 0.f ? tm : 0.2f*tm; tm *= at;
    float m0 = headReduce<C>(tm);
    float l = 1.0f;     // exp(m0 - m0)
    float o = xls;

    int beg = indptr[d], end = indptr[d+1];
    int j = beg;
    for (; j + 2 <= end; j += 2){
        int sA = srclist[j], sB = srclist[j+1];
        float xvA = xl[(long)sA*HC + t];
        float xvB = xl[(long)sB*HC + t];
        float qA = xvA + xr_d; qA = qA > 0.f ? qA : 0.2f*qA; qA *= at;
        float qB = xvB + xr_d; qB = qB > 0.f ? qB : 0.2f*qB; qB *= at;
        float aA = headReduce<C>(qA);
        float aB = headReduce<C>(qB);
        float pA = __expf(aA - m0);
        float pB = __expf(aB - m0);
        l += pA + pB;
        o = fmaf(pA, xvA, o);
        o = fmaf(pB, xvB, o);
    }
    if (j < end){
        int s = srclist[j];
        float xv = xl[(long)s*HC + t];
        float q = xv + xr_d; q = q > 0.f ? q : 0.2f*q; q *= at;
        float a2 = headReduce<C>(q);
        float p = __expf(a2 - m0);
        l += p;
        o = fmaf(p, xv, o);
    }
    float r = o / l;
    if (!MEAN){
        val[(long)d*HC + t] = r + bias[t];
    } else {
        r += __shfl_xor(r, 8, 64);
        r += __shfl_xor(r, 16, 64);
        r += __shfl_xor(r, 32, 64);
        if (t < 8) val[(long)d*8 + t] = r*0.125f + bias[t];
    }
}

// ---------------- GraphNorm stats: chunked partials + finalize ----------------
template<int F>
__global__ void k_gn_partial(const float* __restrict__ val,
                             const int* __restrict__ gstart, const int* __restrict__ gend,
                             float* __restrict__ gsum, float* __restrict__ gsq){
    int g = blockIdx.x, ch = blockIdx.y, nch = gridDim.y;
    int c = threadIdx.x;
    int s = gstart[g], e = gend[g];
    float sum = 0.f, sq = 0.f;
    for (int i = s + ch; i < e; i += nch){
        float v = val[(long)i*F + c];
        sum += v; sq += v*v;
    }
    if (sum != 0.f || sq != 0.f){
        atomicAdd(&gsum[g*F + c], sum);
        atomicAdd(&gsq[g*F + c], sq);
    }
}

__global__ void k_gn_finalize(const float* __restrict__ gsum, const float* __restrict__ gsq,
                              const int* __restrict__ gstart, const int* __restrict__ gend,
                              const float* __restrict__ ms,
                              float* __restrict__ gmu, float* __restrict__ ginv, int F){
    int idx = blockIdx.x*blockDim.x + threadIdx.x;
    if (idx >= GG*F) return;
    int g = idx / F, c = idx - g*F;
    int cnti = gend[g] - gstart[g];
    float cn = cnti > 0 ? (float)cnti : 1.f;
    float mean = gsum[idx] / cn;
    float mu = mean * ms[c];
    float var = gsq[idx]/cn - 2.f*mu*mean + mu*mu;
    gmu[idx]  = mu;
    ginv[idx] = rsqrtf(var + EPSV);
}

__global__ void k_gn_stats8(const float* __restrict__ val,
                            const int* __restrict__ gstart, const int* __restrict__ gend,
                            const float* __restrict__ ms,
                            float* __restrict__ gmu, float* __restrict__ ginv){
    const int F = 8;
    int g = blockIdx.x;
    int t = threadIdx.x;
    int c = t % F, r = t / F;
    int s = gstart[g], e = gend[g];
    float sum = 0.f, sq = 0.f;
    for (int i = s + r; i < e; i += 8){
        float v = val[(long)i*F + c];
        sum += v; sq += v*v;
    }
    #pragma unroll
    for (int mask = 8; mask < 64; mask <<= 1){
        sum += __shfl_xor(sum, mask, 64);
        sq  += __shfl_xor(sq,  mask, 64);
    }
    if (r == 0){
        int cnti = e - s;
        float cn = cnti > 0 ? (float)cnti : 1.f;
        float mean = sum / cn;
        float mu = mean * ms[c];
        float var = sq/cn - 2.f*mu*mean + mu*mu;
        gmu[g*F + c]  = mu;
        ginv[g*F + c] = rsqrtf(var + EPSV);
    }
}

__global__ void k_gn_apply(const float* __restrict__ val,
                           const float* __restrict__ gmu, const float* __restrict__ ginv,
                           const float* __restrict__ w, const float* __restrict__ b,
                           const int* __restrict__ batch, float* __restrict__ out, int F){
    int idx = blockIdx.x*blockDim.x + threadIdx.x;
    if (idx >= NN*F) return;
    int n = idx / F, c = idx - n*F, g = batch[n];
    float v = (val[idx] - gmu[g*F + c]) * ginv[g*F + c] * w[c] + b[c];
    out[idx] = fmaxf(v, 0.f);
}

// ---------------- pool + head ----------------
__global__ void k_pool(const float* __restrict__ h,
                       const int* __restrict__ gstart, const int* __restrict__ gend,
                       float* __restrict__ outFeat){
    int g = blockIdx.x;
    int t = threadIdx.x;
    int c = t & 7, r = t >> 3;
    int s = gstart[g], e = gend[g];
    float sum = 0.f;
    for (int i = s + r; i < e; i += 8) sum += h[(long)i*8 + c];
    sum += __shfl_xor(sum, 8, 64);
    sum += __shfl_xor(sum, 16, 64);
    sum += __shfl_xor(sum, 32, 64);
    if (t < 8){
        int cnti = e - s;
        float cn = cnti > 0 ? (float)cnti : 1.f;
        outFeat[g*8 + t] = sum / cn;
    }
}

__global__ void k_logits(const float* __restrict__ feat, const float* __restrict__ lw,
                         const float* __restrict__ lb, float* __restrict__ outLog){
    int idx = blockIdx.x*blockDim.x + threadIdx.x;
    if (idx >= GG*4) return;
    int g = idx >> 2, j = idx & 3;
    float a = lb[j];
    for (int c = 0; c < 8; ++c) a += feat[g*8 + c] * lw[c*4 + j];
    outLog[idx] = a;
}

extern "C" void kernel_launch(void* const* d_in, const int* in_sizes, int n_in,
                              void* d_out, int out_size, void* d_ws, size_t ws_size,
                              hipStream_t stream) {
    const float* x     = (const float*)d_in[0];
    const int*   ei    = (const int*)  d_in[1];
    const int*   batch = (const int*)  d_in[2];
    const float* W1l = (const float*)d_in[3];  const float* b1l = (const float*)d_in[4];
    const float* W1r = (const float*)d_in[5];  const float* b1r = (const float*)d_in[6];
    const float* att1= (const float*)d_in[7];  const float* bias1=(const float*)d_in[8];
    const float* g1w = (const float*)d_in[9];  const float* g1b = (const float*)d_in[10];
    const float* g1m = (const float*)d_in[11];
    const float* W2l = (const float*)d_in[12]; const float* b2l = (const float*)d_in[13];
    const float* W2r = (const float*)d_in[14]; const float* b2r = (const float*)d_in[15];
    const float* att2= (const float*)d_in[16]; const float* bias2=(const float*)d_in[17];
    const float* g2w = (const float*)d_in[18]; const float* g2b = (const float*)d_in[19];
    const float* g2m = (const float*)d_in[20];
    const float* W3l = (const float*)d_in[21]; const float* b3l = (const float*)d_in[22];
    const float* W3r = (const float*)d_in[23]; const float* b3r = (const float*)d_in[24];
    const float* att3= (const float*)d_in[25]; const float* bias3=(const float*)d_in[26];
    const float* g3w = (const float*)d_in[27]; const float* g3b = (const float*)d_in[28];
    const float* g3m = (const float*)d_in[29];
    const float* lin_w=(const float*)d_in[30]; const float* lin_b=(const float*)d_in[31];

    const int* esrc = ei;
    const int* edst = ei + EE;

    // ---- workspace arena (units of 4B) ----
    float* ws = (float*)d_ws;
    int*   cursor  = (int*)(ws + 0);         // 20480
    int*   indptr  = (int*)(ws + 20480);     // 20480
    int*   srclist = (int*)(ws + 40960);     // 320512
    int*   gstart  = (int*)(ws + 361472);    // 512
    int*   gend    = (int*)(ws + 361984);    // 512
    float* gmu     = ws + 362496;            // 16384
    float* ginv    = ws + 378880;            // 16384
    float* gsumP   = ws + 395264;            // 16384
    float* gsqP    = ws + 411648;            // 16384
    float* A  = ws + 428032;                 // 5,120,000
    float* B  = ws + 5548032;                // 5,120,000
    float* Cb = ws + 10668032;               // 5,120,000
    float* D  = ws + 15788032;               // 5,120,000

    const int TB = 256;
    const int MB = (NN + 127)/128;   // 157 row-tiles
    const int NCH = 32;

    // CSR + graph bounds
    hipMemsetAsync(cursor, 0, NN*sizeof(int), stream);
    k_deg<<<gridFor(EE, TB), TB, 0, stream>>>(edst, cursor);
    k_scan<<<1, 1024, 0, stream>>>(cursor, indptr);
    hipMemsetAsync(cursor, 0, NN*sizeof(int), stream);
    k_scatter<<<gridFor(EE, TB), TB, 0, stream>>>(esrc, edst, indptr, cursor, srclist);
    k_bounds<<<gridFor(NN, TB), TB, 0, stream>>>(batch, gstart, gend);

    // ---- layer 1: 19 -> 256 (concat) ----
    k_gemm_tiled<<<dim3(MB, 8), 256, 0, stream>>>(x,  W1l, b1l, W1r, b1r, B, Cb, 19, 256);
    k_gat<32, false><<<NN, 256, 0, stream>>>(indptr, srclist, B, Cb, att1, bias1, D);
    hipMemsetAsync(gsumP, 0, GG*256*sizeof(float), stream);
    hipMemsetAsync(gsqP, 0, GG*256*sizeof(float), stream);
    k_gn_partial<256><<<dim3(GG, NCH), 256, 0, stream>>>(D, gstart, gend, gsumP, gsqP);
    k_gn_finalize<<<gridFor(GG*256, TB), TB, 0, stream>>>(gsumP, gsqP, gstart, gend, g1m, gmu, ginv, 256);
    k_gn_apply<<<gridFor((long)NN*256, TB), TB, 0, stream>>>(D, gmu, ginv, g1w, g1b, batch, A, 256);

    // ---- layer 2: 256 -> 128 (concat) ----
    k_gemm_tiled<<<dim3(MB, 4), 256, 0, stream>>>(A, W2l, b2l, W2r, b2r, B, Cb, 256, 128);
    k_gat<16, false><<<NN, 128, 0, stream>>>(indptr, srclist, B, Cb, att2, bias2, D);
    hipMemsetAsync(gsumP, 0, GG*128*sizeof(float), stream);
    hipMemsetAsync(gsqP, 0, GG*128*sizeof(float), stream);
    k_gn_partial<128><<<dim3(GG, NCH), 128, 0, stream>>>(D, gstart, gend, gsumP, gsqP);
    k_gn_finalize<<<gridFor(GG*128, TB), TB, 0, stream>>>(gsumP, gsqP, gstart, gend, g2m, gmu, ginv, 128);
    k_gn_apply<<<gridFor((long)NN*128, TB), TB, 0, stream>>>(D, gmu, ginv, g2w, g2b, batch, A, 128);

    // ---- layer 3: 128 -> 64 (head mean -> 8) ----
    k_gemm_tiled<<<dim3(MB, 2), 256, 0, stream>>>(A, W3l, b3l, W3r, b3r, B, Cb, 128, 64);
    k_gat<8, true><<<NN, 64, 0, stream>>>(indptr, srclist, B, Cb, att3, bias3, D);
    k_gn_stats8<<<GG, 64, 0, stream>>>(D, gstart, gend, g3m, gmu, ginv);
    k_gn_apply<<<gridFor((long)NN*8, TB), TB, 0, stream>>>(D, gmu, ginv, g3w, g3b, batch, A, 8);

    // ---- pool + head ----
    float* outLog  = (float*)d_out;
    float* outFeat = outLog + GG*4;
    k_pool<<<GG, 64, 0, stream>>>(A, gstart, gend, outFeat);
    k_logits<<<1, 256, 0, stream>>>(outFeat, lin_w, lin_b, outLog);
}

// Round 6
// 467.197 us; speedup vs baseline: 18.7954x; 1.0753x over previous
//
#include <hip/hip_runtime.h>
#include <math.h>

#define NN 20000
#define EE 320000
#define GG 64
#define HH 8
#define EPSV 1e-5f

static inline unsigned int gridFor(long n, int b){ return (unsigned int)((n + b - 1)/b); }

// ---------------- CSR build ----------------
__global__ void k_deg(const int* __restrict__ edst, int* __restrict__ deg){
    int e = blockIdx.x*blockDim.x + threadIdx.x;
    if (e < EE) atomicAdd(&deg[edst[e]], 1);
}

__global__ void k_scan(const int* __restrict__ deg, int* __restrict__ indptr){
    __shared__ int partial[1024];
    const int CH = (NN + 1023)/1024;   // 20
    int t = threadIdx.x;
    int base = t*CH;
    int vals[CH];
    int sum = 0;
    for (int i = 0; i < CH; ++i){
        int v = (base+i < NN) ? deg[base+i] : 0;
        vals[i] = sum; sum += v;
    }
    partial[t] = sum;
    __syncthreads();
    for (int off = 1; off < 1024; off <<= 1){
        int v = (t >= off) ? partial[t-off] : 0;
        __syncthreads();
        partial[t] += v;
        __syncthreads();
    }
    int prefix = (t > 0) ? partial[t-1] : 0;
    for (int i = 0; i < CH; ++i)
        if (base+i < NN) indptr[base+i] = prefix + vals[i];
    if (t == 1023) indptr[NN] = prefix + sum;
}

__global__ void k_scatter(const int* __restrict__ esrc, const int* __restrict__ edst,
                          const int* __restrict__ indptr, int* __restrict__ cursor,
                          int* __restrict__ srclist){
    int e = blockIdx.x*blockDim.x + threadIdx.x;
    if (e >= EE) return;
    int d = edst[e];
    int pos = atomicAdd(&cursor[d], 1);
    srclist[indptr[d] + pos] = esrc[e];
}

__global__ void k_bounds(const int* __restrict__ batch, int* __restrict__ gstart, int* __restrict__ gend){
    int i = blockIdx.x*blockDim.x + threadIdx.x;
    if (i >= NN) return;
    int b = batch[i];
    if (i == 0 || batch[i-1] != b) gstart[b] = i;
    if (i == NN-1 || batch[i+1] != b) gend[b] = i+1;
}

// ---------------- tiled dual linear: [xl | xr] = h @ [Wl | Wr] + [bl | br] ----------------
__global__ __launch_bounds__(256)
void k_gemm_tiled(const float* __restrict__ h,
                  const float* __restrict__ Wl, const float* __restrict__ bl,
                  const float* __restrict__ Wr, const float* __restrict__ br,
                  float* __restrict__ xl, float* __restrict__ xr,
                  int K, int HC){
    __shared__ float As[16][132];
    __shared__ float Bs[16][68];
    const int tid = threadIdx.x;
    const int m0 = blockIdx.x * 128;
    const int n0 = blockIdx.y * 64;
    const int tx = tid & 15, ty = tid >> 4;

    const bool right = (n0 >= HC);
    const float* W  = right ? Wr : Wl;
    const float* bv = right ? br : bl;
    const int nbase = right ? (n0 - HC) : n0;

    float acc[8][4] = {};

    for (int k0 = 0; k0 < K; k0 += 16){
        #pragma unroll
        for (int i = 0; i < 8; ++i){
            int idx = i*256 + tid;
            int kk = idx & 15, mm = idx >> 4;
            int gm = m0 + mm, gk = k0 + kk;
            As[kk][mm] = (gm < NN && gk < K) ? h[(long)gm*K + gk] : 0.f;
        }
        #pragma unroll
        for (int i = 0; i < 4; ++i){
            int idx = i*256 + tid;
            int kk = idx >> 6, nn = idx & 63;
            int gk = k0 + kk;
            Bs[kk][nn] = (gk < K) ? W[(long)gk*HC + nbase + nn] : 0.f;
        }
        __syncthreads();
        #pragma unroll
        for (int kk = 0; kk < 16; ++kk){
            float4 a0 = *(const float4*)&As[kk][ty*8];
            float4 a1 = *(const float4*)&As[kk][ty*8 + 4];
            float4 b  = *(const float4*)&Bs[kk][tx*4];
            acc[0][0] = fmaf(a0.x,b.x,acc[0][0]); acc[0][1] = fmaf(a0.x,b.y,acc[0][1]); acc[0][2] = fmaf(a0.x,b.z,acc[0][2]); acc[0][3] = fmaf(a0.x,b.w,acc[0][3]);
            acc[1][0] = fmaf(a0.y,b.x,acc[1][0]); acc[1][1] = fmaf(a0.y,b.y,acc[1][1]); acc[1][2] = fmaf(a0.y,b.z,acc[1][2]); acc[1][3] = fmaf(a0.y,b.w,acc[1][3]);
            acc[2][0] = fmaf(a0.z,b.x,acc[2][0]); acc[2][1] = fmaf(a0.z,b.y,acc[2][1]); acc[2][2] = fmaf(a0.z,b.z,acc[2][2]); acc[2][3] = fmaf(a0.z,b.w,acc[2][3]);
            acc[3][0] = fmaf(a0.w,b.x,acc[3][0]); acc[3][1] = fmaf(a0.w,b.y,acc[3][1]); acc[3][2] = fmaf(a0.w,b.z,acc[3][2]); acc[3][3] = fmaf(a0.w,b.w,acc[3][3]);
            acc[4][0] = fmaf(a1.x,b.x,acc[4][0]); acc[4][1] = fmaf(a1.x,b.y,acc[4][1]); acc[4][2] = fmaf(a1.x,b.z,acc[4][2]); acc[4][3] = fmaf(a1.x,b.w,acc[4][3]);
            acc[5][0] = fmaf(a1.y,b.x,acc[5][0]); acc[5][1] = fmaf(a1.y,b.y,acc[5][1]); acc[5][2] = fmaf(a1.y,b.z,acc[5][2]); acc[5][3] = fmaf(a1.y,b.w,acc[5][3]);
            acc[6][0] = fmaf(a1.z,b.x,acc[6][0]); acc[6][1] = fmaf(a1.z,b.y,acc[6][1]); acc[6][2] = fmaf(a1.z,b.z,acc[6][2]); acc[6][3] = fmaf(a1.z,b.w,acc[6][3]);
            acc[7][0] = fmaf(a1.w,b.x,acc[7][0]); acc[7][1] = fmaf(a1.w,b.y,acc[7][1]); acc[7][2] = fmaf(a1.w,b.z,acc[7][2]); acc[7][3] = fmaf(a1.w,b.w,acc[7][3]);
        }
        __syncthreads();
    }

    float* X = right ? xr : xl;
    float4 bb = *(const float4*)&bv[nbase + tx*4];
    #pragma unroll
    for (int i = 0; i < 8; ++i){
        int gm = m0 + ty*8 + i;
        if (gm >= NN) break;
        float4 v;
        v.x = acc[i][0] + bb.x; v.y = acc[i][1] + bb.y;
        v.z = acc[i][2] + bb.z; v.w = acc[i][3] + bb.w;
        *(float4*)&X[(long)gm*HC + nbase + tx*4] = v;
    }
}

// ---------------- fused GATv2, wave-per-node, VEC channels/lane ----------------
template<int VEC> struct VT;
template<> struct VT<1>{ using T = float;  };
template<> struct VT<2>{ using T = float2; };
template<> struct VT<4>{ using T = float4; };

__device__ __forceinline__ float lrelu(float z){ return z > 0.f ? z : 0.2f*z; }

__device__ __forceinline__ float edot(float xv, float xr, float at){
    return lrelu(xv + xr) * at;
}
__device__ __forceinline__ float edot(float2 xv, float2 xr, float2 at){
    return lrelu(xv.x+xr.x)*at.x + lrelu(xv.y+xr.y)*at.y;
}
__device__ __forceinline__ float edot(float4 xv, float4 xr, float4 at){
    return lrelu(xv.x+xr.x)*at.x + lrelu(xv.y+xr.y)*at.y
         + lrelu(xv.z+xr.z)*at.z + lrelu(xv.w+xr.w)*at.w;
}
__device__ __forceinline__ void efma(float& o, float p, float xv){ o = fmaf(p,xv,o); }
__device__ __forceinline__ void efma(float2& o, float p, float2 xv){
    o.x = fmaf(p,xv.x,o.x); o.y = fmaf(p,xv.y,o.y);
}
__device__ __forceinline__ void efma(float4& o, float p, float4 xv){
    o.x = fmaf(p,xv.x,o.x); o.y = fmaf(p,xv.y,o.y);
    o.z = fmaf(p,xv.z,o.z); o.w = fmaf(p,xv.w,o.w);
}
__device__ __forceinline__ float escale(float o, float s, float b){ return fmaf(o,s,b); }
__device__ __forceinline__ float2 escale(float2 o, float s, float2 b){
    return make_float2(fmaf(o.x,s,b.x), fmaf(o.y,s,b.y));
}
__device__ __forceinline__ float4 escale(float4 o, float s, float4 b){
    return make_float4(fmaf(o.x,s,b.x), fmaf(o.y,s,b.y), fmaf(o.z,s,b.z), fmaf(o.w,s,b.w));
}

// 8-lane butterfly (head segment); xor masks 1,2,4 stay within 8-lane groups
__device__ __forceinline__ float red8(float v){
    v += __shfl_xor(v, 1);
    v += __shfl_xor(v, 2);
    v += __shfl_xor(v, 4);
    return v;
}

// one wave per node; 4 waves per block (independent, no barrier)
template<int VEC, bool MEAN>
__global__ __launch_bounds__(256)
void k_gat_w(const int* __restrict__ indptr, const int* __restrict__ srclist,
             const float* __restrict__ xl, const float* __restrict__ xr,
             const float* __restrict__ att, const float* __restrict__ bias,
             float* __restrict__ val){
    using V = typename VT<VEC>::T;
    constexpr int HC = 64*VEC;
    const int lane = threadIdx.x & 63;
    const int d = blockIdx.x*4 + (threadIdx.x >> 6);
    const int co = lane*VEC;

    const long rowd = (long)d*HC + co;
    V xrd = *(const V*)&xr[rowd];
    V at  = *(const V*)&att[co];
    V xls = *(const V*)&xl[rowd];

    // self-loop logit = fixed softmax baseline (result is baseline-invariant)
    float m0 = red8(edot(xls, xrd, at));
    float l = 1.0f;
    V o = xls;

    int j = indptr[d], end = indptr[d+1];
    for (; j < end; j += 4){
        int m = end - j;
        int s0 = srclist[j];
        int s1 = (m > 1) ? srclist[j+1] : s0;
        int s2 = (m > 2) ? srclist[j+2] : s0;
        int s3 = (m > 3) ? srclist[j+3] : s0;
        V x0 = *(const V*)&xl[(long)s0*HC + co];
        V x1 = *(const V*)&xl[(long)s1*HC + co];
        V x2 = *(const V*)&xl[(long)s2*HC + co];
        V x3 = *(const V*)&xl[(long)s3*HC + co];
        float a0 = red8(edot(x0, xrd, at));
        float a1 = red8(edot(x1, xrd, at));
        float a2 = red8(edot(x2, xrd, at));
        float a3 = red8(edot(x3, xrd, at));
        float p0 = __expf(a0 - m0);
        float p1 = __expf(a1 - m0);
        float p2 = __expf(a2 - m0);
        float p3 = __expf(a3 - m0);
        l += p0; efma(o, p0, x0);
        if (m > 1){ l += p1; efma(o, p1, x1); }
        if (m > 2){ l += p2; efma(o, p2, x2); }
        if (m > 3){ l += p3; efma(o, p3, x3); }
    }
    float invl = 1.0f / l;
    if (!MEAN){
        V bv = *(const V*)&bias[co];
        *(V*)&val[rowd] = escale(o, invl, bv);
    } else {
        // VEC==1: lane = h*8 + c ; mean over heads = lanes stride 8
        float r = ((float&)o) * invl;
        r += __shfl_xor(r, 8);
        r += __shfl_xor(r, 16);
        r += __shfl_xor(r, 32);
        if (lane < 8) val[(long)d*8 + lane] = r*0.125f + bias[lane];
    }
}

// ---------------- GraphNorm stats: chunked partials + finalize ----------------
template<int F>
__global__ void k_gn_partial(const float* __restrict__ val,
                             const int* __restrict__ gstart, const int* __restrict__ gend,
                             float* __restrict__ gsum, float* __restrict__ gsq){
    int g = blockIdx.x, ch = blockIdx.y, nch = gridDim.y;
    int c = threadIdx.x;
    int s = gstart[g], e = gend[g];
    float sum = 0.f, sq = 0.f;
    for (int i = s + ch; i < e; i += nch){
        float v = val[(long)i*F + c];
        sum += v; sq += v*v;
    }
    if (sum != 0.f || sq != 0.f){
        atomicAdd(&gsum[g*F + c], sum);
        atomicAdd(&gsq[g*F + c], sq);
    }
}

__global__ void k_gn_finalize(const float* __restrict__ gsum, const float* __restrict__ gsq,
                              const int* __restrict__ gstart, const int* __restrict__ gend,
                              const float* __restrict__ ms,
                              float* __restrict__ gmu, float* __restrict__ ginv, int F){
    int idx = blockIdx.x*blockDim.x + threadIdx.x;
    if (idx >= GG*F) return;
    int g = idx / F, c = idx - g*F;
    int cnti = gend[g] - gstart[g];
    float cn = cnti > 0 ? (float)cnti : 1.f;
    float mean = gsum[idx] / cn;
    float mu = mean * ms[c];
    float var = gsq[idx]/cn - 2.f*mu*mean + mu*mu;
    gmu[idx]  = mu;
    ginv[idx] = rsqrtf(var + EPSV);
}

__global__ void k_gn_stats8(const float* __restrict__ val,
                            const int* __restrict__ gstart, const int* __restrict__ gend,
                            const float* __restrict__ ms,
                            float* __restrict__ gmu, float* __restrict__ ginv){
    const int F = 8;
    int g = blockIdx.x;
    int t = threadIdx.x;
    int c = t % F, r = t / F;
    int s = gstart[g], e = gend[g];
    float sum = 0.f, sq = 0.f;
    for (int i = s + r; i < e; i += 8){
        float v = val[(long)i*F + c];
        sum += v; sq += v*v;
    }
    #pragma unroll
    for (int mask = 8; mask < 64; mask <<= 1){
        sum += __shfl_xor(sum, mask, 64);
        sq  += __shfl_xor(sq,  mask, 64);
    }
    if (r == 0){
        int cnti = e - s;
        float cn = cnti > 0 ? (float)cnti : 1.f;
        float mean = sum / cn;
        float mu = mean * ms[c];
        float var = sq/cn - 2.f*mu*mean + mu*mu;
        gmu[g*F + c]  = mu;
        ginv[g*F + c] = rsqrtf(var + EPSV);
    }
}

__global__ void k_gn_apply(const float* __restrict__ val,
                           const float* __restrict__ gmu, const float* __restrict__ ginv,
                           const float* __restrict__ w, const float* __restrict__ b,
                           const int* __restrict__ batch, float* __restrict__ out, int F){
    int idx = blockIdx.x*blockDim.x + threadIdx.x;
    if (idx >= NN*F) return;
    int n = idx / F, c = idx - n*F, g = batch[n];
    float v = (val[idx] - gmu[g*F + c]) * ginv[g*F + c] * w[c] + b[c];
    out[idx] = fmaxf(v, 0.f);
}

// ---------------- pool + head ----------------
__global__ void k_pool(const float* __restrict__ h,
                       const int* __restrict__ gstart, const int* __restrict__ gend,
                       float* __restrict__ outFeat){
    int g = blockIdx.x;
    int t = threadIdx.x;
    int c = t & 7, r = t >> 3;
    int s = gstart[g], e = gend[g];
    float sum = 0.f;
    for (int i = s + r; i < e; i += 8) sum += h[(long)i*8 + c];
    sum += __shfl_xor(sum, 8, 64);
    sum += __shfl_xor(sum, 16, 64);
    sum += __shfl_xor(sum, 32, 64);
    if (t < 8){
        int cnti = e - s;
        float cn = cnti > 0 ? (float)cnti : 1.f;
        outFeat[g*8 + t] = sum / cn;
    }
}

__global__ void k_logits(const float* __restrict__ feat, const float* __restrict__ lw,
                         const float* __restrict__ lb, float* __restrict__ outLog){
    int idx = blockIdx.x*blockDim.x + threadIdx.x;
    if (idx >= GG*4) return;
    int g = idx >> 2, j = idx & 3;
    float a = lb[j];
    for (int c = 0; c < 8; ++c) a += feat[g*8 + c] * lw[c*4 + j];
    outLog[idx] = a;
}

extern "C" void kernel_launch(void* const* d_in, const int* in_sizes, int n_in,
                              void* d_out, int out_size, void* d_ws, size_t ws_size,
                              hipStream_t stream) {
    const float* x     = (const float*)d_in[0];
    const int*   ei    = (const int*)  d_in[1];
    const int*   batch = (const int*)  d_in[2];
    const float* W1l = (const float*)d_in[3];  const float* b1l = (const float*)d_in[4];
    const float* W1r = (const float*)d_in[5];  const float* b1r = (const float*)d_in[6];
    const float* att1= (const float*)d_in[7];  const float* bias1=(const float*)d_in[8];
    const float* g1w = (const float*)d_in[9];  const float* g1b = (const float*)d_in[10];
    const float* g1m = (const float*)d_in[11];
    const float* W2l = (const float*)d_in[12]; const float* b2l = (const float*)d_in[13];
    const float* W2r = (const float*)d_in[14]; const float* b2r = (const float*)d_in[15];
    const float* att2= (const float*)d_in[16]; const float* bias2=(const float*)d_in[17];
    const float* g2w = (const float*)d_in[18]; const float* g2b = (const float*)d_in[19];
    const float* g2m = (const float*)d_in[20];
    const float* W3l = (const float*)d_in[21]; const float* b3l = (const float*)d_in[22];
    const float* W3r = (const float*)d_in[23]; const float* b3r = (const float*)d_in[24];
    const float* att3= (const float*)d_in[25]; const float* bias3=(const float*)d_in[26];
    const float* g3w = (const float*)d_in[27]; const float* g3b = (const float*)d_in[28];
    const float* g3m = (const float*)d_in[29];
    const float* lin_w=(const float*)d_in[30]; const float* lin_b=(const float*)d_in[31];

    const int* esrc = ei;
    const int* edst = ei + EE;

    // ---- workspace arena (units of 4B) ----
    float* ws = (float*)d_ws;
    int*   cursor  = (int*)(ws + 0);         // 20480
    int*   indptr  = (int*)(ws + 20480);     // 20480
    int*   srclist = (int*)(ws + 40960);     // 320512
    int*   gstart  = (int*)(ws + 361472);    // 512
    int*   gend    = (int*)(ws + 361984);    // 512
    float* gmu     = ws + 362496;            // 16384
    float* ginv    = ws + 378880;            // 16384
    float* gsumP   = ws + 395264;            // 16384
    float* gsqP    = ws + 411648;            // 16384
    float* A  = ws + 428032;                 // 5,120,000
    float* B  = ws + 5548032;                // 5,120,000
    float* Cb = ws + 10668032;               // 5,120,000
    float* D  = ws + 15788032;               // 5,120,000

    const int TB = 256;
    const int MB = (NN + 127)/128;
    const int NCH = 32;

    // CSR + graph bounds
    hipMemsetAsync(cursor, 0, NN*sizeof(int), stream);
    k_deg<<<gridFor(EE, TB), TB, 0, stream>>>(edst, cursor);
    k_scan<<<1, 1024, 0, stream>>>(cursor, indptr);
    hipMemsetAsync(cursor, 0, NN*sizeof(int), stream);
    k_scatter<<<gridFor(EE, TB), TB, 0, stream>>>(esrc, edst, indptr, cursor, srclist);
    k_bounds<<<gridFor(NN, TB), TB, 0, stream>>>(batch, gstart, gend);

    // ---- layer 1: 19 -> 256 (concat) ----
    k_gemm_tiled<<<dim3(MB, 8), 256, 0, stream>>>(x,  W1l, b1l, W1r, b1r, B, Cb, 19, 256);
    k_gat_w<4, false><<<NN/4, 256, 0, stream>>>(indptr, srclist, B, Cb, att1, bias1, D);
    hipMemsetAsync(gsumP, 0, GG*256*sizeof(float), stream);
    hipMemsetAsync(gsqP, 0, GG*256*sizeof(float), stream);
    k_gn_partial<256><<<dim3(GG, NCH), 256, 0, stream>>>(D, gstart, gend, gsumP, gsqP);
    k_gn_finalize<<<gridFor(GG*256, TB), TB, 0, stream>>>(gsumP, gsqP, gstart, gend, g1m, gmu, ginv, 256);
    k_gn_apply<<<gridFor((long)NN*256, TB), TB, 0, stream>>>(D, gmu, ginv, g1w, g1b, batch, A, 256);

    // ---- layer 2: 256 -> 128 (concat) ----
    k_gemm_tiled<<<dim3(MB, 4), 256, 0, stream>>>(A, W2l, b2l, W2r, b2r, B, Cb, 256, 128);
    k_gat_w<2, false><<<NN/4, 256, 0, stream>>>(indptr, srclist, B, Cb, att2, bias2, D);
    hipMemsetAsync(gsumP, 0, GG*128*sizeof(float), stream);
    hipMemsetAsync(gsqP, 0, GG*128*sizeof(float), stream);
    k_gn_partial<128><<<dim3(GG, NCH), 128, 0, stream>>>(D, gstart, gend, gsumP, gsqP);
    k_gn_finalize<<<gridFor(GG*128, TB), TB, 0, stream>>>(gsumP, gsqP, gstart, gend, g2m, gmu, ginv, 128);
    k_gn_apply<<<gridFor((long)NN*128, TB), TB, 0, stream>>>(D, gmu, ginv, g2w, g2b, batch, A, 128);

    // ---- layer 3: 128 -> 64 (head mean -> 8) ----
    k_gemm_tiled<<<dim3(MB, 2), 256, 0, stream>>>(A, W3l, b3l, W3r, b3r, B, Cb, 128, 64);
    k_gat_w<1, true><<<NN/4, 256, 0, stream>>>(indptr, srclist, B, Cb, att3, bias3, D);
    k_gn_stats8<<<GG, 64, 0, stream>>>(D, gstart, gend, g3m, gmu, ginv);
    k_gn_apply<<<gridFor((long)NN*8, TB), TB, 0, stream>>>(D, gmu, ginv, g3w, g3b, batch, A, 8);

    // ---- pool + head ----
    float* outLog  = (float*)d_out;
    float* outFeat = outLog + GG*4;
    k_pool<<<GG, 64, 0, stream>>>(A, gstart, gend, outFeat);
    k_logits<<<1, 256, 0, stream>>>(outFeat, lin_w, lin_b, outLog);
}

// Round 7
// 400.266 us; speedup vs baseline: 21.9383x; 1.1672x over previous
//
#include <hip/hip_runtime.h>
#include <math.h>

#define NN 20000
#define EE 320000
#define GG 64
#define HH 8
#define EPSV 1e-5f

static inline unsigned int gridFor(long n, int b){ return (unsigned int)((n + b - 1)/b); }

typedef __attribute__((ext_vector_type(8))) short short8;
typedef __attribute__((ext_vector_type(4))) float f32x4;

// ---------------- CSR build ----------------
__global__ void k_deg(const int* __restrict__ edst, int* __restrict__ deg){
    int e = blockIdx.x*blockDim.x + threadIdx.x;
    if (e < EE) atomicAdd(&deg[edst[e]], 1);
}

__global__ void k_scan(const int* __restrict__ deg, int* __restrict__ indptr){
    __shared__ int partial[1024];
    const int CH = (NN + 1023)/1024;   // 20
    int t = threadIdx.x;
    int base = t*CH;
    int vals[CH];
    int sum = 0;
    for (int i = 0; i < CH; ++i){
        int v = (base+i < NN) ? deg[base+i] : 0;
        vals[i] = sum; sum += v;
    }
    partial[t] = sum;
    __syncthreads();
    for (int off = 1; off < 1024; off <<= 1){
        int v = (t >= off) ? partial[t-off] : 0;
        __syncthreads();
        partial[t] += v;
        __syncthreads();
    }
    int prefix = (t > 0) ? partial[t-1] : 0;
    for (int i = 0; i < CH; ++i)
        if (base+i < NN) indptr[base+i] = prefix + vals[i];
    if (t == 1023) indptr[NN] = prefix + sum;
}

__global__ void k_scatter(const int* __restrict__ esrc, const int* __restrict__ edst,
                          const int* __restrict__ indptr, int* __restrict__ cursor,
                          int* __restrict__ srclist){
    int e = blockIdx.x*blockDim.x + threadIdx.x;
    if (e >= EE) return;
    int d = edst[e];
    int pos = atomicAdd(&cursor[d], 1);
    srclist[indptr[d] + pos] = esrc[e];
}

__global__ void k_bounds(const int* __restrict__ batch, int* __restrict__ gstart, int* __restrict__ gend){
    int i = blockIdx.x*blockDim.x + threadIdx.x;
    if (i >= NN) return;
    int b = batch[i];
    if (i == 0 || batch[i-1] != b) gstart[b] = i;
    if (i == NN-1 || batch[i+1] != b) gend[b] = i+1;
}

// ---------------- bf16-split MFMA dual linear ----------------
// [xl | xr] = h @ [Wl | Wr] + [bl | br], fp32 in/out.
// a = a_hi + a_lo (bf16 RNE); D += Ahi*Bhi + Ahi*Blo + Alo*Bhi (drop lo*lo, ~2^-18 rel).
// mfma_f32_16x16x32_bf16 layouts (m89-verified):
//   A frag: m=lane&15, k=(lane>>4)*8+j   B frag: n=lane&15, k=(lane>>4)*8+j
//   C/D:    col=lane&15, row=(lane>>4)*4+reg
#define SA 40   // LDS row stride in shorts (80B: 16B-aligned b128 frags)

__device__ __forceinline__ void split_bf16(float x, short& hi, short& lo){
    unsigned u = __float_as_uint(x);
    unsigned r = u + 0x7FFFu + ((u >> 16) & 1u);
    hi = (short)(r >> 16);
    float hf = __uint_as_float(((unsigned)(unsigned short)hi) << 16);
    float res = x - hf;
    unsigned u2 = __float_as_uint(res);
    unsigned r2 = u2 + 0x7FFFu + ((u2 >> 16) & 1u);
    lo = (short)(r2 >> 16);
}

__global__ __launch_bounds__(256)
void k_gemm_mfma(const float* __restrict__ h,
                 const float* __restrict__ Wl, const float* __restrict__ bl,
                 const float* __restrict__ Wr, const float* __restrict__ br,
                 float* __restrict__ xl, float* __restrict__ xr,
                 int K, int HC){
    __shared__ short Ahi[64*SA], Alo[64*SA], Bhi[64*SA], Blo[64*SA];
    const int tid  = threadIdx.x;
    const int lane = tid & 63;
    const int wave = tid >> 6;
    const int m0   = blockIdx.x * 64;
    const int n0g  = blockIdx.y * 64;
    const bool right = (n0g >= HC);
    const float* W  = right ? Wr : Wl;
    const float* bv = right ? br : bl;
    float* X        = right ? xr : xl;
    const int nbase = right ? (n0g - HC) : n0g;

    const int wr = (wave & 1) * 32;   // wave row offset in 64x64 tile
    const int wc = (wave >> 1) * 32;  // wave col offset

    f32x4 acc[2][2] = {};

    const int sm = tid & 63;   // staging row (A) / col (B)
    const int sq = tid >> 6;   // k-octet 0..3
    const bool kvec = ((K & 7) == 0);   // rows 16B-aligned & full octets

    for (int k0 = 0; k0 < K; k0 += 32){
        // ---- stage A: row m0+sm, k = k0+sq*8 .. +7, split to bf16 hi/lo
        {
            int gm = m0 + sm;
            int kb = k0 + sq*8;
            float v[8];
            if (gm < NN && kvec && kb + 8 <= K){
                const float* src = h + (long)gm*K + kb;
                float4 t0 = *(const float4*)src;
                float4 t1 = *(const float4*)(src+4);
                v[0]=t0.x; v[1]=t0.y; v[2]=t0.z; v[3]=t0.w;
                v[4]=t1.x; v[5]=t1.y; v[6]=t1.z; v[7]=t1.w;
            } else {
                const float* src = h + (long)gm*K + kb;
                #pragma unroll
                for (int j = 0; j < 8; ++j)
                    v[j] = (gm < NN && kb + j < K) ? src[j] : 0.f;
            }
            short hi[8], lo[8];
            #pragma unroll
            for (int j = 0; j < 8; ++j) split_bf16(v[j], hi[j], lo[j]);
            *(short8*)&Ahi[sm*SA + sq*8] = *(short8*)hi;
            *(short8*)&Alo[sm*SA + sq*8] = *(short8*)lo;
        }
        // ---- stage B: col nbase+sm, k = k0+sq*8 .. +7 (transpose to [n][k])
        {
            int n = sm;
            float v[8];
            #pragma unroll
            for (int j = 0; j < 8; ++j){
                int gk = k0 + sq*8 + j;
                v[j] = (gk < K) ? W[(long)gk*HC + nbase + n] : 0.f;
            }
            short hi[8], lo[8];
            #pragma unroll
            for (int j = 0; j < 8; ++j) split_bf16(v[j], hi[j], lo[j]);
            *(short8*)&Bhi[n*SA + sq*8] = *(short8*)hi;
            *(short8*)&Blo[n*SA + sq*8] = *(short8*)lo;
        }
        __syncthreads();

        const int fm = lane & 15;
        const int fk = (lane >> 4) * 8;
        short8 ah0 = *(short8*)&Ahi[(wr+fm)*SA + fk];
        short8 ah1 = *(short8*)&Ahi[(wr+16+fm)*SA + fk];
        short8 al0 = *(short8*)&Alo[(wr+fm)*SA + fk];
        short8 al1 = *(short8*)&Alo[(wr+16+fm)*SA + fk];
        short8 bh0 = *(short8*)&Bhi[(wc+fm)*SA + fk];
        short8 bh1 = *(short8*)&Bhi[(wc+16+fm)*SA + fk];
        short8 bl0 = *(short8*)&Blo[(wc+fm)*SA + fk];
        short8 bl1 = *(short8*)&Blo[(wc+16+fm)*SA + fk];

        acc[0][0] = __builtin_amdgcn_mfma_f32_16x16x32_bf16(al0, bh0, acc[0][0], 0,0,0);
        acc[0][0] = __builtin_amdgcn_mfma_f32_16x16x32_bf16(ah0, bl0, acc[0][0], 0,0,0);
        acc[0][0] = __builtin_amdgcn_mfma_f32_16x16x32_bf16(ah0, bh0, acc[0][0], 0,0,0);
        acc[0][1] = __builtin_amdgcn_mfma_f32_16x16x32_bf16(al0, bh1, acc[0][1], 0,0,0);
        acc[0][1] = __builtin_amdgcn_mfma_f32_16x16x32_bf16(ah0, bl1, acc[0][1], 0,0,0);
        acc[0][1] = __builtin_amdgcn_mfma_f32_16x16x32_bf16(ah0, bh1, acc[0][1], 0,0,0);
        acc[1][0] = __builtin_amdgcn_mfma_f32_16x16x32_bf16(al1, bh0, acc[1][0], 0,0,0);
        acc[1][0] = __builtin_amdgcn_mfma_f32_16x16x32_bf16(ah1, bl0, acc[1][0], 0,0,0);
        acc[1][0] = __builtin_amdgcn_mfma_f32_16x16x32_bf16(ah1, bh0, acc[1][0], 0,0,0);
        acc[1][1] = __builtin_amdgcn_mfma_f32_16x16x32_bf16(al1, bh1, acc[1][1], 0,0,0);
        acc[1][1] = __builtin_amdgcn_mfma_f32_16x16x32_bf16(ah1, bl1, acc[1][1], 0,0,0);
        acc[1][1] = __builtin_amdgcn_mfma_f32_16x16x32_bf16(ah1, bh1, acc[1][1], 0,0,0);

        __syncthreads();
    }

    // epilogue: C/D layout col=lane&15, row=(lane>>4)*4+reg
    #pragma unroll
    for (int i = 0; i < 2; ++i){
        int row0 = m0 + wr + i*16 + (lane >> 4)*4;
        #pragma unroll
        for (int j = 0; j < 2; ++j){
            int col = wc + j*16 + (lane & 15);
            float bb = bv[nbase + col];
            #pragma unroll
            for (int r = 0; r < 4; ++r){
                int gm = row0 + r;
                if (gm < NN) X[(long)gm*HC + nbase + col] = acc[i][j][r] + bb;
            }
        }
    }
}

// ---------------- fused GATv2, wave-per-node, VEC channels/lane ----------------
template<int VEC> struct VT;
template<> struct VT<1>{ using T = float;  };
template<> struct VT<2>{ using T = float2; };
template<> struct VT<4>{ using T = float4; };

__device__ __forceinline__ float lrelu(float z){ return z > 0.f ? z : 0.2f*z; }

__device__ __forceinline__ float edot(float xv, float xr, float at){
    return lrelu(xv + xr) * at;
}
__device__ __forceinline__ float edot(float2 xv, float2 xr, float2 at){
    return lrelu(xv.x+xr.x)*at.x + lrelu(xv.y+xr.y)*at.y;
}
__device__ __forceinline__ float edot(float4 xv, float4 xr, float4 at){
    return lrelu(xv.x+xr.x)*at.x + lrelu(xv.y+xr.y)*at.y
         + lrelu(xv.z+xr.z)*at.z + lrelu(xv.w+xr.w)*at.w;
}
__device__ __forceinline__ void efma(float& o, float p, float xv){ o = fmaf(p,xv,o); }
__device__ __forceinline__ void efma(float2& o, float p, float2 xv){
    o.x = fmaf(p,xv.x,o.x); o.y = fmaf(p,xv.y,o.y);
}
__device__ __forceinline__ void efma(float4& o, float p, float4 xv){
    o.x = fmaf(p,xv.x,o.x); o.y = fmaf(p,xv.y,o.y);
    o.z = fmaf(p,xv.z,o.z); o.w = fmaf(p,xv.w,o.w);
}
__device__ __forceinline__ float escale(float o, float s, float b){ return fmaf(o,s,b); }
__device__ __forceinline__ float2 escale(float2 o, float s, float2 b){
    return make_float2(fmaf(o.x,s,b.x), fmaf(o.y,s,b.y));
}
__device__ __forceinline__ float4 escale(float4 o, float s, float4 b){
    return make_float4(fmaf(o.x,s,b.x), fmaf(o.y,s,b.y), fmaf(o.z,s,b.z), fmaf(o.w,s,b.w));
}

__device__ __forceinline__ float red8(float v){
    v += __shfl_xor(v, 1);
    v += __shfl_xor(v, 2);
    v += __shfl_xor(v, 4);
    return v;
}

template<int VEC, bool MEAN>
__global__ __launch_bounds__(256)
void k_gat_w(const int* __restrict__ indptr, const int* __restrict__ srclist,
             const float* __restrict__ xl, const float* __restrict__ xr,
             const float* __restrict__ att, const float* __restrict__ bias,
             float* __restrict__ val){
    using V = typename VT<VEC>::T;
    constexpr int HC = 64*VEC;
    const int lane = threadIdx.x & 63;
    const int d = blockIdx.x*4 + (threadIdx.x >> 6);
    const int co = lane*VEC;

    const long rowd = (long)d*HC + co;
    V xrd = *(const V*)&xr[rowd];
    V at  = *(const V*)&att[co];
    V xls = *(const V*)&xl[rowd];

    float m0 = red8(edot(xls, xrd, at));
    float l = 1.0f;
    V o = xls;

    int j = indptr[d], end = indptr[d+1];
    for (; j < end; j += 4){
        int m = end - j;
        int s0 = srclist[j];
        int s1 = (m > 1) ? srclist[j+1] : s0;
        int s2 = (m > 2) ? srclist[j+2] : s0;
        int s3 = (m > 3) ? srclist[j+3] : s0;
        V x0 = *(const V*)&xl[(long)s0*HC + co];
        V x1 = *(const V*)&xl[(long)s1*HC + co];
        V x2 = *(const V*)&xl[(long)s2*HC + co];
        V x3 = *(const V*)&xl[(long)s3*HC + co];
        float a0 = red8(edot(x0, xrd, at));
        float a1 = red8(edot(x1, xrd, at));
        float a2 = red8(edot(x2, xrd, at));
        float a3 = red8(edot(x3, xrd, at));
        float p0 = __expf(a0 - m0);
        float p1 = __expf(a1 - m0);
        float p2 = __expf(a2 - m0);
        float p3 = __expf(a3 - m0);
        l += p0; efma(o, p0, x0);
        if (m > 1){ l += p1; efma(o, p1, x1); }
        if (m > 2){ l += p2; efma(o, p2, x2); }
        if (m > 3){ l += p3; efma(o, p3, x3); }
    }
    float invl = 1.0f / l;
    if (!MEAN){
        V bv = *(const V*)&bias[co];
        *(V*)&val[rowd] = escale(o, invl, bv);
    } else {
        float r = ((float&)o) * invl;
        r += __shfl_xor(r, 8);
        r += __shfl_xor(r, 16);
        r += __shfl_xor(r, 32);
        if (lane < 8) val[(long)d*8 + lane] = r*0.125f + bias[lane];
    }
}

// ---------------- GraphNorm stats: chunked partials + finalize ----------------
template<int F>
__global__ void k_gn_partial(const float* __restrict__ val,
                             const int* __restrict__ gstart, const int* __restrict__ gend,
                             float* __restrict__ gsum, float* __restrict__ gsq){
    int g = blockIdx.x, ch = blockIdx.y, nch = gridDim.y;
    int c = threadIdx.x;
    int s = gstart[g], e = gend[g];
    float sum = 0.f, sq = 0.f;
    for (int i = s + ch; i < e; i += nch){
        float v = val[(long)i*F + c];
        sum += v; sq += v*v;
    }
    if (sum != 0.f || sq != 0.f){
        atomicAdd(&gsum[g*F + c], sum);
        atomicAdd(&gsq[g*F + c], sq);
    }
}

__global__ void k_gn_finalize(const float* __restrict__ gsum, const float* __restrict__ gsq,
                              const int* __restrict__ gstart, const int* __restrict__ gend,
                              const float* __restrict__ ms,
                              float* __restrict__ gmu, float* __restrict__ ginv, int F){
    int idx = blockIdx.x*blockDim.x + threadIdx.x;
    if (idx >= GG*F) return;
    int g = idx / F, c = idx - g*F;
    int cnti = gend[g] - gstart[g];
    float cn = cnti > 0 ? (float)cnti : 1.f;
    float mean = gsum[idx] / cn;
    float mu = mean * ms[c];
    float var = gsq[idx]/cn - 2.f*mu*mean + mu*mu;
    gmu[idx]  = mu;
    ginv[idx] = rsqrtf(var + EPSV);
}

__global__ void k_gn_stats8(const float* __restrict__ val,
                            const int* __restrict__ gstart, const int* __restrict__ gend,
                            const float* __restrict__ ms,
                            float* __restrict__ gmu, float* __restrict__ ginv){
    const int F = 8;
    int g = blockIdx.x;
    int t = threadIdx.x;
    int c = t % F, r = t / F;
    int s = gstart[g], e = gend[g];
    float sum = 0.f, sq = 0.f;
    for (int i = s + r; i < e; i += 8){
        float v = val[(long)i*F + c];
        sum += v; sq += v*v;
    }
    #pragma unroll
    for (int mask = 8; mask < 64; mask <<= 1){
        sum += __shfl_xor(sum, mask, 64);
        sq  += __shfl_xor(sq,  mask, 64);
    }
    if (r == 0){
        int cnti = e - s;
        float cn = cnti > 0 ? (float)cnti : 1.f;
        float mean = sum / cn;
        float mu = mean * ms[c];
        float var = sq/cn - 2.f*mu*mean + mu*mu;
        gmu[g*F + c]  = mu;
        ginv[g*F + c] = rsqrtf(var + EPSV);
    }
}

__global__ void k_gn_apply(const float* __restrict__ val,
                           const float* __restrict__ gmu, const float* __restrict__ ginv,
                           const float* __restrict__ w, const float* __restrict__ b,
                           const int* __restrict__ batch, float* __restrict__ out, int F){
    int idx = blockIdx.x*blockDim.x + threadIdx.x;
    if (idx >= NN*F) return;
    int n = idx / F, c = idx - n*F, g = batch[n];
    float v = (val[idx] - gmu[g*F + c]) * ginv[g*F + c] * w[c] + b[c];
    out[idx] = fmaxf(v, 0.f);
}

// ---------------- pool + head ----------------
__global__ void k_pool(const float* __restrict__ h,
                       const int* __restrict__ gstart, const int* __restrict__ gend,
                       float* __restrict__ outFeat){
    int g = blockIdx.x;
    int t = threadIdx.x;
    int c = t & 7, r = t >> 3;
    int s = gstart[g], e = gend[g];
    float sum = 0.f;
    for (int i = s + r; i < e; i += 8) sum += h[(long)i*8 + c];
    sum += __shfl_xor(sum, 8, 64);
    sum += __shfl_xor(sum, 16, 64);
    sum += __shfl_xor(sum, 32, 64);
    if (t < 8){
        int cnti = e - s;
        float cn = cnti > 0 ? (float)cnti : 1.f;
        outFeat[g*8 + t] = sum / cn;
    }
}

__global__ void k_logits(const float* __restrict__ feat, const float* __restrict__ lw,
                         const float* __restrict__ lb, float* __restrict__ outLog){
    int idx = blockIdx.x*blockDim.x + threadIdx.x;
    if (idx >= GG*4) return;
    int g = idx >> 2, j = idx & 3;
    float a = lb[j];
    for (int c = 0; c < 8; ++c) a += feat[g*8 + c] * lw[c*4 + j];
    outLog[idx] = a;
}

extern "C" void kernel_launch(void* const* d_in, const int* in_sizes, int n_in,
                              void* d_out, int out_size, void* d_ws, size_t ws_size,
                              hipStream_t stream) {
    const float* x     = (const float*)d_in[0];
    const int*   ei    = (const int*)  d_in[1];
    const int*   batch = (const int*)  d_in[2];
    const float* W1l = (const float*)d_in[3];  const float* b1l = (const float*)d_in[4];
    const float* W1r = (const float*)d_in[5];  const float* b1r = (const float*)d_in[6];
    const float* att1= (const float*)d_in[7];  const float* bias1=(const float*)d_in[8];
    const float* g1w = (const float*)d_in[9];  const float* g1b = (const float*)d_in[10];
    const float* g1m = (const float*)d_in[11];
    const float* W2l = (const float*)d_in[12]; const float* b2l = (const float*)d_in[13];
    const float* W2r = (const float*)d_in[14]; const float* b2r = (const float*)d_in[15];
    const float* att2= (const float*)d_in[16]; const float* bias2=(const float*)d_in[17];
    const float* g2w = (const float*)d_in[18]; const float* g2b = (const float*)d_in[19];
    const float* g2m = (const float*)d_in[20];
    const float* W3l = (const float*)d_in[21]; const float* b3l = (const float*)d_in[22];
    const float* W3r = (const float*)d_in[23]; const float* b3r = (const float*)d_in[24];
    const float* att3= (const float*)d_in[25]; const float* bias3=(const float*)d_in[26];
    const float* g3w = (const float*)d_in[27]; const float* g3b = (const float*)d_in[28];
    const float* g3m = (const float*)d_in[29];
    const float* lin_w=(const float*)d_in[30]; const float* lin_b=(const float*)d_in[31];

    const int* esrc = ei;
    const int* edst = ei + EE;

    // ---- workspace arena (units of 4B) ----
    float* ws = (float*)d_ws;
    int*   cursor  = (int*)(ws + 0);         // 20480
    int*   indptr  = (int*)(ws + 20480);     // 20480
    int*   srclist = (int*)(ws + 40960);     // 320512
    int*   gstart  = (int*)(ws + 361472);    // 512
    int*   gend    = (int*)(ws + 361984);    // 512
    float* gmu     = ws + 362496;            // 16384
    float* ginv    = ws + 378880;            // 16384
    float* gsumP   = ws + 395264;            // 16384
    float* gsqP    = ws + 411648;            // 16384
    float* A  = ws + 428032;                 // 5,120,000
    float* B  = ws + 5548032;                // 5,120,000
    float* Cb = ws + 10668032;               // 5,120,000
    float* D  = ws + 15788032;               // 5,120,000

    const int TB = 256;
    const int MBm = (NN + 63)/64;    // 313 row tiles for MFMA gemm
    const int NCH = 32;

    // CSR + graph bounds
    hipMemsetAsync(cursor, 0, NN*sizeof(int), stream);
    k_deg<<<gridFor(EE, TB), TB, 0, stream>>>(edst, cursor);
    k_scan<<<1, 1024, 0, stream>>>(cursor, indptr);
    hipMemsetAsync(cursor, 0, NN*sizeof(int), stream);
    k_scatter<<<gridFor(EE, TB), TB, 0, stream>>>(esrc, edst, indptr, cursor, srclist);
    k_bounds<<<gridFor(NN, TB), TB, 0, stream>>>(batch, gstart, gend);

    // ---- layer 1: 19 -> 256 (concat) ----
    k_gemm_mfma<<<dim3(MBm, 8), 256, 0, stream>>>(x,  W1l, b1l, W1r, b1r, B, Cb, 19, 256);
    k_gat_w<4, false><<<NN/4, 256, 0, stream>>>(indptr, srclist, B, Cb, att1, bias1, D);
    hipMemsetAsync(gsumP, 0, GG*256*sizeof(float), stream);
    hipMemsetAsync(gsqP, 0, GG*256*sizeof(float), stream);
    k_gn_partial<256><<<dim3(GG, NCH), 256, 0, stream>>>(D, gstart, gend, gsumP, gsqP);
    k_gn_finalize<<<gridFor(GG*256, TB), TB, 0, stream>>>(gsumP, gsqP, gstart, gend, g1m, gmu, ginv, 256);
    k_gn_apply<<<gridFor((long)NN*256, TB), TB, 0, stream>>>(D, gmu, ginv, g1w, g1b, batch, A, 256);

    // ---- layer 2: 256 -> 128 (concat) ----
    k_gemm_mfma<<<dim3(MBm, 4), 256, 0, stream>>>(A, W2l, b2l, W2r, b2r, B, Cb, 256, 128);
    k_gat_w<2, false><<<NN/4, 256, 0, stream>>>(indptr, srclist, B, Cb, att2, bias2, D);
    hipMemsetAsync(gsumP, 0, GG*128*sizeof(float), stream);
    hipMemsetAsync(gsqP, 0, GG*128*sizeof(float), stream);
    k_gn_partial<128><<<dim3(GG, NCH), 128, 0, stream>>>(D, gstart, gend, gsumP, gsqP);
    k_gn_finalize<<<gridFor(GG*128, TB), TB, 0, stream>>>(gsumP, gsqP, gstart, gend, g2m, gmu, ginv, 128);
    k_gn_apply<<<gridFor((long)NN*128, TB), TB, 0, stream>>>(D, gmu, ginv, g2w, g2b, batch, A, 128);

    // ---- layer 3: 128 -> 64 (head mean -> 8) ----
    k_gemm_mfma<<<dim3(MBm, 2), 256, 0, stream>>>(A, W3l, b3l, W3r, b3r, B, Cb, 128, 64);
    k_gat_w<1, true><<<NN/4, 256, 0, stream>>>(indptr, srclist, B, Cb, att3, bias3, D);
    k_gn_stats8<<<GG, 64, 0, stream>>>(D, gstart, gend, g3m, gmu, ginv);
    k_gn_apply<<<gridFor((long)NN*8, TB), TB, 0, stream>>>(D, gmu, ginv, g3w, g3b, batch, A, 8);

    // ---- pool + head ----
    float* outLog  = (float*)d_out;
    float* outFeat = outLog + GG*4;
    k_pool<<<GG, 64, 0, stream>>>(A, gstart, gend, outFeat);
    k_logits<<<1, 256, 0, stream>>>(outFeat, lin_w, lin_b, outLog);
}

// Round 8
// 379.518 us; speedup vs baseline: 23.1377x; 1.0547x over previous
//
#include <hip/hip_runtime.h>
#include <math.h>

#define NN 20000
#define EE 320000
#define GG 64
#define HH 8
#define EPSV 1e-5f

static inline unsigned int gridFor(long n, int b){ return (unsigned int)((n + b - 1)/b); }

typedef __attribute__((ext_vector_type(8))) short short8;
typedef __attribute__((ext_vector_type(4))) float f32x4;

// ---------------- CSR build ----------------
__global__ void k_deg(const int* __restrict__ edst, int* __restrict__ deg){
    int e = blockIdx.x*blockDim.x + threadIdx.x;
    if (e < EE) atomicAdd(&deg[edst[e]], 1);
}

__global__ void k_scan(const int* __restrict__ deg, int* __restrict__ indptr){
    __shared__ int partial[1024];
    const int CH = (NN + 1023)/1024;   // 20
    int t = threadIdx.x;
    int base = t*CH;
    int vals[CH];
    int sum = 0;
    for (int i = 0; i < CH; ++i){
        int v = (base+i < NN) ? deg[base+i] : 0;
        vals[i] = sum; sum += v;
    }
    partial[t] = sum;
    __syncthreads();
    for (int off = 1; off < 1024; off <<= 1){
        int v = (t >= off) ? partial[t-off] : 0;
        __syncthreads();
        partial[t] += v;
        __syncthreads();
    }
    int prefix = (t > 0) ? partial[t-1] : 0;
    for (int i = 0; i < CH; ++i)
        if (base+i < NN) indptr[base+i] = prefix + vals[i];
    if (t == 1023) indptr[NN] = prefix + sum;
}

__global__ void k_scatter(const int* __restrict__ esrc, const int* __restrict__ edst,
                          const int* __restrict__ indptr, int* __restrict__ cursor,
                          int* __restrict__ srclist){
    int e = blockIdx.x*blockDim.x + threadIdx.x;
    if (e >= EE) return;
    int d = edst[e];
    int pos = atomicAdd(&cursor[d], 1);
    srclist[indptr[d] + pos] = esrc[e];
}

__global__ void k_bounds(const int* __restrict__ batch, int* __restrict__ gstart, int* __restrict__ gend){
    int i = blockIdx.x*blockDim.x + threadIdx.x;
    if (i >= NN) return;
    int b = batch[i];
    if (i == 0 || batch[i-1] != b) gstart[b] = i;
    if (i == NN-1 || batch[i+1] != b) gend[b] = i+1;
}

// ---------------- bf16-split MFMA dual linear (+ optional fused GraphNorm+ReLU on input) ----------------
// [xl | xr] = f(h) @ [Wl | Wr] + [bl | br], fp32 in/out, f = identity or relu(gn(.)).
#define SA 40   // LDS row stride in shorts (80B: 16B-aligned b128 frags)

__device__ __forceinline__ void split_bf16(float x, short& hi, short& lo){
    unsigned u = __float_as_uint(x);
    unsigned r = u + 0x7FFFu + ((u >> 16) & 1u);
    hi = (short)(r >> 16);
    float hf = __uint_as_float(((unsigned)(unsigned short)hi) << 16);
    float res = x - hf;
    unsigned u2 = __float_as_uint(res);
    unsigned r2 = u2 + 0x7FFFu + ((u2 >> 16) & 1u);
    lo = (short)(r2 >> 16);
}

template<bool NORM>
__global__ __launch_bounds__(256)
void k_gemm_mfma(const float* __restrict__ h,
                 const float* __restrict__ Wl, const float* __restrict__ bl,
                 const float* __restrict__ Wr, const float* __restrict__ br,
                 const float* __restrict__ gmu, const float* __restrict__ ginv,
                 const float* __restrict__ nw, const float* __restrict__ nb,
                 const int* __restrict__ batch,
                 float* __restrict__ xl, float* __restrict__ xr,
                 int K, int HC){
    __shared__ short Ahi[64*SA], Alo[64*SA], Bhi[64*SA], Blo[64*SA];
    const int tid  = threadIdx.x;
    const int lane = tid & 63;
    const int wave = tid >> 6;
    const int m0   = blockIdx.x * 64;
    const int n0g  = blockIdx.y * 64;
    const bool right = (n0g >= HC);
    const float* W  = right ? Wr : Wl;
    const float* bv = right ? br : bl;
    float* X        = right ? xr : xl;
    const int nbase = right ? (n0g - HC) : n0g;

    const int wr = (wave & 1) * 32;
    const int wc = (wave >> 1) * 32;

    f32x4 acc[2][2] = {};

    const int sm = tid & 63;
    const int sq = tid >> 6;
    const bool kvec = ((K & 7) == 0);

    for (int k0 = 0; k0 < K; k0 += 32){
        // ---- stage A: row m0+sm, k = k0+sq*8 .. +7, optional norm, split to bf16 hi/lo
        {
            int gm = m0 + sm;
            int kb = k0 + sq*8;
            float v[8];
            if (gm < NN && kvec && kb + 8 <= K){
                const float* src = h + (long)gm*K + kb;
                float4 t0 = *(const float4*)src;
                float4 t1 = *(const float4*)(src+4);
                v[0]=t0.x; v[1]=t0.y; v[2]=t0.z; v[3]=t0.w;
                v[4]=t1.x; v[5]=t1.y; v[6]=t1.z; v[7]=t1.w;
            } else {
                const float* src = h + (long)gm*K + kb;
                #pragma unroll
                for (int j = 0; j < 8; ++j)
                    v[j] = (gm < NN && kb + j < K) ? src[j] : 0.f;
            }
            if (NORM && gm < NN){
                int g = batch[gm];
                const float* mu = gmu + (long)g*K;
                const float* iv = ginv + (long)g*K;
                #pragma unroll
                for (int j = 0; j < 8; ++j){
                    int c = kb + j;
                    float t = (v[j] - mu[c]) * iv[c] * nw[c] + nb[c];
                    v[j] = fmaxf(t, 0.f);
                }
            }
            short hi[8], lo[8];
            #pragma unroll
            for (int j = 0; j < 8; ++j) split_bf16(v[j], hi[j], lo[j]);
            *(short8*)&Ahi[sm*SA + sq*8] = *(short8*)hi;
            *(short8*)&Alo[sm*SA + sq*8] = *(short8*)lo;
        }
        // ---- stage B
        {
            int n = sm;
            float v[8];
            #pragma unroll
            for (int j = 0; j < 8; ++j){
                int gk = k0 + sq*8 + j;
                v[j] = (gk < K) ? W[(long)gk*HC + nbase + n] : 0.f;
            }
            short hi[8], lo[8];
            #pragma unroll
            for (int j = 0; j < 8; ++j) split_bf16(v[j], hi[j], lo[j]);
            *(short8*)&Bhi[n*SA + sq*8] = *(short8*)hi;
            *(short8*)&Blo[n*SA + sq*8] = *(short8*)lo;
        }
        __syncthreads();

        const int fm = lane & 15;
        const int fk = (lane >> 4) * 8;
        short8 ah0 = *(short8*)&Ahi[(wr+fm)*SA + fk];
        short8 ah1 = *(short8*)&Ahi[(wr+16+fm)*SA + fk];
        short8 al0 = *(short8*)&Alo[(wr+fm)*SA + fk];
        short8 al1 = *(short8*)&Alo[(wr+16+fm)*SA + fk];
        short8 bh0 = *(short8*)&Bhi[(wc+fm)*SA + fk];
        short8 bh1 = *(short8*)&Bhi[(wc+16+fm)*SA + fk];
        short8 bl0 = *(short8*)&Blo[(wc+fm)*SA + fk];
        short8 bl1 = *(short8*)&Blo[(wc+16+fm)*SA + fk];

        acc[0][0] = __builtin_amdgcn_mfma_f32_16x16x32_bf16(al0, bh0, acc[0][0], 0,0,0);
        acc[0][0] = __builtin_amdgcn_mfma_f32_16x16x32_bf16(ah0, bl0, acc[0][0], 0,0,0);
        acc[0][0] = __builtin_amdgcn_mfma_f32_16x16x32_bf16(ah0, bh0, acc[0][0], 0,0,0);
        acc[0][1] = __builtin_amdgcn_mfma_f32_16x16x32_bf16(al0, bh1, acc[0][1], 0,0,0);
        acc[0][1] = __builtin_amdgcn_mfma_f32_16x16x32_bf16(ah0, bl1, acc[0][1], 0,0,0);
        acc[0][1] = __builtin_amdgcn_mfma_f32_16x16x32_bf16(ah0, bh1, acc[0][1], 0,0,0);
        acc[1][0] = __builtin_amdgcn_mfma_f32_16x16x32_bf16(al1, bh0, acc[1][0], 0,0,0);
        acc[1][0] = __builtin_amdgcn_mfma_f32_16x16x32_bf16(ah1, bl0, acc[1][0], 0,0,0);
        acc[1][0] = __builtin_amdgcn_mfma_f32_16x16x32_bf16(ah1, bh0, acc[1][0], 0,0,0);
        acc[1][1] = __builtin_amdgcn_mfma_f32_16x16x32_bf16(al1, bh1, acc[1][1], 0,0,0);
        acc[1][1] = __builtin_amdgcn_mfma_f32_16x16x32_bf16(ah1, bl1, acc[1][1], 0,0,0);
        acc[1][1] = __builtin_amdgcn_mfma_f32_16x16x32_bf16(ah1, bh1, acc[1][1], 0,0,0);

        __syncthreads();
    }

    #pragma unroll
    for (int i = 0; i < 2; ++i){
        int row0 = m0 + wr + i*16 + (lane >> 4)*4;
        #pragma unroll
        for (int j = 0; j < 2; ++j){
            int col = wc + j*16 + (lane & 15);
            float bb = bv[nbase + col];
            #pragma unroll
            for (int r = 0; r < 4; ++r){
                int gm = row0 + r;
                if (gm < NN) X[(long)gm*HC + nbase + col] = acc[i][j][r] + bb;
            }
        }
    }
}

// ---------------- fused GATv2, wave-per-node, VEC channels/lane ----------------
template<int VEC> struct VT;
template<> struct VT<1>{ using T = float;  };
template<> struct VT<2>{ using T = float2; };
template<> struct VT<4>{ using T = float4; };

__device__ __forceinline__ float lrelu(float z){ return z > 0.f ? z : 0.2f*z; }

__device__ __forceinline__ float edot(float xv, float xr, float at){
    return lrelu(xv + xr) * at;
}
__device__ __forceinline__ float edot(float2 xv, float2 xr, float2 at){
    return lrelu(xv.x+xr.x)*at.x + lrelu(xv.y+xr.y)*at.y;
}
__device__ __forceinline__ float edot(float4 xv, float4 xr, float4 at){
    return lrelu(xv.x+xr.x)*at.x + lrelu(xv.y+xr.y)*at.y
         + lrelu(xv.z+xr.z)*at.z + lrelu(xv.w+xr.w)*at.w;
}
__device__ __forceinline__ void efma(float& o, float p, float xv){ o = fmaf(p,xv,o); }
__device__ __forceinline__ void efma(float2& o, float p, float2 xv){
    o.x = fmaf(p,xv.x,o.x); o.y = fmaf(p,xv.y,o.y);
}
__device__ __forceinline__ void efma(float4& o, float p, float4 xv){
    o.x = fmaf(p,xv.x,o.x); o.y = fmaf(p,xv.y,o.y);
    o.z = fmaf(p,xv.z,o.z); o.w = fmaf(p,xv.w,o.w);
}
__device__ __forceinline__ float escale(float o, float s, float b){ return fmaf(o,s,b); }
__device__ __forceinline__ float2 escale(float2 o, float s, float2 b){
    return make_float2(fmaf(o.x,s,b.x), fmaf(o.y,s,b.y));
}
__device__ __forceinline__ float4 escale(float4 o, float s, float4 b){
    return make_float4(fmaf(o.x,s,b.x), fmaf(o.y,s,b.y), fmaf(o.z,s,b.z), fmaf(o.w,s,b.w));
}

__device__ __forceinline__ float red8(float v){
    v += __shfl_xor(v, 1);
    v += __shfl_xor(v, 2);
    v += __shfl_xor(v, 4);
    return v;
}

template<int VEC, bool MEAN>
__global__ __launch_bounds__(256)
void k_gat_w(const int* __restrict__ indptr, const int* __restrict__ srclist,
             const float* __restrict__ xl, const float* __restrict__ xr,
             const float* __restrict__ att, const float* __restrict__ bias,
             float* __restrict__ val){
    using V = typename VT<VEC>::T;
    constexpr int HC = 64*VEC;
    const int lane = threadIdx.x & 63;
    const int d = blockIdx.x*4 + (threadIdx.x >> 6);
    const int co = lane*VEC;

    const long rowd = (long)d*HC + co;
    V xrd = *(const V*)&xr[rowd];
    V at  = *(const V*)&att[co];
    V xls = *(const V*)&xl[rowd];

    float m0 = red8(edot(xls, xrd, at));
    float l = 1.0f;
    V o = xls;

    int j = indptr[d], end = indptr[d+1];   // wave-uniform
    // 8-deep unrolled main loop: 8 gathers in flight
    for (; j + 8 <= end; j += 8){
        int s0 = srclist[j+0], s1 = srclist[j+1], s2 = srclist[j+2], s3 = srclist[j+3];
        int s4 = srclist[j+4], s5 = srclist[j+5], s6 = srclist[j+6], s7 = srclist[j+7];
        V x0 = *(const V*)&xl[(long)s0*HC + co];
        V x1 = *(const V*)&xl[(long)s1*HC + co];
        V x2 = *(const V*)&xl[(long)s2*HC + co];
        V x3 = *(const V*)&xl[(long)s3*HC + co];
        V x4 = *(const V*)&xl[(long)s4*HC + co];
        V x5 = *(const V*)&xl[(long)s5*HC + co];
        V x6 = *(const V*)&xl[(long)s6*HC + co];
        V x7 = *(const V*)&xl[(long)s7*HC + co];
        float a0 = red8(edot(x0, xrd, at));
        float a1 = red8(edot(x1, xrd, at));
        float a2 = red8(edot(x2, xrd, at));
        float a3 = red8(edot(x3, xrd, at));
        float a4 = red8(edot(x4, xrd, at));
        float a5 = red8(edot(x5, xrd, at));
        float a6 = red8(edot(x6, xrd, at));
        float a7 = red8(edot(x7, xrd, at));
        float p0 = __expf(a0 - m0), p1 = __expf(a1 - m0);
        float p2 = __expf(a2 - m0), p3 = __expf(a3 - m0);
        float p4 = __expf(a4 - m0), p5 = __expf(a5 - m0);
        float p6 = __expf(a6 - m0), p7 = __expf(a7 - m0);
        l += ((p0+p1)+(p2+p3)) + ((p4+p5)+(p6+p7));
        efma(o, p0, x0); efma(o, p1, x1); efma(o, p2, x2); efma(o, p3, x3);
        efma(o, p4, x4); efma(o, p5, x5); efma(o, p6, x6); efma(o, p7, x7);
    }
    // masked remainder (m < 8, wave-uniform guards)
    for (; j < end; j += 4){
        int m = end - j;
        int s0 = srclist[j];
        int s1 = (m > 1) ? srclist[j+1] : s0;
        int s2 = (m > 2) ? srclist[j+2] : s0;
        int s3 = (m > 3) ? srclist[j+3] : s0;
        V x0 = *(const V*)&xl[(long)s0*HC + co];
        V x1 = *(const V*)&xl[(long)s1*HC + co];
        V x2 = *(const V*)&xl[(long)s2*HC + co];
        V x3 = *(const V*)&xl[(long)s3*HC + co];
        float a0 = red8(edot(x0, xrd, at));
        float a1 = red8(edot(x1, xrd, at));
        float a2 = red8(edot(x2, xrd, at));
        float a3 = red8(edot(x3, xrd, at));
        float p0 = __expf(a0 - m0);
        float p1 = __expf(a1 - m0);
        float p2 = __expf(a2 - m0);
        float p3 = __expf(a3 - m0);
        l += p0; efma(o, p0, x0);
        if (m > 1){ l += p1; efma(o, p1, x1); }
        if (m > 2){ l += p2; efma(o, p2, x2); }
        if (m > 3){ l += p3; efma(o, p3, x3); }
    }
    float invl = 1.0f / l;
    if (!MEAN){
        V bv = *(const V*)&bias[co];
        *(V*)&val[rowd] = escale(o, invl, bv);
    } else {
        float r = ((float&)o) * invl;
        r += __shfl_xor(r, 8);
        r += __shfl_xor(r, 16);
        r += __shfl_xor(r, 32);
        if (lane < 8) val[(long)d*8 + lane] = r*0.125f + bias[lane];
    }
}

// ---------------- GraphNorm stats: chunked partials + finalize ----------------
template<int F>
__global__ void k_gn_partial(const float* __restrict__ val,
                             const int* __restrict__ gstart, const int* __restrict__ gend,
                             float* __restrict__ gsum, float* __restrict__ gsq){
    int g = blockIdx.x, ch = blockIdx.y, nch = gridDim.y;
    int c = threadIdx.x;
    int s = gstart[g], e = gend[g];
    float sum = 0.f, sq = 0.f;
    for (int i = s + ch; i < e; i += nch){
        float v = val[(long)i*F + c];
        sum += v; sq += v*v;
    }
    if (sum != 0.f || sq != 0.f){
        atomicAdd(&gsum[g*F + c], sum);
        atomicAdd(&gsq[g*F + c], sq);
    }
}

__global__ void k_gn_finalize(const float* __restrict__ gsum, const float* __restrict__ gsq,
                              const int* __restrict__ gstart, const int* __restrict__ gend,
                              const float* __restrict__ ms,
                              float* __restrict__ gmu, float* __restrict__ ginv, int F){
    int idx = blockIdx.x*blockDim.x + threadIdx.x;
    if (idx >= GG*F) return;
    int g = idx / F, c = idx - g*F;
    int cnti = gend[g] - gstart[g];
    float cn = cnti > 0 ? (float)cnti : 1.f;
    float mean = gsum[idx] / cn;
    float mu = mean * ms[c];
    float var = gsq[idx]/cn - 2.f*mu*mean + mu*mu;
    gmu[idx]  = mu;
    ginv[idx] = rsqrtf(var + EPSV);
}

__global__ void k_gn_stats8(const float* __restrict__ val,
                            const int* __restrict__ gstart, const int* __restrict__ gend,
                            const float* __restrict__ ms,
                            float* __restrict__ gmu, float* __restrict__ ginv){
    const int F = 8;
    int g = blockIdx.x;
    int t = threadIdx.x;
    int c = t % F, r = t / F;
    int s = gstart[g], e = gend[g];
    float sum = 0.f, sq = 0.f;
    for (int i = s + r; i < e; i += 8){
        float v = val[(long)i*F + c];
        sum += v; sq += v*v;
    }
    #pragma unroll
    for (int mask = 8; mask < 64; mask <<= 1){
        sum += __shfl_xor(sum, mask, 64);
        sq  += __shfl_xor(sq,  mask, 64);
    }
    if (r == 0){
        int cnti = e - s;
        float cn = cnti > 0 ? (float)cnti : 1.f;
        float mean = sum / cn;
        float mu = mean * ms[c];
        float var = sq/cn - 2.f*mu*mean + mu*mu;
        gmu[g*F + c]  = mu;
        ginv[g*F + c] = rsqrtf(var + EPSV);
    }
}

// ---------------- pool with fused layer-3 GraphNorm+ReLU ----------------
__global__ void k_pool_gn(const float* __restrict__ D,
                          const int* __restrict__ gstart, const int* __restrict__ gend,
                          const float* __restrict__ gmu, const float* __restrict__ ginv,
                          const float* __restrict__ w, const float* __restrict__ b,
                          float* __restrict__ outFeat){
    int g = blockIdx.x;
    int t = threadIdx.x;
    int c = t & 7, r = t >> 3;
    int s = gstart[g], e = gend[g];
    float mu = gmu[g*8 + c], iv = ginv[g*8 + c], wc = w[c], bc = b[c];
    float sum = 0.f;
    for (int i = s + r; i < e; i += 8){
        float v = (D[(long)i*8 + c] - mu) * iv * wc + bc;
        sum += fmaxf(v, 0.f);
    }
    sum += __shfl_xor(sum, 8, 64);
    sum += __shfl_xor(sum, 16, 64);
    sum += __shfl_xor(sum, 32, 64);
    if (t < 8){
        int cnti = e - s;
        float cn = cnti > 0 ? (float)cnti : 1.f;
        outFeat[g*8 + t] = sum / cn;
    }
}

__global__ void k_logits(const float* __restrict__ feat, const float* __restrict__ lw,
                         const float* __restrict__ lb, float* __restrict__ outLog){
    int idx = blockIdx.x*blockDim.x + threadIdx.x;
    if (idx >= GG*4) return;
    int g = idx >> 2, j = idx & 3;
    float a = lb[j];
    for (int c = 0; c < 8; ++c) a += feat[g*8 + c] * lw[c*4 + j];
    outLog[idx] = a;
}

extern "C" void kernel_launch(void* const* d_in, const int* in_sizes, int n_in,
                              void* d_out, int out_size, void* d_ws, size_t ws_size,
                              hipStream_t stream) {
    const float* x     = (const float*)d_in[0];
    const int*   ei    = (const int*)  d_in[1];
    const int*   batch = (const int*)  d_in[2];
    const float* W1l = (const float*)d_in[3];  const float* b1l = (const float*)d_in[4];
    const float* W1r = (const float*)d_in[5];  const float* b1r = (const float*)d_in[6];
    const float* att1= (const float*)d_in[7];  const float* bias1=(const float*)d_in[8];
    const float* g1w = (const float*)d_in[9];  const float* g1b = (const float*)d_in[10];
    const float* g1m = (const float*)d_in[11];
    const float* W2l = (const float*)d_in[12]; const float* b2l = (const float*)d_in[13];
    const float* W2r = (const float*)d_in[14]; const float* b2r = (const float*)d_in[15];
    const float* att2= (const float*)d_in[16]; const float* bias2=(const float*)d_in[17];
    const float* g2w = (const float*)d_in[18]; const float* g2b = (const float*)d_in[19];
    const float* g2m = (const float*)d_in[20];
    const float* W3l = (const float*)d_in[21]; const float* b3l = (const float*)d_in[22];
    const float* W3r = (const float*)d_in[23]; const float* b3r = (const float*)d_in[24];
    const float* att3= (const float*)d_in[25]; const float* bias3=(const float*)d_in[26];
    const float* g3w = (const float*)d_in[27]; const float* g3b = (const float*)d_in[28];
    const float* g3m = (const float*)d_in[29];
    const float* lin_w=(const float*)d_in[30]; const float* lin_b=(const float*)d_in[31];

    const int* esrc = ei;
    const int* edst = ei + EE;

    // ---- workspace arena (units of 4B) ----
    float* ws = (float*)d_ws;
    int*   cursor  = (int*)(ws + 0);         // 20480
    int*   indptr  = (int*)(ws + 20480);     // 20480
    int*   srclist = (int*)(ws + 40960);     // 320512
    int*   gstart  = (int*)(ws + 361472);    // 512
    int*   gend    = (int*)(ws + 361984);    // 512
    float* gmu     = ws + 362496;            // 16384
    float* ginv    = ws + 378880;            // 16384
    float* gsumP   = ws + 395264;            // 16384
    float* gsqP    = ws + 411648;            // 16384
    float* B  = ws + 428032;                 // 5,120,000 (xl)
    float* Cb = ws + 5548032;                // 5,120,000 (xr)
    float* D  = ws + 10668032;               // 5,120,000 (pre-norm GAT out)

    const int TB = 256;
    const int MBm = (NN + 63)/64;    // 313 row tiles
    const int NCH = 32;

    // CSR + graph bounds
    hipMemsetAsync(cursor, 0, NN*sizeof(int), stream);
    k_deg<<<gridFor(EE, TB), TB, 0, stream>>>(edst, cursor);
    k_scan<<<1, 1024, 0, stream>>>(cursor, indptr);
    hipMemsetAsync(cursor, 0, NN*sizeof(int), stream);
    k_scatter<<<gridFor(EE, TB), TB, 0, stream>>>(esrc, edst, indptr, cursor, srclist);
    k_bounds<<<gridFor(NN, TB), TB, 0, stream>>>(batch, gstart, gend);

    // ---- layer 1: 19 -> 256 (concat) ----
    k_gemm_mfma<false><<<dim3(MBm, 8), 256, 0, stream>>>(x, W1l, b1l, W1r, b1r,
        nullptr, nullptr, nullptr, nullptr, nullptr, B, Cb, 19, 256);
    k_gat_w<4, false><<<NN/4, 256, 0, stream>>>(indptr, srclist, B, Cb, att1, bias1, D);
    hipMemsetAsync(gsumP, 0, GG*256*sizeof(float), stream);
    hipMemsetAsync(gsqP, 0, GG*256*sizeof(float), stream);
    k_gn_partial<256><<<dim3(GG, NCH), 256, 0, stream>>>(D, gstart, gend, gsumP, gsqP);
    k_gn_finalize<<<gridFor(GG*256, TB), TB, 0, stream>>>(gsumP, gsqP, gstart, gend, g1m, gmu, ginv, 256);

    // ---- layer 2: 256 -> 128 (concat); layer-1 norm fused into A-staging ----
    k_gemm_mfma<true><<<dim3(MBm, 4), 256, 0, stream>>>(D, W2l, b2l, W2r, b2r,
        gmu, ginv, g1w, g1b, batch, B, Cb, 256, 128);
    k_gat_w<2, false><<<NN/4, 256, 0, stream>>>(indptr, srclist, B, Cb, att2, bias2, D);
    hipMemsetAsync(gsumP, 0, GG*128*sizeof(float), stream);
    hipMemsetAsync(gsqP, 0, GG*128*sizeof(float), stream);
    k_gn_partial<128><<<dim3(GG, NCH), 128, 0, stream>>>(D, gstart, gend, gsumP, gsqP);
    k_gn_finalize<<<gridFor(GG*128, TB), TB, 0, stream>>>(gsumP, gsqP, gstart, gend, g2m, gmu, ginv, 128);

    // ---- layer 3: 128 -> 64 (head mean -> 8); layer-2 norm fused ----
    k_gemm_mfma<true><<<dim3(MBm, 2), 256, 0, stream>>>(D, W3l, b3l, W3r, b3r,
        gmu, ginv, g2w, g2b, batch, B, Cb, 128, 64);
    k_gat_w<1, true><<<NN/4, 256, 0, stream>>>(indptr, srclist, B, Cb, att3, bias3, D);
    k_gn_stats8<<<GG, 64, 0, stream>>>(D, gstart, gend, g3m, gmu, ginv);

    // ---- pool (layer-3 norm fused) + head ----
    float* outLog  = (float*)d_out;
    float* outFeat = outLog + GG*4;
    k_pool_gn<<<GG, 64, 0, stream>>>(D, gstart, gend, gmu, ginv, g3w, g3b, outFeat);
    k_logits<<<1, 256, 0, stream>>>(outFeat, lin_w, lin_b, outLog);
}

// Round 9
// 363.769 us; speedup vs baseline: 24.1394x; 1.0433x over previous
//
#include <hip/hip_runtime.h>
#include <math.h>

#define NN 20000
#define EE 320000
#define GG 64
#define HH 8
#define EPSV 1e-5f

static inline unsigned int gridFor(long n, int b){ return (unsigned int)((n + b - 1)/b); }

typedef __attribute__((ext_vector_type(8))) short short8;
typedef __attribute__((ext_vector_type(4))) float f32x4;
typedef unsigned short ushort_t;

// ---------------- CSR build ----------------
__global__ void k_deg(const int* __restrict__ edst, int* __restrict__ deg){
    int e = blockIdx.x*blockDim.x + threadIdx.x;
    if (e < EE) atomicAdd(&deg[edst[e]], 1);
}

__global__ void k_scan(const int* __restrict__ deg, int* __restrict__ indptr){
    __shared__ int partial[1024];
    const int CH = (NN + 1023)/1024;   // 20
    int t = threadIdx.x;
    int base = t*CH;
    int vals[CH];
    int sum = 0;
    for (int i = 0; i < CH; ++i){
        int v = (base+i < NN) ? deg[base+i] : 0;
        vals[i] = sum; sum += v;
    }
    partial[t] = sum;
    __syncthreads();
    for (int off = 1; off < 1024; off <<= 1){
        int v = (t >= off) ? partial[t-off] : 0;
        __syncthreads();
        partial[t] += v;
        __syncthreads();
    }
    int prefix = (t > 0) ? partial[t-1] : 0;
    for (int i = 0; i < CH; ++i)
        if (base+i < NN) indptr[base+i] = prefix + vals[i];
    if (t == 1023) indptr[NN] = prefix + sum;
}

__global__ void k_scatter(const int* __restrict__ esrc, const int* __restrict__ edst,
                          const int* __restrict__ indptr, int* __restrict__ cursor,
                          int* __restrict__ srclist){
    int e = blockIdx.x*blockDim.x + threadIdx.x;
    if (e >= EE) return;
    int d = edst[e];
    int pos = atomicAdd(&cursor[d], 1);
    srclist[indptr[d] + pos] = esrc[e];
}

__global__ void k_bounds(const int* __restrict__ batch, int* __restrict__ gstart, int* __restrict__ gend){
    int i = blockIdx.x*blockDim.x + threadIdx.x;
    if (i >= NN) return;
    int b = batch[i];
    if (i == 0 || batch[i-1] != b) gstart[b] = i;
    if (i == NN-1 || batch[i+1] != b) gend[b] = i+1;
}

// ---------------- bf16 helpers ----------------
__device__ __forceinline__ float asf(unsigned int u){
    union{unsigned int i; float f;} c; c.i = u; return c.f;
}
__device__ __forceinline__ ushort_t f2bf(float x){   // RNE
    unsigned u = __float_as_uint(x);
    unsigned r = u + 0x7FFFu + ((u >> 16) & 1u);
    return (ushort_t)(r >> 16);
}
__device__ __forceinline__ void split_bf16(float x, short& hi, short& lo){
    unsigned u = __float_as_uint(x);
    unsigned r = u + 0x7FFFu + ((u >> 16) & 1u);
    hi = (short)(r >> 16);
    float hf = asf(((unsigned)(unsigned short)hi) << 16);
    float res = x - hf;
    unsigned u2 = __float_as_uint(res);
    unsigned r2 = u2 + 0x7FFFu + ((u2 >> 16) & 1u);
    lo = (short)(r2 >> 16);
}

// ---------------- bf16-split MFMA dual linear (+ optional fused GraphNorm+ReLU on input) ----------------
// [xl | xr] = f(h) @ [Wl | Wr] + [bl | br]; xl written bf16-packed (gather operand), xr fp32.
#define SA 40   // LDS row stride in shorts (80B: 16B-aligned b128 frags)

template<bool NORM>
__global__ __launch_bounds__(256)
void k_gemm_mfma(const float* __restrict__ h,
                 const float* __restrict__ Wl, const float* __restrict__ bl,
                 const float* __restrict__ Wr, const float* __restrict__ br,
                 const float* __restrict__ gmu, const float* __restrict__ ginv,
                 const float* __restrict__ nw, const float* __restrict__ nb,
                 const int* __restrict__ batch,
                 ushort_t* __restrict__ xlb, float* __restrict__ xr,
                 int K, int HC){
    __shared__ short Ahi[64*SA], Alo[64*SA], Bhi[64*SA], Blo[64*SA];
    const int tid  = threadIdx.x;
    const int lane = tid & 63;
    const int wave = tid >> 6;
    const int m0   = blockIdx.x * 64;
    const int n0g  = blockIdx.y * 64;
    const bool right = (n0g >= HC);
    const float* W  = right ? Wr : Wl;
    const float* bv = right ? br : bl;
    const int nbase = right ? (n0g - HC) : n0g;

    const int wr = (wave & 1) * 32;
    const int wc = (wave >> 1) * 32;

    f32x4 acc[2][2] = {};

    const int sm = tid & 63;
    const int sq = tid >> 6;
    const bool kvec = ((K & 7) == 0);

    for (int k0 = 0; k0 < K; k0 += 32){
        {
            int gm = m0 + sm;
            int kb = k0 + sq*8;
            float v[8];
            if (gm < NN && kvec && kb + 8 <= K){
                const float* src = h + (long)gm*K + kb;
                float4 t0 = *(const float4*)src;
                float4 t1 = *(const float4*)(src+4);
                v[0]=t0.x; v[1]=t0.y; v[2]=t0.z; v[3]=t0.w;
                v[4]=t1.x; v[5]=t1.y; v[6]=t1.z; v[7]=t1.w;
            } else {
                const float* src = h + (long)gm*K + kb;
                #pragma unroll
                for (int j = 0; j < 8; ++j)
                    v[j] = (gm < NN && kb + j < K) ? src[j] : 0.f;
            }
            if (NORM && gm < NN){
                int g = batch[gm];
                const float* mu = gmu + (long)g*K;
                const float* iv = ginv + (long)g*K;
                #pragma unroll
                for (int j = 0; j < 8; ++j){
                    int c = kb + j;
                    float t = (v[j] - mu[c]) * iv[c] * nw[c] + nb[c];
                    v[j] = fmaxf(t, 0.f);
                }
            }
            short hi[8], lo[8];
            #pragma unroll
            for (int j = 0; j < 8; ++j) split_bf16(v[j], hi[j], lo[j]);
            *(short8*)&Ahi[sm*SA + sq*8] = *(short8*)hi;
            *(short8*)&Alo[sm*SA + sq*8] = *(short8*)lo;
        }
        {
            int n = sm;
            float v[8];
            #pragma unroll
            for (int j = 0; j < 8; ++j){
                int gk = k0 + sq*8 + j;
                v[j] = (gk < K) ? W[(long)gk*HC + nbase + n] : 0.f;
            }
            short hi[8], lo[8];
            #pragma unroll
            for (int j = 0; j < 8; ++j) split_bf16(v[j], hi[j], lo[j]);
            *(short8*)&Bhi[n*SA + sq*8] = *(short8*)hi;
            *(short8*)&Blo[n*SA + sq*8] = *(short8*)lo;
        }
        __syncthreads();

        const int fm = lane & 15;
        const int fk = (lane >> 4) * 8;
        short8 ah0 = *(short8*)&Ahi[(wr+fm)*SA + fk];
        short8 ah1 = *(short8*)&Ahi[(wr+16+fm)*SA + fk];
        short8 al0 = *(short8*)&Alo[(wr+fm)*SA + fk];
        short8 al1 = *(short8*)&Alo[(wr+16+fm)*SA + fk];
        short8 bh0 = *(short8*)&Bhi[(wc+fm)*SA + fk];
        short8 bh1 = *(short8*)&Bhi[(wc+16+fm)*SA + fk];
        short8 bl0 = *(short8*)&Blo[(wc+fm)*SA + fk];
        short8 bl1 = *(short8*)&Blo[(wc+16+fm)*SA + fk];

        acc[0][0] = __builtin_amdgcn_mfma_f32_16x16x32_bf16(al0, bh0, acc[0][0], 0,0,0);
        acc[0][0] = __builtin_amdgcn_mfma_f32_16x16x32_bf16(ah0, bl0, acc[0][0], 0,0,0);
        acc[0][0] = __builtin_amdgcn_mfma_f32_16x16x32_bf16(ah0, bh0, acc[0][0], 0,0,0);
        acc[0][1] = __builtin_amdgcn_mfma_f32_16x16x32_bf16(al0, bh1, acc[0][1], 0,0,0);
        acc[0][1] = __builtin_amdgcn_mfma_f32_16x16x32_bf16(ah0, bl1, acc[0][1], 0,0,0);
        acc[0][1] = __builtin_amdgcn_mfma_f32_16x16x32_bf16(ah0, bh1, acc[0][1], 0,0,0);
        acc[1][0] = __builtin_amdgcn_mfma_f32_16x16x32_bf16(al1, bh0, acc[1][0], 0,0,0);
        acc[1][0] = __builtin_amdgcn_mfma_f32_16x16x32_bf16(ah1, bl0, acc[1][0], 0,0,0);
        acc[1][0] = __builtin_amdgcn_mfma_f32_16x16x32_bf16(ah1, bh0, acc[1][0], 0,0,0);
        acc[1][1] = __builtin_amdgcn_mfma_f32_16x16x32_bf16(al1, bh1, acc[1][1], 0,0,0);
        acc[1][1] = __builtin_amdgcn_mfma_f32_16x16x32_bf16(ah1, bl1, acc[1][1], 0,0,0);
        acc[1][1] = __builtin_amdgcn_mfma_f32_16x16x32_bf16(ah1, bh1, acc[1][1], 0,0,0);

        __syncthreads();
    }

    #pragma unroll
    for (int i = 0; i < 2; ++i){
        int row0 = m0 + wr + i*16 + (lane >> 4)*4;
        #pragma unroll
        for (int j = 0; j < 2; ++j){
            int col = wc + j*16 + (lane & 15);
            float bb = bv[nbase + col];
            #pragma unroll
            for (int r = 0; r < 4; ++r){
                int gm = row0 + r;
                if (gm >= NN) continue;
                float v = acc[i][j][r] + bb;
                if (right) xr[(long)gm*HC + nbase + col] = v;
                else       xlb[(long)gm*HC + nbase + col] = f2bf(v);
            }
        }
    }
}

// ---------------- fused GATv2, wave-per-node, bf16 gather operand ----------------
template<int VEC> struct VT;
template<> struct VT<1>{ using T = float;  };
template<> struct VT<2>{ using T = float2; };
template<> struct VT<4>{ using T = float4; };

template<int VEC> struct BF;
template<> struct BF<1>{
    static __device__ __forceinline__ float load(const ushort_t* p){
        return asf(((unsigned)*p) << 16);
    }
};
template<> struct BF<2>{
    static __device__ __forceinline__ float2 load(const ushort_t* p){
        unsigned u = *(const unsigned*)p;
        return make_float2(asf(u << 16), asf(u & 0xFFFF0000u));
    }
};
template<> struct BF<4>{
    static __device__ __forceinline__ float4 load(const ushort_t* p){
        uint2 u = *(const uint2*)p;
        return make_float4(asf(u.x << 16), asf(u.x & 0xFFFF0000u),
                           asf(u.y << 16), asf(u.y & 0xFFFF0000u));
    }
};

__device__ __forceinline__ float lrelu(float z){ return z > 0.f ? z : 0.2f*z; }

__device__ __forceinline__ float edot(float xv, float xr, float at){
    return lrelu(xv + xr) * at;
}
__device__ __forceinline__ float edot(float2 xv, float2 xr, float2 at){
    return lrelu(xv.x+xr.x)*at.x + lrelu(xv.y+xr.y)*at.y;
}
__device__ __forceinline__ float edot(float4 xv, float4 xr, float4 at){
    return lrelu(xv.x+xr.x)*at.x + lrelu(xv.y+xr.y)*at.y
         + lrelu(xv.z+xr.z)*at.z + lrelu(xv.w+xr.w)*at.w;
}
__device__ __forceinline__ void efma(float& o, float p, float xv){ o = fmaf(p,xv,o); }
__device__ __forceinline__ void efma(float2& o, float p, float2 xv){
    o.x = fmaf(p,xv.x,o.x); o.y = fmaf(p,xv.y,o.y);
}
__device__ __forceinline__ void efma(float4& o, float p, float4 xv){
    o.x = fmaf(p,xv.x,o.x); o.y = fmaf(p,xv.y,o.y);
    o.z = fmaf(p,xv.z,o.z); o.w = fmaf(p,xv.w,o.w);
}
__device__ __forceinline__ float escale(float o, float s, float b){ return fmaf(o,s,b); }
__device__ __forceinline__ float2 escale(float2 o, float s, float2 b){
    return make_float2(fmaf(o.x,s,b.x), fmaf(o.y,s,b.y));
}
__device__ __forceinline__ float4 escale(float4 o, float s, float4 b){
    return make_float4(fmaf(o.x,s,b.x), fmaf(o.y,s,b.y), fmaf(o.z,s,b.z), fmaf(o.w,s,b.w));
}

__device__ __forceinline__ float red8(float v){
    v += __shfl_xor(v, 1);
    v += __shfl_xor(v, 2);
    v += __shfl_xor(v, 4);
    return v;
}

template<int VEC, bool MEAN>
__global__ __launch_bounds__(256)
void k_gat_w(const int* __restrict__ indptr, const int* __restrict__ srclist,
             const ushort_t* __restrict__ xlb, const float* __restrict__ xr,
             const float* __restrict__ att, const float* __restrict__ bias,
             float* __restrict__ val){
    using V = typename VT<VEC>::T;
    constexpr int HC = 64*VEC;
    const int lane = threadIdx.x & 63;
    const int d = blockIdx.x*4 + (threadIdx.x >> 6);
    const int co = lane*VEC;

    V xrd = *(const V*)&xr[(long)d*HC + co];
    V at  = *(const V*)&att[co];
    V xls = BF<VEC>::load(xlb + (long)d*HC + co);

    float m0 = red8(edot(xls, xrd, at));
    float l = 1.0f;
    V o = xls;

    int j = indptr[d], end = indptr[d+1];   // wave-uniform
    for (; j + 8 <= end; j += 8){
        int s0 = srclist[j+0], s1 = srclist[j+1], s2 = srclist[j+2], s3 = srclist[j+3];
        int s4 = srclist[j+4], s5 = srclist[j+5], s6 = srclist[j+6], s7 = srclist[j+7];
        V x0 = BF<VEC>::load(xlb + (long)s0*HC + co);
        V x1 = BF<VEC>::load(xlb + (long)s1*HC + co);
        V x2 = BF<VEC>::load(xlb + (long)s2*HC + co);
        V x3 = BF<VEC>::load(xlb + (long)s3*HC + co);
        V x4 = BF<VEC>::load(xlb + (long)s4*HC + co);
        V x5 = BF<VEC>::load(xlb + (long)s5*HC + co);
        V x6 = BF<VEC>::load(xlb + (long)s6*HC + co);
        V x7 = BF<VEC>::load(xlb + (long)s7*HC + co);
        float a0 = red8(edot(x0, xrd, at));
        float a1 = red8(edot(x1, xrd, at));
        float a2 = red8(edot(x2, xrd, at));
        float a3 = red8(edot(x3, xrd, at));
        float a4 = red8(edot(x4, xrd, at));
        float a5 = red8(edot(x5, xrd, at));
        float a6 = red8(edot(x6, xrd, at));
        float a7 = red8(edot(x7, xrd, at));
        float p0 = __expf(a0 - m0), p1 = __expf(a1 - m0);
        float p2 = __expf(a2 - m0), p3 = __expf(a3 - m0);
        float p4 = __expf(a4 - m0), p5 = __expf(a5 - m0);
        float p6 = __expf(a6 - m0), p7 = __expf(a7 - m0);
        l += ((p0+p1)+(p2+p3)) + ((p4+p5)+(p6+p7));
        efma(o, p0, x0); efma(o, p1, x1); efma(o, p2, x2); efma(o, p3, x3);
        efma(o, p4, x4); efma(o, p5, x5); efma(o, p6, x6); efma(o, p7, x7);
    }
    for (; j < end; j += 4){
        int m = end - j;
        int s0 = srclist[j];
        int s1 = (m > 1) ? srclist[j+1] : s0;
        int s2 = (m > 2) ? srclist[j+2] : s0;
        int s3 = (m > 3) ? srclist[j+3] : s0;
        V x0 = BF<VEC>::load(xlb + (long)s0*HC + co);
        V x1 = BF<VEC>::load(xlb + (long)s1*HC + co);
        V x2 = BF<VEC>::load(xlb + (long)s2*HC + co);
        V x3 = BF<VEC>::load(xlb + (long)s3*HC + co);
        float a0 = red8(edot(x0, xrd, at));
        float a1 = red8(edot(x1, xrd, at));
        float a2 = red8(edot(x2, xrd, at));
        float a3 = red8(edot(x3, xrd, at));
        float p0 = __expf(a0 - m0);
        float p1 = __expf(a1 - m0);
        float p2 = __expf(a2 - m0);
        float p3 = __expf(a3 - m0);
        l += p0; efma(o, p0, x0);
        if (m > 1){ l += p1; efma(o, p1, x1); }
        if (m > 2){ l += p2; efma(o, p2, x2); }
        if (m > 3){ l += p3; efma(o, p3, x3); }
    }
    float invl = 1.0f / l;
    if (!MEAN){
        V bv = *(const V*)&bias[co];
        *(V*)&val[(long)d*HC + co] = escale(o, invl, bv);
    } else {
        float r = ((float&)o) * invl;
        r += __shfl_xor(r, 8);
        r += __shfl_xor(r, 16);
        r += __shfl_xor(r, 32);
        if (lane < 8) val[(long)d*8 + lane] = r*0.125f + bias[lane];
    }
}

// ---------------- GraphNorm stats: chunked partials + finalize ----------------
template<int F>
__global__ void k_gn_partial(const float* __restrict__ val,
                             const int* __restrict__ gstart, const int* __restrict__ gend,
                             float* __restrict__ gsum, float* __restrict__ gsq){
    int g = blockIdx.x, ch = blockIdx.y, nch = gridDim.y;
    int c = threadIdx.x;
    int s = gstart[g], e = gend[g];
    float sum = 0.f, sq = 0.f;
    for (int i = s + ch; i < e; i += nch){
        float v = val[(long)i*F + c];
        sum += v; sq += v*v;
    }
    if (sum != 0.f || sq != 0.f){
        atomicAdd(&gsum[g*F + c], sum);
        atomicAdd(&gsq[g*F + c], sq);
    }
}

__global__ void k_gn_finalize(const float* __restrict__ gsum, const float* __restrict__ gsq,
                              const int* __restrict__ gstart, const int* __restrict__ gend,
                              const float* __restrict__ ms,
                              float* __restrict__ gmu, float* __restrict__ ginv, int F){
    int idx = blockIdx.x*blockDim.x + threadIdx.x;
    if (idx >= GG*F) return;
    int g = idx / F, c = idx - g*F;
    int cnti = gend[g] - gstart[g];
    float cn = cnti > 0 ? (float)cnti : 1.f;
    float mean = gsum[idx] / cn;
    float mu = mean * ms[c];
    float var = gsq[idx]/cn - 2.f*mu*mean + mu*mu;
    gmu[idx]  = mu;
    ginv[idx] = rsqrtf(var + EPSV);
}

__global__ void k_gn_stats8(const float* __restrict__ val,
                            const int* __restrict__ gstart, const int* __restrict__ gend,
                            const float* __restrict__ ms,
                            float* __restrict__ gmu, float* __restrict__ ginv){
    const int F = 8;
    int g = blockIdx.x;
    int t = threadIdx.x;
    int c = t % F, r = t / F;
    int s = gstart[g], e = gend[g];
    float sum = 0.f, sq = 0.f;
    for (int i = s + r; i < e; i += 8){
        float v = val[(long)i*F + c];
        sum += v; sq += v*v;
    }
    #pragma unroll
    for (int mask = 8; mask < 64; mask <<= 1){
        sum += __shfl_xor(sum, mask, 64);
        sq  += __shfl_xor(sq,  mask, 64);
    }
    if (r == 0){
        int cnti = e - s;
        float cn = cnti > 0 ? (float)cnti : 1.f;
        float mean = sum / cn;
        float mu = mean * ms[c];
        float var = sq/cn - 2.f*mu*mean + mu*mu;
        gmu[g*F + c]  = mu;
        ginv[g*F + c] = rsqrtf(var + EPSV);
    }
}

// ---------------- pool with fused layer-3 GraphNorm+ReLU ----------------
__global__ void k_pool_gn(const float* __restrict__ D,
                          const int* __restrict__ gstart, const int* __restrict__ gend,
                          const float* __restrict__ gmu, const float* __restrict__ ginv,
                          const float* __restrict__ w, const float* __restrict__ b,
                          float* __restrict__ outFeat){
    int g = blockIdx.x;
    int t = threadIdx.x;
    int c = t & 7, r = t >> 3;
    int s = gstart[g], e = gend[g];
    float mu = gmu[g*8 + c], iv = ginv[g*8 + c], wc = w[c], bc = b[c];
    float sum = 0.f;
    for (int i = s + r; i < e; i += 8){
        float v = (D[(long)i*8 + c] - mu) * iv * wc + bc;
        sum += fmaxf(v, 0.f);
    }
    sum += __shfl_xor(sum, 8, 64);
    sum += __shfl_xor(sum, 16, 64);
    sum += __shfl_xor(sum, 32, 64);
    if (t < 8){
        int cnti = e - s;
        float cn = cnti > 0 ? (float)cnti : 1.f;
        outFeat[g*8 + t] = sum / cn;
    }
}

__global__ void k_logits(const float* __restrict__ feat, const float* __restrict__ lw,
                         const float* __restrict__ lb, float* __restrict__ outLog){
    int idx = blockIdx.x*blockDim.x + threadIdx.x;
    if (idx >= GG*4) return;
    int g = idx >> 2, j = idx & 3;
    float a = lb[j];
    for (int c = 0; c < 8; ++c) a += feat[g*8 + c] * lw[c*4 + j];
    outLog[idx] = a;
}

extern "C" void kernel_launch(void* const* d_in, const int* in_sizes, int n_in,
                              void* d_out, int out_size, void* d_ws, size_t ws_size,
                              hipStream_t stream) {
    const float* x     = (const float*)d_in[0];
    const int*   ei    = (const int*)  d_in[1];
    const int*   batch = (const int*)  d_in[2];
    const float* W1l = (const float*)d_in[3];  const float* b1l = (const float*)d_in[4];
    const float* W1r = (const float*)d_in[5];  const float* b1r = (const float*)d_in[6];
    const float* att1= (const float*)d_in[7];  const float* bias1=(const float*)d_in[8];
    const float* g1w = (const float*)d_in[9];  const float* g1b = (const float*)d_in[10];
    const float* g1m = (const float*)d_in[11];
    const float* W2l = (const float*)d_in[12]; const float* b2l = (const float*)d_in[13];
    const float* W2r = (const float*)d_in[14]; const float* b2r = (const float*)d_in[15];
    const float* att2= (const float*)d_in[16]; const float* bias2=(const float*)d_in[17];
    const float* g2w = (const float*)d_in[18]; const float* g2b = (const float*)d_in[19];
    const float* g2m = (const float*)d_in[20];
    const float* W3l = (const float*)d_in[21]; const float* b3l = (const float*)d_in[22];
    const float* W3r = (const float*)d_in[23]; const float* b3r = (const float*)d_in[24];
    const float* att3= (const float*)d_in[25]; const float* bias3=(const float*)d_in[26];
    const float* g3w = (const float*)d_in[27]; const float* g3b = (const float*)d_in[28];
    const float* g3m = (const float*)d_in[29];
    const float* lin_w=(const float*)d_in[30]; const float* lin_b=(const float*)d_in[31];

    const int* esrc = ei;
    const int* edst = ei + EE;

    // ---- workspace arena (units of 4B) ----
    float* ws = (float*)d_ws;
    int*   cursor  = (int*)(ws + 0);         // 20480
    int*   indptr  = (int*)(ws + 20480);     // 20480
    int*   srclist = (int*)(ws + 40960);     // 320512
    int*   gstart  = (int*)(ws + 361472);    // 512
    int*   gend    = (int*)(ws + 361984);    // 512
    float* gmu     = ws + 362496;            // 16384
    float* ginv    = ws + 378880;            // 16384
    float* gsumP   = ws + 395264;            // 16384
    float* gsqP    = ws + 411648;            // 16384 (contiguous with gsumP)
    ushort_t* Bb = (ushort_t*)(ws + 428032); // xl bf16: 5,120,000 shorts -> 2,560,000 floats
    float* Cb = ws + 2988032;                // xr fp32: 5,120,000
    float* D  = ws + 8108032;                // pre-norm GAT out: 5,120,000

    const int TB = 256;
    const int MBm = (NN + 63)/64;    // 313 row tiles
    const int NCH = 32;

    // CSR + graph bounds
    hipMemsetAsync(cursor, 0, NN*sizeof(int), stream);
    k_deg<<<gridFor(EE, TB), TB, 0, stream>>>(edst, cursor);
    k_scan<<<1, 1024, 0, stream>>>(cursor, indptr);
    hipMemsetAsync(cursor, 0, NN*sizeof(int), stream);
    k_scatter<<<gridFor(EE, TB), TB, 0, stream>>>(esrc, edst, indptr, cursor, srclist);
    k_bounds<<<gridFor(NN, TB), TB, 0, stream>>>(batch, gstart, gend);

    // ---- layer 1: 19 -> 256 (concat) ----
    k_gemm_mfma<false><<<dim3(MBm, 8), 256, 0, stream>>>(x, W1l, b1l, W1r, b1r,
        nullptr, nullptr, nullptr, nullptr, nullptr, Bb, Cb, 19, 256);
    k_gat_w<4, false><<<NN/4, 256, 0, stream>>>(indptr, srclist, Bb, Cb, att1, bias1, D);
    hipMemsetAsync(gsumP, 0, 2*GG*256*sizeof(float), stream);   // gsumP+gsqP contiguous
    k_gn_partial<256><<<dim3(GG, NCH), 256, 0, stream>>>(D, gstart, gend, gsumP, gsqP);
    k_gn_finalize<<<gridFor(GG*256, TB), TB, 0, stream>>>(gsumP, gsqP, gstart, gend, g1m, gmu, ginv, 256);

    // ---- layer 2: 256 -> 128 (concat); layer-1 norm fused into A-staging ----
    k_gemm_mfma<true><<<dim3(MBm, 4), 256, 0, stream>>>(D, W2l, b2l, W2r, b2r,
        gmu, ginv, g1w, g1b, batch, Bb, Cb, 256, 128);
    k_gat_w<2, false><<<NN/4, 256, 0, stream>>>(indptr, srclist, Bb, Cb, att2, bias2, D);
    hipMemsetAsync(gsumP, 0, 2*GG*256*sizeof(float), stream);
    k_gn_partial<128><<<dim3(GG, NCH), 128, 0, stream>>>(D, gstart, gend, gsumP, gsqP);
    k_gn_finalize<<<gridFor(GG*128, TB), TB, 0, stream>>>(gsumP, gsqP, gstart, gend, g2m, gmu, ginv, 128);

    // ---- layer 3: 128 -> 64 (head mean -> 8); layer-2 norm fused ----
    k_gemm_mfma<true><<<dim3(MBm, 2), 256, 0, stream>>>(D, W3l, b3l, W3r, b3r,
        gmu, ginv, g2w, g2b, batch, Bb, Cb, 128, 64);
    k_gat_w<1, true><<<NN/4, 256, 0, stream>>>(indptr, srclist, Bb, Cb, att3, bias3, D);
    k_gn_stats8<<<GG, 64, 0, stream>>>(D, gstart, gend, g3m, gmu, ginv);

    // ---- pool (layer-3 norm fused) + head ----
    float* outLog  = (float*)d_out;
    float* outFeat = outLog + GG*4;
    k_pool_gn<<<GG, 64, 0, stream>>>(D, gstart, gend, gmu, ginv, g3w, g3b, outFeat);
    k_logits<<<1, 256, 0, stream>>>(outFeat, lin_w, lin_b, outLog);
}

// Round 10
// 345.392 us; speedup vs baseline: 25.4238x; 1.0532x over previous
//
#include <hip/hip_runtime.h>
#include <math.h>

#define NN 20000
#define EE 320000
#define GG 64
#define HH 8
#define EPSV 1e-5f

static inline unsigned int gridFor(long n, int b){ return (unsigned int)((n + b - 1)/b); }

typedef __attribute__((ext_vector_type(8))) short short8;
typedef __attribute__((ext_vector_type(4))) float f32x4;
typedef unsigned short ushort_t;

// ---------------- CSR build ----------------
__global__ void k_deg(const int* __restrict__ edst, int* __restrict__ deg){
    int e = blockIdx.x*blockDim.x + threadIdx.x;
    if (e < EE) atomicAdd(&deg[edst[e]], 1);
}

__global__ void k_scan(const int* __restrict__ deg, int* __restrict__ indptr){
    __shared__ int partial[1024];
    const int CH = (NN + 1023)/1024;   // 20
    int t = threadIdx.x;
    int base = t*CH;
    int vals[CH];
    int sum = 0;
    for (int i = 0; i < CH; ++i){
        int v = (base+i < NN) ? deg[base+i] : 0;
        vals[i] = sum; sum += v;
    }
    partial[t] = sum;
    __syncthreads();
    for (int off = 1; off < 1024; off <<= 1){
        int v = (t >= off) ? partial[t-off] : 0;
        __syncthreads();
        partial[t] += v;
        __syncthreads();
    }
    int prefix = (t > 0) ? partial[t-1] : 0;
    for (int i = 0; i < CH; ++i)
        if (base+i < NN) indptr[base+i] = prefix + vals[i];
    if (t == 1023) indptr[NN] = prefix + sum;
}

__global__ void k_scatter(const int* __restrict__ esrc, const int* __restrict__ edst,
                          const int* __restrict__ indptr, int* __restrict__ cursor,
                          int* __restrict__ srclist){
    int e = blockIdx.x*blockDim.x + threadIdx.x;
    if (e >= EE) return;
    int d = edst[e];
    int pos = atomicAdd(&cursor[d], 1);
    srclist[indptr[d] + pos] = esrc[e];
}

__global__ void k_bounds(const int* __restrict__ batch, int* __restrict__ gstart, int* __restrict__ gend){
    int i = blockIdx.x*blockDim.x + threadIdx.x;
    if (i >= NN) return;
    int b = batch[i];
    if (i == 0 || batch[i-1] != b) gstart[b] = i;
    if (i == NN-1 || batch[i+1] != b) gend[b] = i+1;
}

// ---------------- bf16 helpers ----------------
__device__ __forceinline__ float asf(unsigned int u){
    union{unsigned int i; float f;} c; c.i = u; return c.f;
}
__device__ __forceinline__ ushort_t f2bf(float x){   // RNE
    unsigned u = __float_as_uint(x);
    unsigned r = u + 0x7FFFu + ((u >> 16) & 1u);
    return (ushort_t)(r >> 16);
}
__device__ __forceinline__ void split_bf16(float x, short& hi, short& lo){
    unsigned u = __float_as_uint(x);
    unsigned r = u + 0x7FFFu + ((u >> 16) & 1u);
    hi = (short)(r >> 16);
    float hf = asf(((unsigned)(unsigned short)hi) << 16);
    float res = x - hf;
    unsigned u2 = __float_as_uint(res);
    unsigned r2 = u2 + 0x7FFFu + ((u2 >> 16) & 1u);
    lo = (short)(r2 >> 16);
}

// ---------------- weight prep: split-transpose [Wl|Wr] into fragment-ready bf16 hi/lo ----------------
// frag layout: element (n,k) lives at ((n>>4)*(Kp/32) + (k>>5))*512 + ((n&15) + 16*((k>>3)&3))*8 + (k&7)
__global__ void k_wprep(const float* __restrict__ Wl, const float* __restrict__ Wr,
                        ushort_t* __restrict__ Whi, ushort_t* __restrict__ Wlo,
                        int K, int Kp, int HC){
    int octs = Kp >> 3;
    int t = blockIdx.x*blockDim.x + threadIdx.x;
    if (t >= 2*HC*octs) return;
    int n = t / octs, ko = t - n*octs;
    int kb = ko*8;
    const float* W = (n < HC) ? (Wl + n) : (Wr + (n - HC));
    short hi[8], lo[8];
    #pragma unroll
    for (int j = 0; j < 8; ++j){
        int k = kb + j;
        float v = (k < K) ? W[(long)k*HC] : 0.f;
        split_bf16(v, hi[j], lo[j]);
    }
    long base = (((long)(n>>4)*(Kp>>5) + (kb>>5))*64 + (n&15) + 16*((kb>>3)&3))*8;
    *(short8*)&Whi[base] = *(short8*)hi;
    *(short8*)&Wlo[base] = *(short8*)lo;
}

// ---------------- bf16-split MFMA dual linear (fragment-ready W from global, A via LDS) ----------------
// block: 64 rows x 128 combined cols; 4 waves in 2x2; wave = 32 rows x 64 cols (2x4 frags)
template<bool NORM>
__global__ __launch_bounds__(256)
void k_gemm_mfma(const float* __restrict__ h,
                 const ushort_t* __restrict__ Whi, const ushort_t* __restrict__ Wlo,
                 const float* __restrict__ bl, const float* __restrict__ br,
                 const float* __restrict__ gmu, const float* __restrict__ ginv,
                 const float* __restrict__ nw, const float* __restrict__ nb,
                 const int* __restrict__ batch,
                 ushort_t* __restrict__ xlb, float* __restrict__ xr,
                 int K, int Kp, int HC){
    __shared__ short Ahi[64*32], Alo[64*32];   // fragment-ready: (rowblk*64 + fraglane)*8
    const int tid  = threadIdx.x;
    const int lane = tid & 63;
    const int wave = tid >> 6;
    const int m0   = blockIdx.x * 64;
    const int n0   = blockIdx.y * 128;
    const int wr   = (wave & 1) * 32;       // wave row offset
    const int wcg  = (wave >> 1) * 64;      // wave col offset (4 frags)
    const int kblocks = Kp >> 5;

    // staging map: 4 threads per row (contiguous 128B per row)
    const int srow = tid >> 2;      // 0..63
    const int soct = tid & 3;       // k-octet 0..3

    f32x4 acc[2][4] = {};

    for (int kb = 0; kb < kblocks; ++kb){
        int k0 = kb*32;
        // ---- stage A (optional fused GraphNorm+ReLU), split bf16 hi/lo, frag-ready LDS
        {
            int gm = m0 + srow;
            int kbase = k0 + soct*8;
            float v[8];
            const float* src = h + (long)gm*K + kbase;
            if (gm < NN && kbase + 8 <= K){
                float4 t0 = *(const float4*)src;
                float4 t1 = *(const float4*)(src+4);
                v[0]=t0.x; v[1]=t0.y; v[2]=t0.z; v[3]=t0.w;
                v[4]=t1.x; v[5]=t1.y; v[6]=t1.z; v[7]=t1.w;
            } else {
                #pragma unroll
                for (int j = 0; j < 8; ++j)
                    v[j] = (gm < NN && kbase + j < K) ? src[j] : 0.f;
            }
            if (NORM && gm < NN){
                int g = batch[gm];
                const float* mu = gmu + (long)g*K;
                const float* iv = ginv + (long)g*K;
                #pragma unroll
                for (int j = 0; j < 8; ++j){
                    int c = kbase + j;
                    float t = (v[j] - mu[c]) * iv[c] * nw[c] + nb[c];
                    v[j] = fmaxf(t, 0.f);
                }
            }
            short hi[8], lo[8];
            #pragma unroll
            for (int j = 0; j < 8; ++j) split_bf16(v[j], hi[j], lo[j]);
            long off = ((long)(srow>>4)*64 + (srow&15) + 16*soct)*8;
            *(short8*)&Ahi[off] = *(short8*)hi;
            *(short8*)&Alo[off] = *(short8*)lo;
        }
        __syncthreads();

        // ---- A fragments (conflict-free linear LDS reads)
        int rb0 = wr >> 4;
        short8 ah0 = *(short8*)&Ahi[((rb0  )*64 + lane)*8];
        short8 ah1 = *(short8*)&Ahi[((rb0+1)*64 + lane)*8];
        short8 al0 = *(short8*)&Alo[((rb0  )*64 + lane)*8];
        short8 al1 = *(short8*)&Alo[((rb0+1)*64 + lane)*8];

        // ---- B fragments straight from global (frag-ready, coalesced, L2-hot)
        short8 bh[4], bl_[4];
        #pragma unroll
        for (int j = 0; j < 4; ++j){
            int n = n0 + wcg + j*16;
            long bbase = (((long)(n>>4)*kblocks + kb)*64 + lane)*8;
            bh[j]  = *(const short8*)&Whi[bbase];
            bl_[j] = *(const short8*)&Wlo[bbase];
        }

        #pragma unroll
        for (int j = 0; j < 4; ++j){
            acc[0][j] = __builtin_amdgcn_mfma_f32_16x16x32_bf16(al0, bh[j],  acc[0][j], 0,0,0);
            acc[0][j] = __builtin_amdgcn_mfma_f32_16x16x32_bf16(ah0, bl_[j], acc[0][j], 0,0,0);
            acc[0][j] = __builtin_amdgcn_mfma_f32_16x16x32_bf16(ah0, bh[j],  acc[0][j], 0,0,0);
            acc[1][j] = __builtin_amdgcn_mfma_f32_16x16x32_bf16(al1, bh[j],  acc[1][j], 0,0,0);
            acc[1][j] = __builtin_amdgcn_mfma_f32_16x16x32_bf16(ah1, bl_[j], acc[1][j], 0,0,0);
            acc[1][j] = __builtin_amdgcn_mfma_f32_16x16x32_bf16(ah1, bh[j],  acc[1][j], 0,0,0);
        }
        __syncthreads();
    }

    // epilogue: C/D layout col=lane&15, row=(lane>>4)*4+reg
    #pragma unroll
    for (int i = 0; i < 2; ++i){
        int row0 = m0 + wr + i*16 + (lane >> 4)*4;
        #pragma unroll
        for (int j = 0; j < 4; ++j){
            int n = n0 + wcg + j*16 + (lane & 15);
            float bb = (n < HC) ? bl[n] : br[n - HC];
            #pragma unroll
            for (int r = 0; r < 4; ++r){
                int gm = row0 + r;
                if (gm >= NN) continue;
                float v = acc[i][j][r] + bb;
                if (n < HC) xlb[(long)gm*HC + n] = f2bf(v);
                else        xr[(long)gm*HC + (n - HC)] = v;
            }
        }
    }
}

// ---------------- fused GATv2, wave-per-node, bf16 gather operand ----------------
template<int VEC> struct VT;
template<> struct VT<1>{ using T = float;  };
template<> struct VT<2>{ using T = float2; };
template<> struct VT<4>{ using T = float4; };

template<int VEC> struct BF;
template<> struct BF<1>{
    static __device__ __forceinline__ float load(const ushort_t* p){
        return asf(((unsigned)*p) << 16);
    }
};
template<> struct BF<2>{
    static __device__ __forceinline__ float2 load(const ushort_t* p){
        unsigned u = *(const unsigned*)p;
        return make_float2(asf(u << 16), asf(u & 0xFFFF0000u));
    }
};
template<> struct BF<4>{
    static __device__ __forceinline__ float4 load(const ushort_t* p){
        uint2 u = *(const uint2*)p;
        return make_float4(asf(u.x << 16), asf(u.x & 0xFFFF0000u),
                           asf(u.y << 16), asf(u.y & 0xFFFF0000u));
    }
};

__device__ __forceinline__ float lrelu(float z){ return z > 0.f ? z : 0.2f*z; }

__device__ __forceinline__ float edot(float xv, float xr, float at){
    return lrelu(xv + xr) * at;
}
__device__ __forceinline__ float edot(float2 xv, float2 xr, float2 at){
    return lrelu(xv.x+xr.x)*at.x + lrelu(xv.y+xr.y)*at.y;
}
__device__ __forceinline__ float edot(float4 xv, float4 xr, float4 at){
    return lrelu(xv.x+xr.x)*at.x + lrelu(xv.y+xr.y)*at.y
         + lrelu(xv.z+xr.z)*at.z + lrelu(xv.w+xr.w)*at.w;
}
__device__ __forceinline__ void efma(float& o, float p, float xv){ o = fmaf(p,xv,o); }
__device__ __forceinline__ void efma(float2& o, float p, float2 xv){
    o.x = fmaf(p,xv.x,o.x); o.y = fmaf(p,xv.y,o.y);
}
__device__ __forceinline__ void efma(float4& o, float p, float4 xv){
    o.x = fmaf(p,xv.x,o.x); o.y = fmaf(p,xv.y,o.y);
    o.z = fmaf(p,xv.z,o.z); o.w = fmaf(p,xv.w,o.w);
}
__device__ __forceinline__ float escale(float o, float s, float b){ return fmaf(o,s,b); }
__device__ __forceinline__ float2 escale(float2 o, float s, float2 b){
    return make_float2(fmaf(o.x,s,b.x), fmaf(o.y,s,b.y));
}
__device__ __forceinline__ float4 escale(float4 o, float s, float4 b){
    return make_float4(fmaf(o.x,s,b.x), fmaf(o.y,s,b.y), fmaf(o.z,s,b.z), fmaf(o.w,s,b.w));
}

__device__ __forceinline__ float red8(float v){
    v += __shfl_xor(v, 1);
    v += __shfl_xor(v, 2);
    v += __shfl_xor(v, 4);
    return v;
}

template<int VEC, bool MEAN>
__global__ __launch_bounds__(256)
void k_gat_w(const int* __restrict__ indptr, const int* __restrict__ srclist,
             const ushort_t* __restrict__ xlb, const float* __restrict__ xr,
             const float* __restrict__ att, const float* __restrict__ bias,
             float* __restrict__ val){
    using V = typename VT<VEC>::T;
    constexpr int HC = 64*VEC;
    const int lane = threadIdx.x & 63;
    const int d = blockIdx.x*4 + (threadIdx.x >> 6);
    const int co = lane*VEC;

    V xrd = *(const V*)&xr[(long)d*HC + co];
    V at  = *(const V*)&att[co];
    V xls = BF<VEC>::load(xlb + (long)d*HC + co);

    float m0 = red8(edot(xls, xrd, at));
    float l = 1.0f;
    V o = xls;

    int j = indptr[d], end = indptr[d+1];   // wave-uniform
    for (; j + 8 <= end; j += 8){
        int s0 = srclist[j+0], s1 = srclist[j+1], s2 = srclist[j+2], s3 = srclist[j+3];
        int s4 = srclist[j+4], s5 = srclist[j+5], s6 = srclist[j+6], s7 = srclist[j+7];
        V x0 = BF<VEC>::load(xlb + (long)s0*HC + co);
        V x1 = BF<VEC>::load(xlb + (long)s1*HC + co);
        V x2 = BF<VEC>::load(xlb + (long)s2*HC + co);
        V x3 = BF<VEC>::load(xlb + (long)s3*HC + co);
        V x4 = BF<VEC>::load(xlb + (long)s4*HC + co);
        V x5 = BF<VEC>::load(xlb + (long)s5*HC + co);
        V x6 = BF<VEC>::load(xlb + (long)s6*HC + co);
        V x7 = BF<VEC>::load(xlb + (long)s7*HC + co);
        float a0 = red8(edot(x0, xrd, at));
        float a1 = red8(edot(x1, xrd, at));
        float a2 = red8(edot(x2, xrd, at));
        float a3 = red8(edot(x3, xrd, at));
        float a4 = red8(edot(x4, xrd, at));
        float a5 = red8(edot(x5, xrd, at));
        float a6 = red8(edot(x6, xrd, at));
        float a7 = red8(edot(x7, xrd, at));
        float p0 = __expf(a0 - m0), p1 = __expf(a1 - m0);
        float p2 = __expf(a2 - m0), p3 = __expf(a3 - m0);
        float p4 = __expf(a4 - m0), p5 = __expf(a5 - m0);
        float p6 = __expf(a6 - m0), p7 = __expf(a7 - m0);
        l += ((p0+p1)+(p2+p3)) + ((p4+p5)+(p6+p7));
        efma(o, p0, x0); efma(o, p1, x1); efma(o, p2, x2); efma(o, p3, x3);
        efma(o, p4, x4); efma(o, p5, x5); efma(o, p6, x6); efma(o, p7, x7);
    }
    for (; j < end; j += 4){
        int m = end - j;
        int s0 = srclist[j];
        int s1 = (m > 1) ? srclist[j+1] : s0;
        int s2 = (m > 2) ? srclist[j+2] : s0;
        int s3 = (m > 3) ? srclist[j+3] : s0;
        V x0 = BF<VEC>::load(xlb + (long)s0*HC + co);
        V x1 = BF<VEC>::load(xlb + (long)s1*HC + co);
        V x2 = BF<VEC>::load(xlb + (long)s2*HC + co);
        V x3 = BF<VEC>::load(xlb + (long)s3*HC + co);
        float a0 = red8(edot(x0, xrd, at));
        float a1 = red8(edot(x1, xrd, at));
        float a2 = red8(edot(x2, xrd, at));
        float a3 = red8(edot(x3, xrd, at));
        float p0 = __expf(a0 - m0);
        float p1 = __expf(a1 - m0);
        float p2 = __expf(a2 - m0);
        float p3 = __expf(a3 - m0);
        l += p0; efma(o, p0, x0);
        if (m > 1){ l += p1; efma(o, p1, x1); }
        if (m > 2){ l += p2; efma(o, p2, x2); }
        if (m > 3){ l += p3; efma(o, p3, x3); }
    }
    float invl = 1.0f / l;
    if (!MEAN){
        V bv = *(const V*)&bias[co];
        *(V*)&val[(long)d*HC + co] = escale(o, invl, bv);
    } else {
        float r = ((float&)o) * invl;
        r += __shfl_xor(r, 8);
        r += __shfl_xor(r, 16);
        r += __shfl_xor(r, 32);
        if (lane < 8) val[(long)d*8 + lane] = r*0.125f + bias[lane];
    }
}

// ---------------- GraphNorm stats: chunked partials + finalize ----------------
template<int F>
__global__ void k_gn_partial(const float* __restrict__ val,
                             const int* __restrict__ gstart, const int* __restrict__ gend,
                             float* __restrict__ gsum, float* __restrict__ gsq){
    int g = blockIdx.x, ch = blockIdx.y, nch = gridDim.y;
    int c = threadIdx.x;
    int s = gstart[g], e = gend[g];
    float sum = 0.f, sq = 0.f;
    for (int i = s + ch; i < e; i += nch){
        float v = val[(long)i*F + c];
        sum += v; sq += v*v;
    }
    if (sum != 0.f || sq != 0.f){
        atomicAdd(&gsum[g*F + c], sum);
        atomicAdd(&gsq[g*F + c], sq);
    }
}

__global__ void k_gn_finalize(const float* __restrict__ gsum, const float* __restrict__ gsq,
                              const int* __restrict__ gstart, const int* __restrict__ gend,
                              const float* __restrict__ ms,
                              float* __restrict__ gmu, float* __restrict__ ginv, int F){
    int idx = blockIdx.x*blockDim.x + threadIdx.x;
    if (idx >= GG*F) return;
    int g = idx / F, c = idx - g*F;
    int cnti = gend[g] - gstart[g];
    float cn = cnti > 0 ? (float)cnti : 1.f;
    float mean = gsum[idx] / cn;
    float mu = mean * ms[c];
    float var = gsq[idx]/cn - 2.f*mu*mean + mu*mu;
    gmu[idx]  = mu;
    ginv[idx] = rsqrtf(var + EPSV);
}

__global__ void k_gn_stats8(const float* __restrict__ val,
                            const int* __restrict__ gstart, const int* __restrict__ gend,
                            const float* __restrict__ ms,
                            float* __restrict__ gmu, float* __restrict__ ginv){
    const int F = 8;
    int g = blockIdx.x;
    int t = threadIdx.x;
    int c = t % F, r = t / F;
    int s = gstart[g], e = gend[g];
    float sum = 0.f, sq = 0.f;
    for (int i = s + r; i < e; i += 8){
        float v = val[(long)i*F + c];
        sum += v; sq += v*v;
    }
    #pragma unroll
    for (int mask = 8; mask < 64; mask <<= 1){
        sum += __shfl_xor(sum, mask, 64);
        sq  += __shfl_xor(sq,  mask, 64);
    }
    if (r == 0){
        int cnti = e - s;
        float cn = cnti > 0 ? (float)cnti : 1.f;
        float mean = sum / cn;
        float mu = mean * ms[c];
        float var = sq/cn - 2.f*mu*mean + mu*mu;
        gmu[g*F + c]  = mu;
        ginv[g*F + c] = rsqrtf(var + EPSV);
    }
}

// ---------------- pool with fused layer-3 GraphNorm+ReLU ----------------
__global__ void k_pool_gn(const float* __restrict__ D,
                          const int* __restrict__ gstart, const int* __restrict__ gend,
                          const float* __restrict__ gmu, const float* __restrict__ ginv,
                          const float* __restrict__ w, const float* __restrict__ b,
                          float* __restrict__ outFeat){
    int g = blockIdx.x;
    int t = threadIdx.x;
    int c = t & 7, r = t >> 3;
    int s = gstart[g], e = gend[g];
    float mu = gmu[g*8 + c], iv = ginv[g*8 + c], wc = w[c], bc = b[c];
    float sum = 0.f;
    for (int i = s + r; i < e; i += 8){
        float v = (D[(long)i*8 + c] - mu) * iv * wc + bc;
        sum += fmaxf(v, 0.f);
    }
    sum += __shfl_xor(sum, 8, 64);
    sum += __shfl_xor(sum, 16, 64);
    sum += __shfl_xor(sum, 32, 64);
    if (t < 8){
        int cnti = e - s;
        float cn = cnti > 0 ? (float)cnti : 1.f;
        outFeat[g*8 + t] = sum / cn;
    }
}

__global__ void k_logits(const float* __restrict__ feat, const float* __restrict__ lw,
                         const float* __restrict__ lb, float* __restrict__ outLog){
    int idx = blockIdx.x*blockDim.x + threadIdx.x;
    if (idx >= GG*4) return;
    int g = idx >> 2, j = idx & 3;
    float a = lb[j];
    for (int c = 0; c < 8; ++c) a += feat[g*8 + c] * lw[c*4 + j];
    outLog[idx] = a;
}

extern "C" void kernel_launch(void* const* d_in, const int* in_sizes, int n_in,
                              void* d_out, int out_size, void* d_ws, size_t ws_size,
                              hipStream_t stream) {
    const float* x     = (const float*)d_in[0];
    const int*   ei    = (const int*)  d_in[1];
    const int*   batch = (const int*)  d_in[2];
    const float* W1l = (const float*)d_in[3];  const float* b1l = (const float*)d_in[4];
    const float* W1r = (const float*)d_in[5];  const float* b1r = (const float*)d_in[6];
    const float* att1= (const float*)d_in[7];  const float* bias1=(const float*)d_in[8];
    const float* g1w = (const float*)d_in[9];  const float* g1b = (const float*)d_in[10];
    const float* g1m = (const float*)d_in[11];
    const float* W2l = (const float*)d_in[12]; const float* b2l = (const float*)d_in[13];
    const float* W2r = (const float*)d_in[14]; const float* b2r = (const float*)d_in[15];
    const float* att2= (const float*)d_in[16]; const float* bias2=(const float*)d_in[17];
    const float* g2w = (const float*)d_in[18]; const float* g2b = (const float*)d_in[19];
    const float* g2m = (const float*)d_in[20];
    const float* W3l = (const float*)d_in[21]; const float* b3l = (const float*)d_in[22];
    const float* W3r = (const float*)d_in[23]; const float* b3r = (const float*)d_in[24];
    const float* att3= (const float*)d_in[25]; const float* bias3=(const float*)d_in[26];
    const float* g3w = (const float*)d_in[27]; const float* g3b = (const float*)d_in[28];
    const float* g3m = (const float*)d_in[29];
    const float* lin_w=(const float*)d_in[30]; const float* lin_b=(const float*)d_in[31];

    const int* esrc = ei;
    const int* edst = ei + EE;

    // ---- workspace arena (units of 4B) ----
    float* ws = (float*)d_ws;
    int*   cursor  = (int*)(ws + 0);         // 20480
    int*   indptr  = (int*)(ws + 20480);     // 20480
    int*   srclist = (int*)(ws + 40960);     // 320512
    int*   gstart  = (int*)(ws + 361472);    // 512
    int*   gend    = (int*)(ws + 361984);    // 512
    float* gmu     = ws + 362496;            // 16384
    float* ginv    = ws + 378880;            // 16384
    float* gsumP   = ws + 395264;            // 16384
    float* gsqP    = ws + 411648;            // 16384 (contiguous with gsumP)
    ushort_t* W1hi = (ushort_t*)(ws + 428032);  // 512*32 shorts  = 8192 words
    ushort_t* W1lo = (ushort_t*)(ws + 436224);  // 8192
    ushort_t* W2hi = (ushort_t*)(ws + 444416);  // 256*256 shorts = 32768 words
    ushort_t* W2lo = (ushort_t*)(ws + 477184);  // 32768
    ushort_t* W3hi = (ushort_t*)(ws + 509952);  // 128*128 shorts = 8192 words
    ushort_t* W3lo = (ushort_t*)(ws + 518144);  // 8192
    ushort_t* Bb = (ushort_t*)(ws + 526336);    // xl bf16: 5,120,000 shorts = 2,560,000 words
    float* Cb = ws + 3086336;                   // xr fp32: 5,120,000
    float* D  = ws + 8206336;                   // pre-norm GAT out: 5,120,000

    const int TB = 256;
    const int MBm = (NN + 63)/64;    // 313 row tiles
    const int NCH = 32;

    // weight prep (fragment-ready bf16 hi/lo split, runs every call)
    k_wprep<<<gridFor(512*4,  TB), TB, 0, stream>>>(W1l, W1r, W1hi, W1lo, 19, 32, 256);
    k_wprep<<<gridFor(256*32, TB), TB, 0, stream>>>(W2l, W2r, W2hi, W2lo, 256, 256, 128);
    k_wprep<<<gridFor(128*16, TB), TB, 0, stream>>>(W3l, W3r, W3hi, W3lo, 128, 128, 64);

    // CSR + graph bounds
    hipMemsetAsync(cursor, 0, NN*sizeof(int), stream);
    k_deg<<<gridFor(EE, TB), TB, 0, stream>>>(edst, cursor);
    k_scan<<<1, 1024, 0, stream>>>(cursor, indptr);
    hipMemsetAsync(cursor, 0, NN*sizeof(int), stream);
    k_scatter<<<gridFor(EE, TB), TB, 0, stream>>>(esrc, edst, indptr, cursor, srclist);
    k_bounds<<<gridFor(NN, TB), TB, 0, stream>>>(batch, gstart, gend);

    // ---- layer 1: 19 -> 256 (concat); combined cols 512 -> 4 col-blocks ----
    k_gemm_mfma<false><<<dim3(MBm, 4), 256, 0, stream>>>(x, W1hi, W1lo, b1l, b1r,
        nullptr, nullptr, nullptr, nullptr, nullptr, Bb, Cb, 19, 32, 256);
    k_gat_w<4, false><<<NN/4, 256, 0, stream>>>(indptr, srclist, Bb, Cb, att1, bias1, D);
    hipMemsetAsync(gsumP, 0, 2*GG*256*sizeof(float), stream);
    k_gn_partial<256><<<dim3(GG, NCH), 256, 0, stream>>>(D, gstart, gend, gsumP, gsqP);
    k_gn_finalize<<<gridFor(GG*256, TB), TB, 0, stream>>>(gsumP, gsqP, gstart, gend, g1m, gmu, ginv, 256);

    // ---- layer 2: 256 -> 128 (concat); combined cols 256 -> 2 col-blocks; L1 norm fused ----
    k_gemm_mfma<true><<<dim3(MBm, 2), 256, 0, stream>>>(D, W2hi, W2lo, b2l, b2r,
        gmu, ginv, g1w, g1b, batch, Bb, Cb, 256, 256, 128);
    k_gat_w<2, false><<<NN/4, 256, 0, stream>>>(indptr, srclist, Bb, Cb, att2, bias2, D);
    hipMemsetAsync(gsumP, 0, 2*GG*256*sizeof(float), stream);
    k_gn_partial<128><<<dim3(GG, NCH), 128, 0, stream>>>(D, gstart, gend, gsumP, gsqP);
    k_gn_finalize<<<gridFor(GG*128, TB), TB, 0, stream>>>(gsumP, gsqP, gstart, gend, g2m, gmu, ginv, 128);

    // ---- layer 3: 128 -> 64 (head mean -> 8); combined cols 128 -> 1 col-block; L2 norm fused ----
    k_gemm_mfma<true><<<dim3(MBm, 1), 256, 0, stream>>>(D, W3hi, W3lo, b3l, b3r,
        gmu, ginv, g2w, g2b, batch, Bb, Cb, 128, 128, 64);
    k_gat_w<1, true><<<NN/4, 256, 0, stream>>>(indptr, srclist, Bb, Cb, att3, bias3, D);
    k_gn_stats8<<<GG, 64, 0, stream>>>(D, gstart, gend, g3m, gmu, ginv);

    // ---- pool (layer-3 norm fused) + head ----
    float* outLog  = (float*)d_out;
    float* outFeat = outLog + GG*4;
    k_pool_gn<<<GG, 64, 0, stream>>>(D, gstart, gend, gmu, ginv, g3w, g3b, outFeat);
    k_logits<<<1, 256, 0, stream>>>(outFeat, lin_w, lin_b, outLog);
}

// Round 11
// 344.674 us; speedup vs baseline: 25.4767x; 1.0021x over previous
//
#include <hip/hip_runtime.h>
#include <math.h>

#define NN 20000
#define EE 320000
#define GG 64
#define HH 8
#define EPSV 1e-5f

static inline unsigned int gridFor(long n, int b){ return (unsigned int)((n + b - 1)/b); }

typedef __attribute__((ext_vector_type(8))) short short8;
typedef __attribute__((ext_vector_type(4))) float f32x4;
typedef unsigned short ushort_t;

// ---------------- bf16 helpers ----------------
__device__ __forceinline__ float asf(unsigned int u){
    union{unsigned int i; float f;} c; c.i = u; return c.f;
}
__device__ __forceinline__ ushort_t f2bf(float x){   // RNE
    unsigned u = __float_as_uint(x);
    unsigned r = u + 0x7FFFu + ((u >> 16) & 1u);
    return (ushort_t)(r >> 16);
}
__device__ __forceinline__ void split_bf16(float x, short& hi, short& lo){
    unsigned u = __float_as_uint(x);
    unsigned r = u + 0x7FFFu + ((u >> 16) & 1u);
    hi = (short)(r >> 16);
    float hf = asf(((unsigned)(unsigned short)hi) << 16);
    float res = x - hf;
    unsigned u2 = __float_as_uint(res);
    unsigned r2 = u2 + 0x7FFFu + ((u2 >> 16) & 1u);
    lo = (short)(r2 >> 16);
}

// ---------------- weight prep (all 3 layers) + cursor zeroing ----------------
// frag layout: element (n,k) at ((n>>4)*(Kp/32) + (k>>5))*512 + ((n&15) + 16*((k>>3)&3))*8 + (k&7)
__device__ __forceinline__ void wprep_one(const float* Wl, const float* Wr,
                                          ushort_t* Whi, ushort_t* Wlo,
                                          int K, int Kp, int HC, int t){
    int octs = Kp >> 3;
    int n = t / octs, ko = t - n*octs;
    int kb = ko*8;
    const float* W = (n < HC) ? (Wl + n) : (Wr + (n - HC));
    short hi[8], lo[8];
    #pragma unroll
    for (int j = 0; j < 8; ++j){
        int k = kb + j;
        float v = (k < K) ? W[(long)k*HC] : 0.f;
        split_bf16(v, hi[j], lo[j]);
    }
    long base = (((long)(n>>4)*(Kp>>5) + (kb>>5))*64 + (n&15) + 16*((kb>>3)&3))*8;
    *(short8*)&Whi[base] = *(short8*)hi;
    *(short8*)&Wlo[base] = *(short8*)lo;
}

#define WP1 2048   // 512 n * 4 octs
#define WP2 8192   // 256 n * 32 octs
#define WP3 2048   // 128 n * 16 octs

__global__ void k_wprep_all(const float* __restrict__ W1l, const float* __restrict__ W1r,
                            const float* __restrict__ W2l, const float* __restrict__ W2r,
                            const float* __restrict__ W3l, const float* __restrict__ W3r,
                            ushort_t* __restrict__ W1hi, ushort_t* __restrict__ W1lo,
                            ushort_t* __restrict__ W2hi, ushort_t* __restrict__ W2lo,
                            ushort_t* __restrict__ W3hi, ushort_t* __restrict__ W3lo,
                            int* __restrict__ cursor){
    int t = blockIdx.x*blockDim.x + threadIdx.x;
    if (t < NN) cursor[t] = 0;
    if (t < WP1) wprep_one(W1l, W1r, W1hi, W1lo, 19, 32, 256, t);
    else if (t < WP1+WP2) wprep_one(W2l, W2r, W2hi, W2lo, 256, 256, 128, t-WP1);
    else if (t < WP1+WP2+WP3) wprep_one(W3l, W3r, W3hi, W3lo, 128, 128, 64, t-WP1-WP2);
}

// ---------------- degree count + graph bounds + gn-partial zeroing ----------------
__global__ void k_degbounds(const int* __restrict__ edst, int* __restrict__ deg,
                            const int* __restrict__ batch,
                            int* __restrict__ gstart, int* __restrict__ gend,
                            float* __restrict__ gz){
    int e = blockIdx.x*blockDim.x + threadIdx.x;
    if (e < EE) atomicAdd(&deg[edst[e]], 1);
    if (e < NN){
        int b = batch[e];
        if (e == 0 || batch[e-1] != b) gstart[b] = e;
        if (e == NN-1 || batch[e+1] != b) gend[b] = e+1;
    }
    if (e < 2*GG*256) gz[e] = 0.f;   // gsumP ++ gsqP (contiguous)
}

// ---------------- exclusive scan (also re-zeroes cursor for scatter) ----------------
__global__ void k_scan(int* __restrict__ deg, int* __restrict__ indptr){
    __shared__ int partial[1024];
    const int CH = (NN + 1023)/1024;   // 20
    int t = threadIdx.x;
    int base = t*CH;
    int vals[CH];
    int sum = 0;
    for (int i = 0; i < CH; ++i){
        int v = (base+i < NN) ? deg[base+i] : 0;
        vals[i] = sum; sum += v;
    }
    for (int i = 0; i < CH; ++i)
        if (base+i < NN) deg[base+i] = 0;   // reset cursor in-place
    partial[t] = sum;
    __syncthreads();
    for (int off = 1; off < 1024; off <<= 1){
        int v = (t >= off) ? partial[t-off] : 0;
        __syncthreads();
        partial[t] += v;
        __syncthreads();
    }
    int prefix = (t > 0) ? partial[t-1] : 0;
    for (int i = 0; i < CH; ++i)
        if (base+i < NN) indptr[base+i] = prefix + vals[i];
    if (t == 1023) indptr[NN] = prefix + sum;
}

__global__ void k_scatter(const int* __restrict__ esrc, const int* __restrict__ edst,
                          const int* __restrict__ indptr, int* __restrict__ cursor,
                          int* __restrict__ srclist){
    int e = blockIdx.x*blockDim.x + threadIdx.x;
    if (e >= EE) return;
    int d = edst[e];
    int pos = atomicAdd(&cursor[d], 1);
    srclist[indptr[d] + pos] = esrc[e];
}

// ---------------- bf16-split MFMA dual linear, double-buffered A, 1 barrier/K-step ----------------
template<bool NORM>
__global__ __launch_bounds__(256)
void k_gemm_mfma(const float* __restrict__ h,
                 const ushort_t* __restrict__ Whi, const ushort_t* __restrict__ Wlo,
                 const float* __restrict__ bl, const float* __restrict__ br,
                 const float* __restrict__ gmu, const float* __restrict__ ginv,
                 const float* __restrict__ nw, const float* __restrict__ nb,
                 const int* __restrict__ batch,
                 ushort_t* __restrict__ xlb, float* __restrict__ xr,
                 int K, int Kp, int HC){
    __shared__ short Ahi[2][64*32], Alo[2][64*32];
    const int tid  = threadIdx.x;
    const int lane = tid & 63;
    const int wave = tid >> 6;
    const int m0   = blockIdx.x * 64;
    const int n0   = blockIdx.y * 128;
    const int wr   = (wave & 1) * 32;
    const int wcg  = (wave >> 1) * 64;
    const int kblocks = Kp >> 5;

    const int srow = tid >> 2;      // 4 threads/row: contiguous 128B
    const int soct = tid & 3;

    f32x4 acc[2][4] = {};

    for (int kb = 0; kb < kblocks; ++kb){
        int p = kb & 1;
        int k0 = kb*32;
        // ---- stage A into buffer p
        {
            int gm = m0 + srow;
            int kbase = k0 + soct*8;
            float v[8];
            const float* src = h + (long)gm*K + kbase;
            if (gm < NN && kbase + 8 <= K){
                float4 t0 = *(const float4*)src;
                float4 t1 = *(const float4*)(src+4);
                v[0]=t0.x; v[1]=t0.y; v[2]=t0.z; v[3]=t0.w;
                v[4]=t1.x; v[5]=t1.y; v[6]=t1.z; v[7]=t1.w;
            } else {
                #pragma unroll
                for (int j = 0; j < 8; ++j)
                    v[j] = (gm < NN && kbase + j < K) ? src[j] : 0.f;
            }
            if (NORM && gm < NN){
                int g = batch[gm];
                const float* mu = gmu + (long)g*K;
                const float* iv = ginv + (long)g*K;
                #pragma unroll
                for (int j = 0; j < 8; ++j){
                    int c = kbase + j;
                    float t = (v[j] - mu[c]) * iv[c] * nw[c] + nb[c];
                    v[j] = fmaxf(t, 0.f);
                }
            }
            short hi[8], lo[8];
            #pragma unroll
            for (int j = 0; j < 8; ++j) split_bf16(v[j], hi[j], lo[j]);
            long off = ((long)(srow>>4)*64 + (srow&15) + 16*soct)*8;
            *(short8*)&Ahi[p][off] = *(short8*)hi;
            *(short8*)&Alo[p][off] = *(short8*)lo;
        }
        __syncthreads();   // single barrier per K-step (dbuf makes write-after-read safe)

        int rb0 = wr >> 4;
        short8 ah0 = *(short8*)&Ahi[p][((rb0  )*64 + lane)*8];
        short8 ah1 = *(short8*)&Ahi[p][((rb0+1)*64 + lane)*8];
        short8 al0 = *(short8*)&Alo[p][((rb0  )*64 + lane)*8];
        short8 al1 = *(short8*)&Alo[p][((rb0+1)*64 + lane)*8];

        short8 bh[4], bl_[4];
        #pragma unroll
        for (int j = 0; j < 4; ++j){
            int n = n0 + wcg + j*16;
            long bbase = (((long)(n>>4)*kblocks + kb)*64 + lane)*8;
            bh[j]  = *(const short8*)&Whi[bbase];
            bl_[j] = *(const short8*)&Wlo[bbase];
        }

        #pragma unroll
        for (int j = 0; j < 4; ++j){
            acc[0][j] = __builtin_amdgcn_mfma_f32_16x16x32_bf16(al0, bh[j],  acc[0][j], 0,0,0);
            acc[0][j] = __builtin_amdgcn_mfma_f32_16x16x32_bf16(ah0, bl_[j], acc[0][j], 0,0,0);
            acc[0][j] = __builtin_amdgcn_mfma_f32_16x16x32_bf16(ah0, bh[j],  acc[0][j], 0,0,0);
            acc[1][j] = __builtin_amdgcn_mfma_f32_16x16x32_bf16(al1, bh[j],  acc[1][j], 0,0,0);
            acc[1][j] = __builtin_amdgcn_mfma_f32_16x16x32_bf16(ah1, bl_[j], acc[1][j], 0,0,0);
            acc[1][j] = __builtin_amdgcn_mfma_f32_16x16x32_bf16(ah1, bh[j],  acc[1][j], 0,0,0);
        }
    }

    // epilogue: C/D layout col=lane&15, row=(lane>>4)*4+reg
    #pragma unroll
    for (int i = 0; i < 2; ++i){
        int row0 = m0 + wr + i*16 + (lane >> 4)*4;
        #pragma unroll
        for (int j = 0; j < 4; ++j){
            int n = n0 + wcg + j*16 + (lane & 15);
            float bb = (n < HC) ? bl[n] : br[n - HC];
            #pragma unroll
            for (int r = 0; r < 4; ++r){
                int gm = row0 + r;
                if (gm >= NN) continue;
                float v = acc[i][j][r] + bb;
                if (n < HC) xlb[(long)gm*HC + n] = f2bf(v);
                else        xr[(long)gm*HC + (n - HC)] = v;
            }
        }
    }
}

// ---------------- fused GATv2, wave-per-node, bf16 gather operand ----------------
template<int VEC> struct VT;
template<> struct VT<1>{ using T = float;  };
template<> struct VT<2>{ using T = float2; };
template<> struct VT<4>{ using T = float4; };

template<int VEC> struct BF;
template<> struct BF<1>{
    static __device__ __forceinline__ float load(const ushort_t* p){
        return asf(((unsigned)*p) << 16);
    }
};
template<> struct BF<2>{
    static __device__ __forceinline__ float2 load(const ushort_t* p){
        unsigned u = *(const unsigned*)p;
        return make_float2(asf(u << 16), asf(u & 0xFFFF0000u));
    }
};
template<> struct BF<4>{
    static __device__ __forceinline__ float4 load(const ushort_t* p){
        uint2 u = *(const uint2*)p;
        return make_float4(asf(u.x << 16), asf(u.x & 0xFFFF0000u),
                           asf(u.y << 16), asf(u.y & 0xFFFF0000u));
    }
};

__device__ __forceinline__ float lrelu(float z){ return z > 0.f ? z : 0.2f*z; }

__device__ __forceinline__ float edot(float xv, float xr, float at){
    return lrelu(xv + xr) * at;
}
__device__ __forceinline__ float edot(float2 xv, float2 xr, float2 at){
    return lrelu(xv.x+xr.x)*at.x + lrelu(xv.y+xr.y)*at.y;
}
__device__ __forceinline__ float edot(float4 xv, float4 xr, float4 at){
    return lrelu(xv.x+xr.x)*at.x + lrelu(xv.y+xr.y)*at.y
         + lrelu(xv.z+xr.z)*at.z + lrelu(xv.w+xr.w)*at.w;
}
__device__ __forceinline__ void efma(float& o, float p, float xv){ o = fmaf(p,xv,o); }
__device__ __forceinline__ void efma(float2& o, float p, float2 xv){
    o.x = fmaf(p,xv.x,o.x); o.y = fmaf(p,xv.y,o.y);
}
__device__ __forceinline__ void efma(float4& o, float p, float4 xv){
    o.x = fmaf(p,xv.x,o.x); o.y = fmaf(p,xv.y,o.y);
    o.z = fmaf(p,xv.z,o.z); o.w = fmaf(p,xv.w,o.w);
}
__device__ __forceinline__ float escale(float o, float s, float b){ return fmaf(o,s,b); }
__device__ __forceinline__ float2 escale(float2 o, float s, float2 b){
    return make_float2(fmaf(o.x,s,b.x), fmaf(o.y,s,b.y));
}
__device__ __forceinline__ float4 escale(float4 o, float s, float4 b){
    return make_float4(fmaf(o.x,s,b.x), fmaf(o.y,s,b.y), fmaf(o.z,s,b.z), fmaf(o.w,s,b.w));
}

__device__ __forceinline__ float red8(float v){
    v += __shfl_xor(v, 1);
    v += __shfl_xor(v, 2);
    v += __shfl_xor(v, 4);
    return v;
}

template<int VEC, bool MEAN>
__global__ __launch_bounds__(256)
void k_gat_w(const int* __restrict__ indptr, const int* __restrict__ srclist,
             const ushort_t* __restrict__ xlb, const float* __restrict__ xr,
             const float* __restrict__ att, const float* __restrict__ bias,
             float* __restrict__ val){
    using V = typename VT<VEC>::T;
    constexpr int HC = 64*VEC;
    const int lane = threadIdx.x & 63;
    const int d = blockIdx.x*4 + (threadIdx.x >> 6);
    const int co = lane*VEC;

    V xrd = *(const V*)&xr[(long)d*HC + co];
    V at  = *(const V*)&att[co];
    V xls = BF<VEC>::load(xlb + (long)d*HC + co);

    float m0 = red8(edot(xls, xrd, at));
    float l = 1.0f;
    V o = xls;

    int j = indptr[d], end = indptr[d+1];   // wave-uniform
    for (; j + 8 <= end; j += 8){
        int s0 = srclist[j+0], s1 = srclist[j+1], s2 = srclist[j+2], s3 = srclist[j+3];
        int s4 = srclist[j+4], s5 = srclist[j+5], s6 = srclist[j+6], s7 = srclist[j+7];
        V x0 = BF<VEC>::load(xlb + (long)s0*HC + co);
        V x1 = BF<VEC>::load(xlb + (long)s1*HC + co);
        V x2 = BF<VEC>::load(xlb + (long)s2*HC + co);
        V x3 = BF<VEC>::load(xlb + (long)s3*HC + co);
        V x4 = BF<VEC>::load(xlb + (long)s4*HC + co);
        V x5 = BF<VEC>::load(xlb + (long)s5*HC + co);
        V x6 = BF<VEC>::load(xlb + (long)s6*HC + co);
        V x7 = BF<VEC>::load(xlb + (long)s7*HC + co);
        float a0 = red8(edot(x0, xrd, at));
        float a1 = red8(edot(x1, xrd, at));
        float a2 = red8(edot(x2, xrd, at));
        float a3 = red8(edot(x3, xrd, at));
        float a4 = red8(edot(x4, xrd, at));
        float a5 = red8(edot(x5, xrd, at));
        float a6 = red8(edot(x6, xrd, at));
        float a7 = red8(edot(x7, xrd, at));
        float p0 = __expf(a0 - m0), p1 = __expf(a1 - m0);
        float p2 = __expf(a2 - m0), p3 = __expf(a3 - m0);
        float p4 = __expf(a4 - m0), p5 = __expf(a5 - m0);
        float p6 = __expf(a6 - m0), p7 = __expf(a7 - m0);
        l += ((p0+p1)+(p2+p3)) + ((p4+p5)+(p6+p7));
        efma(o, p0, x0); efma(o, p1, x1); efma(o, p2, x2); efma(o, p3, x3);
        efma(o, p4, x4); efma(o, p5, x5); efma(o, p6, x6); efma(o, p7, x7);
    }
    for (; j < end; j += 4){
        int m = end - j;
        int s0 = srclist[j];
        int s1 = (m > 1) ? srclist[j+1] : s0;
        int s2 = (m > 2) ? srclist[j+2] : s0;
        int s3 = (m > 3) ? srclist[j+3] : s0;
        V x0 = BF<VEC>::load(xlb + (long)s0*HC + co);
        V x1 = BF<VEC>::load(xlb + (long)s1*HC + co);
        V x2 = BF<VEC>::load(xlb + (long)s2*HC + co);
        V x3 = BF<VEC>::load(xlb + (long)s3*HC + co);
        float a0 = red8(edot(x0, xrd, at));
        float a1 = red8(edot(x1, xrd, at));
        float a2 = red8(edot(x2, xrd, at));
        float a3 = red8(edot(x3, xrd, at));
        float p0 = __expf(a0 - m0);
        float p1 = __expf(a1 - m0);
        float p2 = __expf(a2 - m0);
        float p3 = __expf(a3 - m0);
        l += p0; efma(o, p0, x0);
        if (m > 1){ l += p1; efma(o, p1, x1); }
        if (m > 2){ l += p2; efma(o, p2, x2); }
        if (m > 3){ l += p3; efma(o, p3, x3); }
    }
    float invl = 1.0f / l;
    if (!MEAN){
        V bv = *(const V*)&bias[co];
        *(V*)&val[(long)d*HC + co] = escale(o, invl, bv);
    } else {
        float r = ((float&)o) * invl;
        r += __shfl_xor(r, 8);
        r += __shfl_xor(r, 16);
        r += __shfl_xor(r, 32);
        if (lane < 8) val[(long)d*8 + lane] = r*0.125f + bias[lane];
    }
}

// ---------------- GraphNorm stats: chunked partials + finalize (self-zeroing) ----------------
template<int F>
__global__ void k_gn_partial(const float* __restrict__ val,
                             const int* __restrict__ gstart, const int* __restrict__ gend,
                             float* __restrict__ gsum, float* __restrict__ gsq){
    int g = blockIdx.x, ch = blockIdx.y, nch = gridDim.y;
    int c = threadIdx.x;
    int s = gstart[g], e = gend[g];
    float sum = 0.f, sq = 0.f;
    for (int i = s + ch; i < e; i += nch){
        float v = val[(long)i*F + c];
        sum += v; sq += v*v;
    }
    if (sum != 0.f || sq != 0.f){
        atomicAdd(&gsum[g*F + c], sum);
        atomicAdd(&gsq[g*F + c], sq);
    }
}

__global__ void k_gn_finalize(float* __restrict__ gsum, float* __restrict__ gsq,
                              const int* __restrict__ gstart, const int* __restrict__ gend,
                              const float* __restrict__ ms,
                              float* __restrict__ gmu, float* __restrict__ ginv, int F){
    int idx = blockIdx.x*blockDim.x + threadIdx.x;
    if (idx >= GG*F) return;
    int g = idx / F, c = idx - g*F;
    int cnti = gend[g] - gstart[g];
    float cn = cnti > 0 ? (float)cnti : 1.f;
    float mean = gsum[idx] / cn;
    float mu = mean * ms[c];
    float var = gsq[idx]/cn - 2.f*mu*mean + mu*mu;
    gmu[idx]  = mu;
    ginv[idx] = rsqrtf(var + EPSV);
    gsum[idx] = 0.f;   // ready for next layer (no memset dispatch)
    gsq[idx]  = 0.f;
}

// ---------------- fused tail: layer-3 GraphNorm stats + norm+relu pool + logits ----------------
__global__ void k_tail(const float* __restrict__ D,
                       const int* __restrict__ gstart, const int* __restrict__ gend,
                       const float* __restrict__ ms, const float* __restrict__ w,
                       const float* __restrict__ b,
                       const float* __restrict__ lw, const float* __restrict__ lb,
                       float* __restrict__ outLog, float* __restrict__ outFeat){
    int g = blockIdx.x;
    int t = threadIdx.x;          // 64: c = t&7, r = t>>3
    int c = t & 7, r = t >> 3;
    int s = gstart[g], e = gend[g];
    int cnti = e - s;
    float cn = cnti > 0 ? (float)cnti : 1.f;

    // pass 1: stats for channel c
    float sum = 0.f, sq = 0.f;
    for (int i = s + r; i < e; i += 8){
        float v = D[(long)i*8 + c];
        sum += v; sq += v*v;
    }
    #pragma unroll
    for (int mask = 8; mask < 64; mask <<= 1){
        sum += __shfl_xor(sum, mask, 64);
        sq  += __shfl_xor(sq,  mask, 64);
    }
    float mean = sum / cn;
    float mu = mean * ms[c];
    float var = sq/cn - 2.f*mu*mean + mu*mu;
    float iv = rsqrtf(var + EPSV);
    float wc = w[c], bc = b[c];

    // pass 2: pooled mean of relu(norm)
    float psum = 0.f;
    for (int i = s + r; i < e; i += 8){
        float v = (D[(long)i*8 + c] - mu) * iv * wc + bc;
        psum += fmaxf(v, 0.f);
    }
    #pragma unroll
    for (int mask = 8; mask < 64; mask <<= 1)
        psum += __shfl_xor(psum, mask, 64);
    float feat = psum / cn;       // every lane: feature for its c

    if (t < 8) outFeat[g*8 + t] = feat;

    // pass 3: logits from lanes 0..7 (they hold c=0..7)
    float a = 0.f;
    int jj = t;                    // lane t<4 computes logit jj
    if (t < 4){
        a = lb[jj];
    }
    #pragma unroll
    for (int cc = 0; cc < 8; ++cc){
        float fc = __shfl(feat, cc, 64);
        if (t < 4) a += fc * lw[cc*4 + jj];
    }
    if (t < 4) outLog[g*4 + jj] = a;
}

extern "C" void kernel_launch(void* const* d_in, const int* in_sizes, int n_in,
                              void* d_out, int out_size, void* d_ws, size_t ws_size,
                              hipStream_t stream) {
    const float* x     = (const float*)d_in[0];
    const int*   ei    = (const int*)  d_in[1];
    const int*   batch = (const int*)  d_in[2];
    const float* W1l = (const float*)d_in[3];  const float* b1l = (const float*)d_in[4];
    const float* W1r = (const float*)d_in[5];  const float* b1r = (const float*)d_in[6];
    const float* att1= (const float*)d_in[7];  const float* bias1=(const float*)d_in[8];
    const float* g1w = (const float*)d_in[9];  const float* g1b = (const float*)d_in[10];
    const float* g1m = (const float*)d_in[11];
    const float* W2l = (const float*)d_in[12]; const float* b2l = (const float*)d_in[13];
    const float* W2r = (const float*)d_in[14]; const float* b2r = (const float*)d_in[15];
    const float* att2= (const float*)d_in[16]; const float* bias2=(const float*)d_in[17];
    const float* g2w = (const float*)d_in[18]; const float* g2b = (const float*)d_in[19];
    const float* g2m = (const float*)d_in[20];
    const float* W3l = (const float*)d_in[21]; const float* b3l = (const float*)d_in[22];
    const float* W3r = (const float*)d_in[23]; const float* b3r = (const float*)d_in[24];
    const float* att3= (const float*)d_in[25]; const float* bias3=(const float*)d_in[26];
    const float* g3w = (const float*)d_in[27]; const float* g3b = (const float*)d_in[28];
    const float* g3m = (const float*)d_in[29];
    const float* lin_w=(const float*)d_in[30]; const float* lin_b=(const float*)d_in[31];

    const int* esrc = ei;
    const int* edst = ei + EE;

    // ---- workspace arena (units of 4B) ----
    float* ws = (float*)d_ws;
    int*   cursor  = (int*)(ws + 0);         // 20480
    int*   indptr  = (int*)(ws + 20480);     // 20480
    int*   srclist = (int*)(ws + 40960);     // 320512
    int*   gstart  = (int*)(ws + 361472);    // 512
    int*   gend    = (int*)(ws + 361984);    // 512
    float* gmu     = ws + 362496;            // 16384
    float* ginv    = ws + 378880;            // 16384
    float* gsumP   = ws + 395264;            // 16384
    float* gsqP    = ws + 411648;            // 16384 (contiguous with gsumP)
    ushort_t* W1hi = (ushort_t*)(ws + 428032);  // 8192 words
    ushort_t* W1lo = (ushort_t*)(ws + 436224);  // 8192
    ushort_t* W2hi = (ushort_t*)(ws + 444416);  // 32768
    ushort_t* W2lo = (ushort_t*)(ws + 477184);  // 32768
    ushort_t* W3hi = (ushort_t*)(ws + 509952);  // 8192
    ushort_t* W3lo = (ushort_t*)(ws + 518144);  // 8192
    ushort_t* Bb = (ushort_t*)(ws + 526336);    // xl bf16: 2,560,000 words
    float* Cb = ws + 3086336;                   // xr fp32: 5,120,000
    float* D  = ws + 8206336;                   // pre-norm GAT out: 5,120,000

    const int TB = 256;
    const int MBm = (NN + 63)/64;    // 313 row tiles
    const int NCH = 32;

    // 1: weight prep (all layers) + cursor zeroing
    k_wprep_all<<<gridFor(NN, TB), TB, 0, stream>>>(W1l, W1r, W2l, W2r, W3l, W3r,
        W1hi, W1lo, W2hi, W2lo, W3hi, W3lo, cursor);
    // 2: degree count + graph bounds + gn-partial zero
    k_degbounds<<<gridFor(EE, TB), TB, 0, stream>>>(edst, cursor, batch, gstart, gend, gsumP);
    // 3: scan (re-zeroes cursor)
    k_scan<<<1, 1024, 0, stream>>>(cursor, indptr);
    // 4: scatter
    k_scatter<<<gridFor(EE, TB), TB, 0, stream>>>(esrc, edst, indptr, cursor, srclist);

    // ---- layer 1: 19 -> 256 (concat) ----
    k_gemm_mfma<false><<<dim3(MBm, 4), 256, 0, stream>>>(x, W1hi, W1lo, b1l, b1r,
        nullptr, nullptr, nullptr, nullptr, nullptr, Bb, Cb, 19, 32, 256);
    k_gat_w<4, false><<<NN/4, 256, 0, stream>>>(indptr, srclist, Bb, Cb, att1, bias1, D);
    k_gn_partial<256><<<dim3(GG, NCH), 256, 0, stream>>>(D, gstart, gend, gsumP, gsqP);
    k_gn_finalize<<<gridFor(GG*256, TB), TB, 0, stream>>>(gsumP, gsqP, gstart, gend, g1m, gmu, ginv, 256);

    // ---- layer 2: 256 -> 128 (concat); L1 norm fused into A-staging ----
    k_gemm_mfma<true><<<dim3(MBm, 2), 256, 0, stream>>>(D, W2hi, W2lo, b2l, b2r,
        gmu, ginv, g1w, g1b, batch, Bb, Cb, 256, 256, 128);
    k_gat_w<2, false><<<NN/4, 256, 0, stream>>>(indptr, srclist, Bb, Cb, att2, bias2, D);
    k_gn_partial<128><<<dim3(GG, NCH), 128, 0, stream>>>(D, gstart, gend, gsumP, gsqP);
    k_gn_finalize<<<gridFor(GG*128, TB), TB, 0, stream>>>(gsumP, gsqP, gstart, gend, g2m, gmu, ginv, 128);

    // ---- layer 3: 128 -> 64 (head mean -> 8); L2 norm fused ----
    k_gemm_mfma<true><<<dim3(MBm, 1), 256, 0, stream>>>(D, W3hi, W3lo, b3l, b3r,
        gmu, ginv, g2w, g2b, batch, Bb, Cb, 128, 128, 64);
    k_gat_w<1, true><<<NN/4, 256, 0, stream>>>(indptr, srclist, Bb, Cb, att3, bias3, D);

    // ---- fused tail: L3 norm stats + pool + logits ----
    float* outLog  = (float*)d_out;
    float* outFeat = outLog + GG*4;
    k_tail<<<GG, 64, 0, stream>>>(D, gstart, gend, g3m, g3w, g3b, lin_w, lin_b, outLog, outFeat);
}